// Round 7
// baseline (238.804 us; speedup 1.0000x reference)
//
#include <hip/hip_runtime.h>
#include <hip/hip_bf16.h>

typedef unsigned short u16;
typedef unsigned int u32;
typedef __bf16 bf16x8 __attribute__((ext_vector_type(8)));
typedef u16 u16x8 __attribute__((ext_vector_type(8)));
typedef u32 u32x4 __attribute__((ext_vector_type(4)));
typedef float f32x4 __attribute__((ext_vector_type(4)));
typedef float f32x16 __attribute__((ext_vector_type(16)));

#define T_SEQ 2048
#define DMODEL 2048
#define NHEAD 16
#define HDIM 128
#define ATT_SCALE 0.08838834764831843f

__device__ __forceinline__ u16 f2bf(float f) {
    return __builtin_bit_cast(u16, __float2bfloat16(f));
}
__device__ __forceinline__ bf16x8 as_bf(u16x8 v) {
    return __builtin_bit_cast(bf16x8, v);
}
__device__ __forceinline__ float lo2f(u32 w) { return __builtin_bit_cast(float, w << 16); }
__device__ __forceinline__ float hi2f(u32 w) { return __builtin_bit_cast(float, w & 0xffff0000u); }
__device__ __forceinline__ void gload_lds16(const u16* g, u16* l) {
    __builtin_amdgcn_global_load_lds(
        (const __attribute__((address_space(1))) u32*)(g),
        (__attribute__((address_space(3))) u32*)(l), 16, 0, 0);
}

// ---------------- fused weight casts fp32 -> bf16 ----------------
__global__ __launch_bounds__(256) void cast_both(const float* __restrict__ w1,
                                                 const float* __restrict__ w2,
                                                 u16* __restrict__ d1,
                                                 u16* __restrict__ d2) {
    int i = blockIdx.x * 256 + threadIdx.x;
    const float* src; u16* dst; int k;
    if (i < 1572864) { src = w1; dst = d1; k = i; }
    else             { src = w2; dst = d2; k = i - 1572864; }
    float4 a = ((const float4*)src)[2 * k];
    float4 b = ((const float4*)src)[2 * k + 1];
    u16x8 o;
    o[0] = f2bf(a.x); o[1] = f2bf(a.y); o[2] = f2bf(a.z); o[3] = f2bf(a.w);
    o[4] = f2bf(b.x); o[5] = f2bf(b.y); o[6] = f2bf(b.z); o[7] = f2bf(b.w);
    *(u16x8*)(dst + (size_t)k * 8) = o;
}

// ---------------- row RMSNorm over D=2048, write bf16 ----------------
__global__ __launch_bounds__(256) void rmsnorm_row(const float* __restrict__ x,
                                                   u16* __restrict__ xn) {
    const int row = blockIdx.x, tid = threadIdx.x;
    const float* xr = x + (size_t)row * DMODEL;
    float4 a = ((const float4*)xr)[2 * tid];
    float4 b = ((const float4*)xr)[2 * tid + 1];
    float ss = a.x*a.x + a.y*a.y + a.z*a.z + a.w*a.w
             + b.x*b.x + b.y*b.y + b.z*b.z + b.w*b.w;
#pragma unroll
    for (int off = 32; off; off >>= 1) ss += __shfl_xor(ss, off);
    __shared__ float red[4];
    if ((tid & 63) == 0) red[tid >> 6] = ss;
    __syncthreads();
    float tot = red[0] + red[1] + red[2] + red[3];
    float r = rsqrtf(tot * (1.f / DMODEL) + 1e-6f);
    u16x8 o;
    o[0] = f2bf(a.x*r); o[1] = f2bf(a.y*r); o[2] = f2bf(a.z*r); o[3] = f2bf(a.w*r);
    o[4] = f2bf(b.x*r); o[5] = f2bf(b.y*r); o[6] = f2bf(b.z*r); o[7] = f2bf(b.w*r);
    *(u16x8*)(xn + (size_t)row * DMODEL + tid * 8) = o;
}

// ---------------- 128x128 m97-style GEMM (out-proj, fp32 C + resid) --------
__global__ __launch_bounds__(256) void gemm_bt(const u16* __restrict__ A,
                                               const u16* __restrict__ B,
                                               float* __restrict__ C,
                                               const float* __restrict__ resid,
                                               int M, int N, int K) {
    __shared__ u16 As[128 * 32];
    __shared__ u16 Bs[128 * 32];
    const int bm = blockIdx.y * 128, bn = blockIdx.x * 128;
    const int tid = threadIdx.x, lane = tid & 63, wid = tid >> 6;
    const int wr = (wid >> 1) * 64, wc = (wid & 1) * 64;
    const int fr = lane & 15, fc = (lane >> 4) * 8;

    f32x4 acc[4][4] = {};
    const int r0 = tid >> 2, c0 = (tid & 3) << 3;
    const u16* a0p = A + (size_t)(bm + r0) * K + c0;
    const u16* a1p = A + (size_t)(bm + r0 + 64) * K + c0;
    const u16* b0p = B + (size_t)(bn + r0) * K + c0;
    const u16* b1p = B + (size_t)(bn + r0 + 64) * K + c0;
    u16* la0 = As + (size_t)tid * 8;
    u16* la1 = As + (size_t)(tid + 256) * 8;
    u16* lb0 = Bs + (size_t)tid * 8;
    u16* lb1 = Bs + (size_t)(tid + 256) * 8;

    for (int k0 = 0; k0 < K; k0 += 32) {
        gload_lds16(a0p + k0, la0);
        gload_lds16(a1p + k0, la1);
        gload_lds16(b0p + k0, lb0);
        gload_lds16(b1p + k0, lb1);
        __syncthreads();

        u16x8 af[4], bfm[4];
#pragma unroll
        for (int m = 0; m < 4; ++m)
            af[m] = *(const u16x8*)&As[(wr + m * 16 + fr) * 32 + fc];
#pragma unroll
        for (int n = 0; n < 4; ++n)
            bfm[n] = *(const u16x8*)&Bs[(wc + n * 16 + fr) * 32 + fc];
#pragma unroll
        for (int m = 0; m < 4; ++m)
#pragma unroll
            for (int n = 0; n < 4; ++n)
                acc[m][n] = __builtin_amdgcn_mfma_f32_16x16x32_bf16(
                    as_bf(af[m]), as_bf(bfm[n]), acc[m][n], 0, 0, 0);
        __syncthreads();
    }

#pragma unroll
    for (int m = 0; m < 4; ++m)
#pragma unroll
        for (int n = 0; n < 4; ++n)
#pragma unroll
            for (int r = 0; r < 4; ++r) {
                int row = bm + wr + m * 16 + (lane >> 4) * 4 + r;
                int col = bn + wc + n * 16 + fr;
                float val = acc[m][n][r];
                if (resid) val += resid[(size_t)row * N + col];
                C[(size_t)row * N + col] = val;
            }
}

// ---------------- 256x256 8-phase GEMM, gray-code operand reuse ------------
#define VM4 asm volatile("s_waitcnt vmcnt(4)" ::: "memory");
#define VM0 asm volatile("s_waitcnt vmcnt(0)" ::: "memory");

#define LDA(BUF, MH)                                                          \
  _Pragma("unroll") for (int mq = 0; mq < 4; ++mq) {                          \
    int ra = wr + (MH) * 64 + mq * 16 + fr;                                   \
    int sw = ra & 7;                                                          \
    _Pragma("unroll") for (int k2 = 0; k2 < 2; ++k2)                          \
      av[mq][k2] = *(const u16x8*)(sA[BUF] + ra * 64 +                        \
                                   ((((k2 << 2) | fg) ^ sw) << 3));           \
  }

#define LDB(BUF, NH)                                                          \
  _Pragma("unroll") for (int nq = 0; nq < 2; ++nq) {                          \
    int rb = wc + (NH) * 32 + nq * 16 + fr;                                   \
    int sw = rb & 7;                                                          \
    _Pragma("unroll") for (int k2 = 0; k2 < 2; ++k2)                          \
      bv[nq][k2] = *(const u16x8*)(sB[BUF] + rb * 64 +                        \
                                   ((((k2 << 2) | fg) ^ sw) << 3));           \
  }

#define MFMAQ(MH, NH)                                                         \
  __builtin_amdgcn_s_barrier();                                               \
  __builtin_amdgcn_s_setprio(1);                                              \
  _Pragma("unroll") for (int k2 = 0; k2 < 2; ++k2)                            \
    _Pragma("unroll") for (int mq = 0; mq < 4; ++mq)                          \
      _Pragma("unroll") for (int nq = 0; nq < 2; ++nq)                        \
        acc[(MH) * 4 + mq][(NH) * 2 + nq] =                                   \
            __builtin_amdgcn_mfma_f32_16x16x32_bf16(                          \
                as_bf(av[mq][k2]), as_bf(bv[nq][k2]),                         \
                acc[(MH) * 4 + mq][(NH) * 2 + nq], 0, 0, 0);                  \
  __builtin_amdgcn_s_setprio(0);

#define ENDP                                                                  \
  __builtin_amdgcn_s_barrier();                                               \
  __builtin_amdgcn_sched_barrier(0);

__global__ __launch_bounds__(512) void gemm256(const u16* __restrict__ A,
                                               const u16* __restrict__ B,
                                               u16* __restrict__ C,
                                               int M, int N, int K) {
    extern __shared__ char smem[];
    const int tid = threadIdx.x, lane = tid & 63, wid = tid >> 6;
    const int bm = blockIdx.y * 256, bn = blockIdx.x * 256;
    const int wr = (wid >> 2) * 128, wc = (wid & 3) * 64;
    const int fr = lane & 15, fg = lane >> 4;

    u16* sA[2] = {(u16*)smem, (u16*)(smem + 65536)};
    u16* sB[2] = {(u16*)(smem + 32768), (u16*)(smem + 98304)};

    const int cs = (((tid & 7) ^ ((tid >> 3) & 7)) << 3);
    const int s8 = (tid & 7) << 3;
    const int rr6 = tid >> 3;
    const int rb0 = ((tid >> 8) << 6) + ((tid >> 3) & 31);

    auto stA = [&](int buf, int k0, int mh) {
#pragma unroll
        for (int j = 0; j < 2; ++j) {
            int r = j * 128 + mh * 64 + rr6;
            gload_lds16(A + (size_t)(bm + r) * K + k0 + cs, sA[buf] + r * 64 + s8);
        }
    };
    auto stB = [&](int buf, int k0, int nh) {
#pragma unroll
        for (int j = 0; j < 2; ++j) {
            int r = j * 128 + nh * 32 + rb0;
            gload_lds16(B + (size_t)(bn + r) * K + k0 + cs, sB[buf] + r * 64 + s8);
        }
    };

    f32x4 acc[8][4] = {};
    u16x8 av[4][2], bv[2][2];
    const int nt = K >> 6;

    stA(0, 0, 0); stA(0, 0, 1); stB(0, 0, 0); stB(0, 0, 1);
    stA(1, 64, 0); stB(1, 64, 1);
    VM4
    __builtin_amdgcn_s_barrier();
    __builtin_amdgcn_sched_barrier(0);

    for (int it = 0; it < (nt >> 1); ++it) {
        const int kc = it << 7;
        const int kn1 = kc + 64, kn2 = kc + 128, kn3 = kc + 192;
        const bool st2 = (kn2 < K), st3 = (kn3 < K);

        LDA(0, 0) LDB(0, 0)
        stA(1, kn1, 1);
        MFMAQ(0, 0) ENDP
        LDB(0, 1)
        stB(1, kn1, 0);
        MFMAQ(0, 1) ENDP
        LDA(0, 1)
        if (st2) stA(0, kn2, 0);
        MFMAQ(1, 1) ENDP
        LDB(0, 0)
        if (st2) stB(0, kn2, 1);
        MFMAQ(1, 0)
        if (st2) { VM4 } else { VM0 }
        ENDP
        LDA(1, 0) LDB(1, 0)
        if (st2) stA(0, kn2, 1);
        MFMAQ(0, 0) ENDP
        LDB(1, 1)
        if (st2) stB(0, kn2, 0);
        MFMAQ(0, 1) ENDP
        LDA(1, 1)
        if (st3) stA(1, kn3, 0);
        MFMAQ(1, 1) ENDP
        LDB(1, 0)
        if (st3) stB(1, kn3, 1);
        MFMAQ(1, 0)
        VM4
        ENDP
    }

#pragma unroll
    for (int am = 0; am < 8; ++am)
#pragma unroll
        for (int bq = 0; bq < 4; ++bq)
#pragma unroll
            for (int r = 0; r < 4; ++r) {
                int row = bm + wr + am * 16 + fg * 4 + r;
                int col = bn + wc + bq * 16 + fr;
                C[(size_t)row * N + col] = f2bf(acc[am][bq][r]);
            }
}

// ---------------- per-head RMSNorm + RoPE (vectorized, bf16 qkv) -----------
// k_blk: blocked 16B-unit layout [h][tb=T/64][cc=16][kvr=64] where
// chunk holds K[t=tb*64+kvr][d=cc*8 .. +8] (for attn gload_lds staging).
__global__ __launch_bounds__(256) void rope_split(const u16* __restrict__ qkv,
                                                  const float* __restrict__ cosb,
                                                  const float* __restrict__ sinb,
                                                  u16* __restrict__ q_bf,
                                                  u16* __restrict__ k_blk,
                                                  float* __restrict__ k_out,
                                                  float* __restrict__ v_out) {
    const int t = blockIdx.x, tid = threadIdx.x, wid = tid >> 6, lane = tid & 63;
    const u16* row = qkv + (size_t)t * (3 * DMODEL);
    const int dp = (lane & 31) << 1;
    float2 c2 = *(const float2*)(cosb + t * 64 + dp);
    float2 s2 = *(const float2*)(sinb + t * 64 + dp);
    const bool hi = lane >= 32;
    const int tb = t >> 6, kvr = t & 63;
    const int d2 = lane * 2;

    for (int task = wid; task < 32; task += 4) {
        u32 w = *(const u32*)(row + task * 128 + lane * 2);
        float xa = lo2f(w), xb = hi2f(w);
        float ss = xa * xa + xb * xb;
#pragma unroll
        for (int off = 32; off; off >>= 1) ss += __shfl_xor(ss, off);
        float rn = rsqrtf(ss * (1.f / 128.f) + 1e-6f);
        float pa = __shfl_xor(xa, 32), pb = __shfl_xor(xb, 32);
        float oa, ob;
        if (!hi) {
            oa = (xa * c2.x - pa * s2.x) * rn;
            ob = (xb * c2.y - pb * s2.y) * rn;
        } else {
            oa = (pa * s2.x + xa * c2.x) * rn;
            ob = (pb * s2.y + xb * c2.y) * rn;
        }
        u32 pk = (u32)f2bf(oa) | ((u32)f2bf(ob) << 16);
        if (task < 16) {
            *(u32*)(q_bf + ((size_t)task * T_SEQ + t) * 128 + lane * 2) = pk;
        } else {
            int hh = task - 16;
            size_t off = ((((size_t)hh * 32 + tb) * 16 + (d2 >> 3)) * 64 + kvr) * 8 + (d2 & 7);
            *(u32*)(k_blk + off) = pk;
            float2 kk; kk.x = oa; kk.y = ob;
            *(float2*)(k_out + (size_t)t * DMODEL + hh * 128 + lane * 2) = kk;
        }
    }
    {
        u16x8 vv = *(const u16x8*)(row + 2 * DMODEL + tid * 8);
        float4 f0, f1;
        f0.x = __builtin_bit_cast(float, (u32)vv[0] << 16);
        f0.y = __builtin_bit_cast(float, (u32)vv[1] << 16);
        f0.z = __builtin_bit_cast(float, (u32)vv[2] << 16);
        f0.w = __builtin_bit_cast(float, (u32)vv[3] << 16);
        f1.x = __builtin_bit_cast(float, (u32)vv[4] << 16);
        f1.y = __builtin_bit_cast(float, (u32)vv[5] << 16);
        f1.z = __builtin_bit_cast(float, (u32)vv[6] << 16);
        f1.w = __builtin_bit_cast(float, (u32)vv[7] << 16);
        *(float4*)(v_out + (size_t)t * DMODEL + tid * 8) = f0;
        *(float4*)(v_out + (size_t)t * DMODEL + tid * 8 + 4) = f1;
    }
}

// ---------------- V blocked transpose: [h][tb][j=8][d=128] 16B units -------
// chunk (h,tb,j,d) holds V[t = tb*64 + j*8 .. +8][d] (8 kv values, fixed d).
__global__ __launch_bounds__(256) void vtrans(const u16* __restrict__ qkv,
                                              u16* __restrict__ vt) {
    const int b = blockIdx.x, tid = threadIdx.x;
    const int head = b >> 7;
    const int i = (b & 127) * 256 + tid;
    const int d = i & 127, tc = i >> 7;
    u16x8 o;
#pragma unroll
    for (int j = 0; j < 8; ++j)
        o[j] = qkv[(size_t)(tc * 8 + j) * (3 * DMODEL) + 2 * DMODEL + head * 128 + d];
    size_t chunk = (((size_t)head * 32 + (tc >> 3)) * 8 + (tc & 7)) * 128 + d;
    *(u16x8*)&vt[chunk * 8] = o;
}

// ---------------- causal flash attention v3 --------------------------------
// 512 blocks x 256 thr = 4 waves: (qg = wid&1) x (s = wid>>1 kv-half).
// Wave owns 32 q-rows, 32x32x16 MFMA (Q in regs), kv tiles split between
// s=0 [0,n0) and s=1 [n0,nt); flash-decode merge at end. K/V staged once
// per tile via gload_lds from blocked global layouts; conflict-free reads.
__global__ __launch_bounds__(256, 1) void attn_fwd(const u16* __restrict__ qb,
                                                   const u16* __restrict__ kblk,
                                                   const u16* __restrict__ vblk,
                                                   u16* __restrict__ xout) {
    extern __shared__ char lds[];   // K: 2s x 2buf x 16KB @0 ; V same @65536
    const int bid = blockIdx.x;
    const int r8 = bid & 7, sb = bid >> 3;
    const int head = r8 + ((sb >> 5) << 3);
    const int jj = sb & 31;
    const int qt = (sb < 32) ? (31 - jj) : jj;

    const int tid = threadIdx.x, lane = tid & 63;
    const int wid = tid >> 6;
    const int qg = wid & 1, s = wid >> 1;
    const int l31 = lane & 31, hi = lane >> 5;

    const int nt = qt + 1;
    const int n0 = (nt + 1) >> 1;
    const int myfirst = s ? n0 : 0;
    const int mycount = s ? (nt - n0) : n0;
    const int qw0 = qt * 64 + qg * 32;
    const int qglob = qw0 + l31;

    const u16* khb = kblk + (size_t)head * 262144;
    const u16* vhb = vblk + (size_t)head * 262144;
    const u16* qh  = qb + (size_t)head * 262144;

    char* Kb0 = lds + s * 32768;
    char* Vb0 = lds + 65536 + s * 32768;

    u16x8 bq[8];
#pragma unroll
    for (int c = 0; c < 8; ++c)
        bq[c] = *(const u16x8*)(qh + (size_t)(qw0 + l31) * 128 + c * 16 + hi * 8);

    auto stage = [&](int t, int buf) {
        const u16* kg = khb + (size_t)t * 8192 + (qg * 512 + lane) * 8;
        const u16* vg = vhb + (size_t)t * 8192 + (qg * 512 + lane) * 8;
        u16* kd = (u16*)(Kb0 + buf * 16384) + (qg * 512 + lane) * 8;
        u16* vd = (u16*)(Vb0 + buf * 16384) + (qg * 512 + lane) * 8;
#pragma unroll
        for (int i = 0; i < 8; ++i) gload_lds16(kg + i * 512, kd + i * 512);
#pragma unroll
        for (int i = 0; i < 8; ++i) gload_lds16(vg + i * 512, vd + i * 512);
    };

    if (mycount > 0) stage(myfirst, 0);

    f32x16 o[4] = {};
    float m_run = -1e30f, l_run = 0.f;

    for (int i = 0; i < n0; ++i) {
        const int buf = i & 1;
        const bool valid = i < mycount;
        const bool havenext = (i + 1) < mycount;
        if (havenext) {
            stage(myfirst + i + 1, buf ^ 1);
            asm volatile("s_waitcnt vmcnt(16)" ::: "memory");
        } else {
            asm volatile("s_waitcnt vmcnt(0)" ::: "memory");
        }
        __builtin_amdgcn_s_barrier();
        __builtin_amdgcn_sched_barrier(0);

        if (valid) {
            const int kv0 = (myfirst + i) * 64;
            const char* Kp = Kb0 + buf * 16384;
            const char* Vp = Vb0 + buf * 16384;

            f32x16 sc[2] = {};
#pragma unroll
            for (int kvg = 0; kvg < 2; ++kvg)
#pragma unroll
                for (int c = 0; c < 8; ++c) {
                    u16x8 ak = *(const u16x8*)(Kp + (2 * c + hi) * 1024 + (kvg * 32 + l31) * 16);
                    sc[kvg] = __builtin_amdgcn_mfma_f32_32x32x16_bf16(
                        as_bf(ak), as_bf(bq[c]), sc[kvg], 0, 0, 0);
                }

            float p[32];
            float pmax = -1e30f;
            const bool msk = (kv0 + 64 > qw0);
#pragma unroll
            for (int kvg = 0; kvg < 2; ++kvg)
#pragma unroll
                for (int r = 0; r < 16; ++r) {
                    float sv = sc[kvg][r] * ATT_SCALE;
                    if (msk) {
                        int kvg_i = kv0 + kvg * 32 + (r & 3) + 8 * (r >> 2) + 4 * hi;
                        sv = (kvg_i <= qglob) ? sv : -1e30f;
                    }
                    p[kvg * 16 + r] = sv;
                    pmax = fmaxf(pmax, sv);
                }
            pmax = fmaxf(pmax, __shfl_xor(pmax, 32));

            float m_use;
            if (__all(pmax - m_run <= 8.f)) {
                m_use = m_run;
            } else {
                float m_new = fmaxf(m_run, pmax);
                float corr = __expf(m_run - m_new);
                l_run *= corr;
                m_run = m_new; m_use = m_new;
#pragma unroll
                for (int r = 0; r < 16; ++r) {
                    float cs = __shfl(corr, (r & 3) + 8 * (r >> 2) + 4 * hi);
                    o[0][r] *= cs; o[1][r] *= cs; o[2][r] *= cs; o[3][r] *= cs;
                }
            }
            float rs = 0.f;
#pragma unroll
            for (int e = 0; e < 32; ++e) { p[e] = __expf(p[e] - m_use); rs += p[e]; }
            rs += __shfl_xor(rs, 32);
            l_run += rs;

            // P -> bf16 A-frags (pack + cross-half exchange)
            u32x4 paf[4];
#pragma unroll
            for (int kvg = 0; kvg < 2; ++kvg) {
                u32 W[8], S[8];
#pragma unroll
                for (int m = 0; m < 8; ++m)
                    W[m] = (u32)f2bf(p[kvg * 16 + 2 * m]) |
                           ((u32)f2bf(p[kvg * 16 + 2 * m + 1]) << 16);
#pragma unroll
                for (int m = 0; m < 8; ++m) S[m] = (u32)__shfl_xor((int)W[m], 32);
#pragma unroll
                for (int kc2 = 0; kc2 < 2; ++kc2) {
                    int kc = kvg * 2 + kc2;
                    paf[kc][0] = hi ? S[4 * kc2 + 2] : W[4 * kc2];
                    paf[kc][1] = hi ? S[4 * kc2 + 3] : W[4 * kc2 + 1];
                    paf[kc][2] = hi ? W[4 * kc2 + 2] : S[4 * kc2];
                    paf[kc][3] = hi ? W[4 * kc2 + 3] : S[4 * kc2 + 1];
                }
            }
#pragma unroll
            for (int kc = 0; kc < 4; ++kc) {
                bf16x8 pa = __builtin_bit_cast(bf16x8, paf[kc]);
#pragma unroll
                for (int dg = 0; dg < 4; ++dg) {
                    u16x8 vB = *(const u16x8*)(Vp + (2 * kc + hi) * 2048 + (dg * 32 + l31) * 16);
                    o[dg] = __builtin_amdgcn_mfma_f32_32x32x16_bf16(
                        pa, as_bf(vB), o[dg], 0, 0, 0);
                }
            }
        }
        __builtin_amdgcn_s_barrier();
    }

    // ---- merge kv-halves (flash-decode style) ----
    float* stm = (float*)lds;            // [qg][s][32]
    float* stl = (float*)(lds + 512);
    float* om  = (float*)(lds + 4096);   // [qg*64+lane][68-pad]
    if (hi == 0) {
        stm[(qg * 2 + s) * 32 + l31] = m_run;
        stl[(qg * 2 + s) * 32 + l31] = l_run;
    }
    __syncthreads();
    float mo = stm[(qg * 2 + (1 ^ s)) * 32 + l31];
    float lo = stl[(qg * 2 + (1 ^ s)) * 32 + l31];
    float mt = fmaxf(m_run, mo);
    float w  = __expf(m_run - mt);
    float lt = l_run * w + lo * __expf(mo - mt);
    float inv = 1.f / lt;
    float ws[16], invs[16];
#pragma unroll
    for (int r = 0; r < 16; ++r) {
        int qr = (r & 3) + 8 * (r >> 2) + 4 * hi;
        ws[r] = __shfl(w, qr);
        invs[r] = __shfl(inv, qr);
    }
    if (s == 1) {
        float* op = om + ((size_t)qg * 64 + lane) * 68;
#pragma unroll
        for (int dg = 0; dg < 4; ++dg)
#pragma unroll
            for (int r = 0; r < 16; ++r) op[dg * 16 + r] = o[dg][r] * ws[r];
    }
    __syncthreads();
    if (s == 0) {
        const float* op = om + ((size_t)qg * 64 + lane) * 68;
#pragma unroll
        for (int dg = 0; dg < 4; ++dg)
#pragma unroll
            for (int r = 0; r < 16; ++r) {
                int qr = (r & 3) + 8 * (r >> 2) + 4 * hi;
                float val = (o[dg][r] * ws[r] + op[dg * 16 + r]) * invs[r];
                xout[(size_t)(qt * 64 + qg * 32 + qr) * DMODEL + head * 128 + dg * 32 + l31] =
                    f2bf(val);
            }
    }
}

extern "C" void kernel_launch(void* const* d_in, const int* in_sizes, int n_in,
                              void* d_out, int out_size, void* d_ws, size_t ws_size,
                              hipStream_t stream) {
    const float* x_in = (const float*)d_in[0];
    const float* w_qkv = (const float*)d_in[1];
    const float* w_o = (const float*)d_in[2];
    const float* cosb = (const float*)d_in[3];
    const float* sinb = (const float*)d_in[4];

    float* out = (float*)d_out;
    float* k_out = out + 4194304;
    float* v_out = out + 8388608;

    char* ws = (char*)d_ws;
    u16* xn    = (u16*)(ws);                         // 8 MiB  [T][D] bf16
    u16* w_bf  = (u16*)(ws + (size_t)(8u << 20));    // 24 MiB [3D][D] bf16
    u16* o_bf  = (u16*)(ws + (size_t)(32u << 20));   // 8 MiB  [D][D] bf16
    u16* qkv   = (u16*)(ws + (size_t)(40u << 20));   // 24 MiB [T][3D] bf16
    u16* q_bf  = (u16*)(ws + (size_t)(64u << 20));   // 8 MiB  [h][T][hd]
    u16* k_blk = (u16*)(ws + (size_t)(72u << 20));   // 8 MiB  blocked K
    u16* vt_bf = (u16*)(ws + (size_t)(80u << 20));   // 8 MiB  blocked V^T
    u16* x_bf  = (u16*)(ws + (size_t)(88u << 20));   // 8 MiB  [T][D]

    (void)hipFuncSetAttribute(reinterpret_cast<const void*>(&gemm256),
                              hipFuncAttributeMaxDynamicSharedMemorySize, 131072);
    (void)hipFuncSetAttribute(reinterpret_cast<const void*>(&attn_fwd),
                              hipFuncAttributeMaxDynamicSharedMemorySize, 131072);

    cast_both<<<8192, 256, 0, stream>>>(w_qkv, w_o, w_bf, o_bf);
    rmsnorm_row<<<2048, 256, 0, stream>>>(x_in, xn);
    gemm256<<<dim3(24, 8), 512, 131072, stream>>>(xn, w_bf, qkv, 2048, 6144, 2048);
    rope_split<<<2048, 256, 0, stream>>>(qkv, cosb, sinb, q_bf, k_blk, k_out, v_out);
    vtrans<<<2048, 256, 0, stream>>>(qkv, vt_bf);
    attn_fwd<<<512, 256, 131072, stream>>>(q_bf, k_blk, vt_bf, x_bf);
    gemm_bt<<<dim3(16, 16), 256, 0, stream>>>(x_bf, o_bf, out, x_in, 2048, 2048, 2048);
}

// Round 8
// 224.701 us; speedup vs baseline: 1.0628x; 1.0628x over previous
//
#include <hip/hip_runtime.h>
#include <hip/hip_bf16.h>

typedef unsigned short u16;
typedef unsigned int u32;
typedef __bf16 bf16x8 __attribute__((ext_vector_type(8)));
typedef u16 u16x8 __attribute__((ext_vector_type(8)));
typedef u16 u16x4 __attribute__((ext_vector_type(4)));
typedef float f32x4 __attribute__((ext_vector_type(4)));
typedef float f32x16 __attribute__((ext_vector_type(16)));

#define T_SEQ 2048
#define DMODEL 2048
#define NHEAD 16
#define HDIM 128
#define ATT_SCALE 0.08838834764831843f

__device__ __forceinline__ u16 f2bf(float f) {
    return __builtin_bit_cast(u16, __float2bfloat16(f));
}
__device__ __forceinline__ bf16x8 as_bf(u16x8 v) {
    return __builtin_bit_cast(bf16x8, v);
}
__device__ __forceinline__ float lo2f(u32 w) { return __builtin_bit_cast(float, w << 16); }
__device__ __forceinline__ float hi2f(u32 w) { return __builtin_bit_cast(float, w & 0xffff0000u); }
__device__ __forceinline__ void gload_lds16(const u16* g, u16* l) {
    __builtin_amdgcn_global_load_lds(
        (const __attribute__((address_space(1))) u32*)(g),
        (__attribute__((address_space(3))) u32*)(l), 16, 0, 0);
}

// ---------------- fused weight casts fp32 -> bf16 ----------------
__global__ __launch_bounds__(256) void cast_both(const float* __restrict__ w1,
                                                 const float* __restrict__ w2,
                                                 u16* __restrict__ d1,
                                                 u16* __restrict__ d2) {
    int i = blockIdx.x * 256 + threadIdx.x;
    const float* src; u16* dst; int k;
    if (i < 1572864) { src = w1; dst = d1; k = i; }
    else             { src = w2; dst = d2; k = i - 1572864; }
    float4 a = ((const float4*)src)[2 * k];
    float4 b = ((const float4*)src)[2 * k + 1];
    u16x8 o;
    o[0] = f2bf(a.x); o[1] = f2bf(a.y); o[2] = f2bf(a.z); o[3] = f2bf(a.w);
    o[4] = f2bf(b.x); o[5] = f2bf(b.y); o[6] = f2bf(b.z); o[7] = f2bf(b.w);
    *(u16x8*)(dst + (size_t)k * 8) = o;
}

// ---------------- row RMSNorm over D=2048, write bf16 ----------------
__global__ __launch_bounds__(256) void rmsnorm_row(const float* __restrict__ x,
                                                   u16* __restrict__ xn) {
    const int row = blockIdx.x, tid = threadIdx.x;
    const float* xr = x + (size_t)row * DMODEL;
    float4 a = ((const float4*)xr)[2 * tid];
    float4 b = ((const float4*)xr)[2 * tid + 1];
    float ss = a.x*a.x + a.y*a.y + a.z*a.z + a.w*a.w
             + b.x*b.x + b.y*b.y + b.z*b.z + b.w*b.w;
#pragma unroll
    for (int off = 32; off; off >>= 1) ss += __shfl_xor(ss, off);
    __shared__ float red[4];
    if ((tid & 63) == 0) red[tid >> 6] = ss;
    __syncthreads();
    float tot = red[0] + red[1] + red[2] + red[3];
    float r = rsqrtf(tot * (1.f / DMODEL) + 1e-6f);
    u16x8 o;
    o[0] = f2bf(a.x*r); o[1] = f2bf(a.y*r); o[2] = f2bf(a.z*r); o[3] = f2bf(a.w*r);
    o[4] = f2bf(b.x*r); o[5] = f2bf(b.y*r); o[6] = f2bf(b.z*r); o[7] = f2bf(b.w*r);
    *(u16x8*)(xn + (size_t)row * DMODEL + tid * 8) = o;
}

// ---------------- 128x128 m97-style GEMM (out-proj, fp32 C + resid) --------
__global__ __launch_bounds__(256) void gemm_bt(const u16* __restrict__ A,
                                               const u16* __restrict__ B,
                                               float* __restrict__ C,
                                               const float* __restrict__ resid,
                                               int M, int N, int K) {
    __shared__ u16 As[128 * 32];
    __shared__ u16 Bs[128 * 32];
    const int bm = blockIdx.y * 128, bn = blockIdx.x * 128;
    const int tid = threadIdx.x, lane = tid & 63, wid = tid >> 6;
    const int wr = (wid >> 1) * 64, wc = (wid & 1) * 64;
    const int fr = lane & 15, fc = (lane >> 4) * 8;

    f32x4 acc[4][4] = {};
    const int r0 = tid >> 2, c0 = (tid & 3) << 3;
    const u16* a0p = A + (size_t)(bm + r0) * K + c0;
    const u16* a1p = A + (size_t)(bm + r0 + 64) * K + c0;
    const u16* b0p = B + (size_t)(bn + r0) * K + c0;
    const u16* b1p = B + (size_t)(bn + r0 + 64) * K + c0;
    u16* la0 = As + (size_t)tid * 8;
    u16* la1 = As + (size_t)(tid + 256) * 8;
    u16* lb0 = Bs + (size_t)tid * 8;
    u16* lb1 = Bs + (size_t)(tid + 256) * 8;

    for (int k0 = 0; k0 < K; k0 += 32) {
        gload_lds16(a0p + k0, la0);
        gload_lds16(a1p + k0, la1);
        gload_lds16(b0p + k0, lb0);
        gload_lds16(b1p + k0, lb1);
        __syncthreads();

        u16x8 af[4], bfm[4];
#pragma unroll
        for (int m = 0; m < 4; ++m)
            af[m] = *(const u16x8*)&As[(wr + m * 16 + fr) * 32 + fc];
#pragma unroll
        for (int n = 0; n < 4; ++n)
            bfm[n] = *(const u16x8*)&Bs[(wc + n * 16 + fr) * 32 + fc];
#pragma unroll
        for (int m = 0; m < 4; ++m)
#pragma unroll
            for (int n = 0; n < 4; ++n)
                acc[m][n] = __builtin_amdgcn_mfma_f32_16x16x32_bf16(
                    as_bf(af[m]), as_bf(bfm[n]), acc[m][n], 0, 0, 0);
        __syncthreads();
    }

#pragma unroll
    for (int m = 0; m < 4; ++m)
#pragma unroll
        for (int n = 0; n < 4; ++n)
#pragma unroll
            for (int r = 0; r < 4; ++r) {
                int row = bm + wr + m * 16 + (lane >> 4) * 4 + r;
                int col = bn + wc + n * 16 + fr;
                float val = acc[m][n][r];
                if (resid) val += resid[(size_t)row * N + col];
                C[(size_t)row * N + col] = val;
            }
}

// ---------------- 256x256 8-phase GEMM, 32x32x16 MFMA + gray-code reuse ----
// Same staging / phase / vmcnt structure as round 6 (ledger unchanged); only
// the fragment reads + MFMA cluster moved to 32x32x16 (v3-verified layouts:
// A row=l31 k=hi*8+j ; C row=(r&3)+8(r>>2)+4hi col=l31).
#define VM4 asm volatile("s_waitcnt vmcnt(4)" ::: "memory");
#define VM0 asm volatile("s_waitcnt vmcnt(0)" ::: "memory");

#define LDA32(BUF, MH)                                                        \
  _Pragma("unroll") for (int mq = 0; mq < 2; ++mq) {                          \
    int ra = wr + (MH) * 64 + mq * 32 + l31;                                  \
    int sw = ra & 7;                                                          \
    _Pragma("unroll") for (int ks = 0; ks < 4; ++ks)                          \
      av32[mq][ks] = *(const u16x8*)(sA[BUF] + ra * 64 +                      \
                                     ((((ks << 1) | hi) ^ sw) << 3));         \
  }

#define LDB32(BUF, NH)                                                        \
  {                                                                           \
    int rb = wc + (NH) * 32 + l31;                                            \
    int sw = rb & 7;                                                          \
    _Pragma("unroll") for (int ks = 0; ks < 4; ++ks)                          \
      bv32[ks] = *(const u16x8*)(sB[BUF] + rb * 64 +                          \
                                 ((((ks << 1) | hi) ^ sw) << 3));             \
  }

#define MFMAQ32(MH, NH)                                                       \
  __builtin_amdgcn_s_barrier();                                               \
  __builtin_amdgcn_s_setprio(1);                                              \
  _Pragma("unroll") for (int ks = 0; ks < 4; ++ks)                            \
    _Pragma("unroll") for (int mq = 0; mq < 2; ++mq)                          \
      acc32[(MH) * 2 + mq][NH] = __builtin_amdgcn_mfma_f32_32x32x16_bf16(     \
          as_bf(av32[mq][ks]), as_bf(bv32[ks]), acc32[(MH) * 2 + mq][NH],     \
          0, 0, 0);                                                           \
  __builtin_amdgcn_s_setprio(0);

#define ENDP                                                                  \
  __builtin_amdgcn_s_barrier();                                               \
  __builtin_amdgcn_sched_barrier(0);

__global__ __launch_bounds__(512) void gemm256(const u16* __restrict__ A,
                                               const u16* __restrict__ B,
                                               u16* __restrict__ C,
                                               int M, int N, int K) {
    extern __shared__ char smem[];
    const int tid = threadIdx.x, lane = tid & 63, wid = tid >> 6;
    const int bm = blockIdx.y * 256, bn = blockIdx.x * 256;
    const int wr = (wid >> 2) * 128, wc = (wid & 3) * 64;
    const int l31 = lane & 31, hi = lane >> 5;

    u16* sA[2] = {(u16*)smem, (u16*)(smem + 65536)};
    u16* sB[2] = {(u16*)(smem + 32768), (u16*)(smem + 98304)};

    const int cs = (((tid & 7) ^ ((tid >> 3) & 7)) << 3);
    const int s8 = (tid & 7) << 3;
    const int rr6 = tid >> 3;
    const int rb0 = ((tid >> 8) << 6) + ((tid >> 3) & 31);

    auto stA = [&](int buf, int k0, int mh) {
#pragma unroll
        for (int j = 0; j < 2; ++j) {
            int r = j * 128 + mh * 64 + rr6;
            gload_lds16(A + (size_t)(bm + r) * K + k0 + cs, sA[buf] + r * 64 + s8);
        }
    };
    auto stB = [&](int buf, int k0, int nh) {
#pragma unroll
        for (int j = 0; j < 2; ++j) {
            int r = j * 128 + nh * 32 + rb0;
            gload_lds16(B + (size_t)(bn + r) * K + k0 + cs, sB[buf] + r * 64 + s8);
        }
    };

    f32x16 acc32[4][2] = {};
    u16x8 av32[2][4], bv32[4];
    const int nt = K >> 6;

    stA(0, 0, 0); stA(0, 0, 1); stB(0, 0, 0); stB(0, 0, 1);
    stA(1, 64, 0); stB(1, 64, 1);
    VM4
    __builtin_amdgcn_s_barrier();
    __builtin_amdgcn_sched_barrier(0);

    for (int it = 0; it < (nt >> 1); ++it) {
        const int kc = it << 7;
        const int kn1 = kc + 64, kn2 = kc + 128, kn3 = kc + 192;
        const bool st2 = (kn2 < K), st3 = (kn3 < K);

        // P1 (buf0; 0,0)  stage buf1-A1(kn1) [last read prev-P7]
        LDA32(0, 0) LDB32(0, 0)
        stA(1, kn1, 1);
        MFMAQ32(0, 0) ENDP
        // P2 (buf0; 0,1)  stage buf1-B0(kn1) [last read prev-P8]
        LDB32(0, 1)
        stB(1, kn1, 0);
        MFMAQ32(0, 1) ENDP
        // P3 (buf0; 1,1)  stage buf0-A0(kn2) [last read P1]
        LDA32(0, 1)
        if (st2) stA(0, kn2, 0);
        MFMAQ32(1, 1) ENDP
        // P4 (buf0; 1,0)  stage buf0-B1(kn2) [last read P2]
        LDB32(0, 0)
        if (st2) stB(0, kn2, 1);
        MFMAQ32(1, 0)
        if (st2) { VM4 } else { VM0 }
        ENDP
        // P5 (buf1; 0,0)  stage buf0-A1(kn2) [last read P3]
        LDA32(1, 0) LDB32(1, 0)
        if (st2) stA(0, kn2, 1);
        MFMAQ32(0, 0) ENDP
        // P6 (buf1; 0,1)  stage buf0-B0(kn2) [last read P4]
        LDB32(1, 1)
        if (st2) stB(0, kn2, 0);
        MFMAQ32(0, 1) ENDP
        // P7 (buf1; 1,1)  stage buf1-A0(kn3) [last read P5]
        LDA32(1, 1)
        if (st3) stA(1, kn3, 0);
        MFMAQ32(1, 1) ENDP
        // P8 (buf1; 1,0)  stage buf1-B1(kn3) [last read P6]
        LDB32(1, 0)
        if (st3) stB(1, kn3, 1);
        MFMAQ32(1, 0)
        VM4
        ENDP
    }

#pragma unroll
    for (int am = 0; am < 4; ++am)
#pragma unroll
        for (int bq = 0; bq < 2; ++bq)
#pragma unroll
            for (int r = 0; r < 16; ++r) {
                int row = bm + wr + am * 32 + (r & 3) + 8 * (r >> 2) + 4 * hi;
                int col = bn + wc + bq * 32 + l31;
                C[(size_t)row * N + col] = f2bf(acc32[am][bq][r]);
            }
}

// ---------------- per-head RMSNorm + RoPE (vectorized, bf16 qkv) -----------
__global__ __launch_bounds__(256) void rope_split(const u16* __restrict__ qkv,
                                                  const float* __restrict__ cosb,
                                                  const float* __restrict__ sinb,
                                                  u16* __restrict__ q_bf,
                                                  u16* __restrict__ k_bf,
                                                  float* __restrict__ k_out,
                                                  float* __restrict__ v_out) {
    const int t = blockIdx.x, tid = threadIdx.x, wid = tid >> 6, lane = tid & 63;
    const u16* row = qkv + (size_t)t * (3 * DMODEL);
    const int dp = (lane & 31) << 1;
    float2 c2 = *(const float2*)(cosb + t * 64 + dp);
    float2 s2 = *(const float2*)(sinb + t * 64 + dp);
    const bool hi = lane >= 32;

    for (int task = wid; task < 32; task += 4) {
        u32 w = *(const u32*)(row + task * 128 + lane * 2);
        float xa = lo2f(w), xb = hi2f(w);
        float ss = xa * xa + xb * xb;
#pragma unroll
        for (int off = 32; off; off >>= 1) ss += __shfl_xor(ss, off);
        float rn = rsqrtf(ss * (1.f / 128.f) + 1e-6f);
        float pa = __shfl_xor(xa, 32), pb = __shfl_xor(xb, 32);
        float oa, ob;
        if (!hi) {
            oa = (xa * c2.x - pa * s2.x) * rn;
            ob = (xb * c2.y - pb * s2.y) * rn;
        } else {
            oa = (pa * s2.x + xa * c2.x) * rn;
            ob = (pb * s2.y + xb * c2.y) * rn;
        }
        u32 pk = (u32)f2bf(oa) | ((u32)f2bf(ob) << 16);
        if (task < 16) {
            *(u32*)(q_bf + ((size_t)task * T_SEQ + t) * 128 + lane * 2) = pk;
        } else {
            int hh = task - 16;
            *(u32*)(k_bf + ((size_t)hh * T_SEQ + t) * 128 + lane * 2) = pk;
            float2 kk; kk.x = oa; kk.y = ob;
            *(float2*)(k_out + (size_t)t * DMODEL + hh * 128 + lane * 2) = kk;
        }
    }
    {
        u16x8 vv = *(const u16x8*)(row + 2 * DMODEL + tid * 8);
        float4 f0, f1;
        f0.x = __builtin_bit_cast(float, (u32)vv[0] << 16);
        f0.y = __builtin_bit_cast(float, (u32)vv[1] << 16);
        f0.z = __builtin_bit_cast(float, (u32)vv[2] << 16);
        f0.w = __builtin_bit_cast(float, (u32)vv[3] << 16);
        f1.x = __builtin_bit_cast(float, (u32)vv[4] << 16);
        f1.y = __builtin_bit_cast(float, (u32)vv[5] << 16);
        f1.z = __builtin_bit_cast(float, (u32)vv[6] << 16);
        f1.w = __builtin_bit_cast(float, (u32)vv[7] << 16);
        *(float4*)(v_out + (size_t)t * DMODEL + tid * 8) = f0;
        *(float4*)(v_out + (size_t)t * DMODEL + tid * 8 + 4) = f1;
    }
}

// ---------------- V transpose: qkv bf16 -> vt bf16 [h][128][T] -------------
__global__ __launch_bounds__(256) void vtrans(const u16* __restrict__ qkv,
                                              u16* __restrict__ vt) {
    const int b = blockIdx.x, tid = threadIdx.x;
    const int head = b >> 7;
    const int i = (b & 127) * 256 + tid;
    const int d = i & 127, tc = i >> 7;
    u16x8 o;
#pragma unroll
    for (int j = 0; j < 8; ++j)
        o[j] = qkv[(size_t)(tc * 8 + j) * (3 * DMODEL) + 2 * DMODEL + head * 128 + d];
    *(u16x8*)&vt[((size_t)head * 128 + d) * T_SEQ + tc * 8] = o;
}

// ---------------- causal flash attention (round-6 version) -----------------
__global__ __launch_bounds__(256) void attn_fwd(const u16* __restrict__ qb,
                                                const u16* __restrict__ kb,
                                                const u16* __restrict__ vtb,
                                                u16* __restrict__ xout) {
    __shared__ u16 Ks[2][64 * 128];
    __shared__ u16 Vs[2][128 * 64];
    __shared__ u16 Ps[4][16 * 64];

    const int bid = blockIdx.x;
    const int r8 = bid & 7, s = bid >> 3;
    const int head = r8 + ((s >> 5) << 3);
    const int j = s & 31;
    const int qt = (s < 32) ? (31 - j) : j;

    const int tid = threadIdx.x, wid = tid >> 6, lane = tid & 63;
    const int fr = lane & 15, fg = lane >> 4;
    const u16* kh = kb + (size_t)head * T_SEQ * 128;
    const u16* vth = vtb + (size_t)head * 128 * T_SEQ;
    const u16* qh = qb + (size_t)head * T_SEQ * 128;
    const int q0 = qt * 64 + wid * 16;
    const int qrow_g = q0 + fr;

    u16x8 bq[4];
    {
        const u16* qrow = qh + (size_t)(q0 + fr) * 128 + fg * 8;
#pragma unroll
        for (int cc = 0; cc < 4; ++cc) bq[cc] = *(const u16x8*)(qrow + cc * 32);
    }

    auto stage = [&](int kv0, int buf) {
#pragma unroll
        for (int i = 0; i < 4; ++i) {
            int idx = i * 256 + tid;
            int r = idx >> 4;
            int cbs = ((idx & 15) << 4) ^ ((r & 7) << 4);
            gload_lds16(kh + (size_t)(kv0 + r) * 128 + (cbs >> 1), &Ks[buf][idx * 8]);
        }
#pragma unroll
        for (int i = 0; i < 4; ++i) {
            int idx = i * 256 + tid;
            int d = idx >> 3;
            int cbs = ((idx & 7) << 4) ^ ((d & 7) << 4);
            gload_lds16(vth + (size_t)d * T_SEQ + kv0 + (cbs >> 1), &Vs[buf][idx * 8]);
        }
    };

    stage(0, 0);

    f32x4 o[8] = {};
    float m_run = -1e30f, l_run = 0.f;
    const int nt = qt + 1;

    for (int kt = 0; kt < nt; ++kt) {
        const int kv0 = kt * 64;
        const int buf = kt & 1;
        if (kt + 1 < nt) {
            stage(kv0 + 64, buf ^ 1);
            asm volatile("s_waitcnt vmcnt(8)" ::: "memory");
        } else {
            asm volatile("s_waitcnt vmcnt(0)" ::: "memory");
        }
        __builtin_amdgcn_s_barrier();
        __builtin_amdgcn_sched_barrier(0);

        const char* ksb = (const char*)&Ks[buf][0];
        const char* vsb = (const char*)&Vs[buf][0];
        char* psb = (char*)&Ps[wid][0];

        float p[4][4];
        float mx = -1e30f;
        const bool diag = (kv0 + 64 > q0);
#pragma unroll
        for (int st = 0; st < 4; ++st) {
            f32x4 sacc = {0.f, 0.f, 0.f, 0.f};
#pragma unroll
            for (int c4 = 0; c4 < 4; ++c4) {
                int r = st * 16 + fr;
                int cb = c4 * 64 + fg * 16;
                u16x8 ak = *(const u16x8*)(ksb + r * 256 + (cb ^ ((r & 7) << 4)));
                sacc = __builtin_amdgcn_mfma_f32_16x16x32_bf16(
                    as_bf(ak), as_bf(bq[c4]), sacc, 0, 0, 0);
            }
#pragma unroll
            for (int rr = 0; rr < 4; ++rr) {
                float sv = sacc[rr] * ATT_SCALE;
                if (diag) {
                    int kvg = kv0 + st * 16 + fg * 4 + rr;
                    sv = (kvg <= qrow_g) ? sv : -1e30f;
                }
                p[st][rr] = sv;
                mx = fmaxf(mx, sv);
            }
        }
        mx = fmaxf(mx, __shfl_xor(mx, 16));
        mx = fmaxf(mx, __shfl_xor(mx, 32));

        if (__all(mx - m_run <= 8.f)) {
            float rs = 0.f;
#pragma unroll
            for (int st = 0; st < 4; ++st) {
                u16x4 pw;
#pragma unroll
                for (int rr = 0; rr < 4; ++rr) {
                    float e = __expf(p[st][rr] - m_run);
                    rs += e;
                    pw[rr] = f2bf(e);
                }
                *(u16x4*)(psb + fr * 128 + ((st * 32 + fg * 8) ^ ((fr & 7) << 4))) = pw;
            }
            rs += __shfl_xor(rs, 16);
            rs += __shfl_xor(rs, 32);
            l_run += rs;
        } else {
            float m_new = fmaxf(m_run, mx);
            float corr = __expf(m_run - m_new);
            float rs = 0.f;
#pragma unroll
            for (int st = 0; st < 4; ++st) {
                u16x4 pw;
#pragma unroll
                for (int rr = 0; rr < 4; ++rr) {
                    float e = __expf(p[st][rr] - m_new);
                    rs += e;
                    pw[rr] = f2bf(e);
                }
                *(u16x4*)(psb + fr * 128 + ((st * 32 + fg * 8) ^ ((fr & 7) << 4))) = pw;
            }
            rs += __shfl_xor(rs, 16);
            rs += __shfl_xor(rs, 32);
            l_run = l_run * corr + rs;
            m_run = m_new;
            float ct[4];
#pragma unroll
            for (int rr = 0; rr < 4; ++rr) ct[rr] = __shfl(corr, fg * 4 + rr);
#pragma unroll
            for (int f = 0; f < 8; ++f)
#pragma unroll
                for (int rr = 0; rr < 4; ++rr) o[f][rr] *= ct[rr];
        }

#pragma unroll
        for (int ks = 0; ks < 2; ++ks) {
            u16x8 pa = *(const u16x8*)(psb + fr * 128 + ((ks * 64 + fg * 16) ^ ((fr & 7) << 4)));
#pragma unroll
            for (int f = 0; f < 8; ++f) {
                int d = f * 16 + fr;
                u16x8 vB = *(const u16x8*)(vsb + d * 128 + ((ks * 64 + fg * 16) ^ ((d & 7) << 4)));
                o[f] = __builtin_amdgcn_mfma_f32_16x16x32_bf16(
                    as_bf(pa), as_bf(vB), o[f], 0, 0, 0);
            }
        }
        __builtin_amdgcn_s_barrier();
    }

    float li[4];
#pragma unroll
    for (int rr = 0; rr < 4; ++rr) li[rr] = __shfl(l_run, fg * 4 + rr);
#pragma unroll
    for (int f = 0; f < 8; ++f)
#pragma unroll
        for (int rr = 0; rr < 4; ++rr) {
            int trow = q0 + fg * 4 + rr;
            float val = o[f][rr] / li[rr];
            xout[(size_t)trow * DMODEL + head * 128 + f * 16 + fr] = f2bf(val);
        }
}

extern "C" void kernel_launch(void* const* d_in, const int* in_sizes, int n_in,
                              void* d_out, int out_size, void* d_ws, size_t ws_size,
                              hipStream_t stream) {
    const float* x_in = (const float*)d_in[0];
    const float* w_qkv = (const float*)d_in[1];
    const float* w_o = (const float*)d_in[2];
    const float* cosb = (const float*)d_in[3];
    const float* sinb = (const float*)d_in[4];

    float* out = (float*)d_out;
    float* k_out = out + 4194304;
    float* v_out = out + 8388608;

    char* ws = (char*)d_ws;
    u16* xn    = (u16*)(ws);                         // 8 MiB  [T][D] bf16
    u16* w_bf  = (u16*)(ws + (size_t)(8u << 20));    // 24 MiB [3D][D] bf16
    u16* o_bf  = (u16*)(ws + (size_t)(32u << 20));   // 8 MiB  [D][D] bf16
    u16* qkv   = (u16*)(ws + (size_t)(40u << 20));   // 24 MiB [T][3D] bf16
    u16* q_bf  = (u16*)(ws + (size_t)(64u << 20));   // 8 MiB  [h][T][hd]
    u16* k_bf  = (u16*)(ws + (size_t)(72u << 20));   // 8 MiB
    u16* vt_bf = (u16*)(ws + (size_t)(80u << 20));   // 8 MiB  [h][hd][T]
    u16* x_bf  = (u16*)(ws + (size_t)(88u << 20));   // 8 MiB  [T][D]

    (void)hipFuncSetAttribute(reinterpret_cast<const void*>(&gemm256),
                              hipFuncAttributeMaxDynamicSharedMemorySize, 131072);

    cast_both<<<8192, 256, 0, stream>>>(w_qkv, w_o, w_bf, o_bf);
    rmsnorm_row<<<2048, 256, 0, stream>>>(x_in, xn);
    gemm256<<<dim3(24, 8), 512, 131072, stream>>>(xn, w_bf, qkv, 2048, 6144, 2048);
    rope_split<<<2048, 256, 0, stream>>>(qkv, cosb, sinb, q_bf, k_bf, k_out, v_out);
    vtrans<<<2048, 256, 0, stream>>>(qkv, vt_bf);
    attn_fwd<<<512, 256, 0, stream>>>(q_bf, k_bf, vt_bf, x_bf);
    gemm_bt<<<dim3(16, 16), 256, 0, stream>>>(x_bf, o_bf, out, x_in, 2048, 2048, 2048);
}

// Round 9
// 189.083 us; speedup vs baseline: 1.2630x; 1.1884x over previous
//
#include <hip/hip_runtime.h>
#include <hip/hip_bf16.h>

typedef unsigned short u16;
typedef unsigned int u32;
typedef __bf16 bf16x8 __attribute__((ext_vector_type(8)));
typedef u16 u16x8 __attribute__((ext_vector_type(8)));
typedef u16 u16x4 __attribute__((ext_vector_type(4)));
typedef float f32x4 __attribute__((ext_vector_type(4)));

#define T_SEQ 2048
#define DMODEL 2048
#define NHEAD 16
#define HDIM 128
#define ATT_SCALE 0.08838834764831843f

__device__ __forceinline__ u16 f2bf(float f) {
    return __builtin_bit_cast(u16, __float2bfloat16(f));
}
__device__ __forceinline__ bf16x8 as_bf(u16x8 v) {
    return __builtin_bit_cast(bf16x8, v);
}
__device__ __forceinline__ float lo2f(u32 w) { return __builtin_bit_cast(float, w << 16); }
__device__ __forceinline__ float hi2f(u32 w) { return __builtin_bit_cast(float, w & 0xffff0000u); }
__device__ __forceinline__ void gload_lds16(const u16* g, u16* l) {
    __builtin_amdgcn_global_load_lds(
        (const __attribute__((address_space(1))) u32*)(g),
        (__attribute__((address_space(3))) u32*)(l), 16, 0, 0);
}

// ---------------- fused weight casts fp32 -> bf16 ----------------
__global__ __launch_bounds__(256) void cast_both(const float* __restrict__ w1,
                                                 const float* __restrict__ w2,
                                                 u16* __restrict__ d1,
                                                 u16* __restrict__ d2) {
    int i = blockIdx.x * 256 + threadIdx.x;
    const float* src; u16* dst; int k;
    if (i < 1572864) { src = w1; dst = d1; k = i; }
    else             { src = w2; dst = d2; k = i - 1572864; }
    float4 a = ((const float4*)src)[2 * k];
    float4 b = ((const float4*)src)[2 * k + 1];
    u16x8 o;
    o[0] = f2bf(a.x); o[1] = f2bf(a.y); o[2] = f2bf(a.z); o[3] = f2bf(a.w);
    o[4] = f2bf(b.x); o[5] = f2bf(b.y); o[6] = f2bf(b.z); o[7] = f2bf(b.w);
    *(u16x8*)(dst + (size_t)k * 8) = o;
}

// ---------------- row RMSNorm over D=2048, write bf16 ----------------
__global__ __launch_bounds__(256) void rmsnorm_row(const float* __restrict__ x,
                                                   u16* __restrict__ xn) {
    const int row = blockIdx.x, tid = threadIdx.x;
    const float* xr = x + (size_t)row * DMODEL;
    float4 a = ((const float4*)xr)[2 * tid];
    float4 b = ((const float4*)xr)[2 * tid + 1];
    float ss = a.x*a.x + a.y*a.y + a.z*a.z + a.w*a.w
             + b.x*b.x + b.y*b.y + b.z*b.z + b.w*b.w;
#pragma unroll
    for (int off = 32; off; off >>= 1) ss += __shfl_xor(ss, off);
    __shared__ float red[4];
    if ((tid & 63) == 0) red[tid >> 6] = ss;
    __syncthreads();
    float tot = red[0] + red[1] + red[2] + red[3];
    float r = rsqrtf(tot * (1.f / DMODEL) + 1e-6f);
    u16x8 o;
    o[0] = f2bf(a.x*r); o[1] = f2bf(a.y*r); o[2] = f2bf(a.z*r); o[3] = f2bf(a.w*r);
    o[4] = f2bf(b.x*r); o[5] = f2bf(b.y*r); o[6] = f2bf(b.z*r); o[7] = f2bf(b.w*r);
    *(u16x8*)(xn + (size_t)row * DMODEL + tid * 8) = o;
}

// ================= shared 8-phase GEMM machinery ===========================
#define VM4 asm volatile("s_waitcnt vmcnt(4)" ::: "memory");
#define VM0 asm volatile("s_waitcnt vmcnt(0)" ::: "memory");

#define ENDP                                                                  \
  __builtin_amdgcn_s_barrier();                                               \
  __builtin_amdgcn_sched_barrier(0);

// ---- 256x256 variant (round-6 verified: 16x16 MFMA, 0 conflicts) ----
#define LDA(BUF, MH)                                                          \
  _Pragma("unroll") for (int mq = 0; mq < 4; ++mq) {                          \
    int ra = wr + (MH) * 64 + mq * 16 + fr;                                   \
    int sw = ra & 7;                                                          \
    _Pragma("unroll") for (int k2 = 0; k2 < 2; ++k2)                          \
      av[mq][k2] = *(const u16x8*)(sA[BUF] + ra * 64 +                        \
                                   ((((k2 << 2) | fg) ^ sw) << 3));           \
  }

#define LDB(BUF, NH)                                                          \
  _Pragma("unroll") for (int nq = 0; nq < 2; ++nq) {                          \
    int rb = wc + (NH) * 32 + nq * 16 + fr;                                   \
    int sw = rb & 7;                                                          \
    _Pragma("unroll") for (int k2 = 0; k2 < 2; ++k2)                          \
      bv[nq][k2] = *(const u16x8*)(sB[BUF] + rb * 64 +                        \
                                   ((((k2 << 2) | fg) ^ sw) << 3));           \
  }

#define MFMAQ(MH, NH)                                                         \
  __builtin_amdgcn_s_barrier();                                               \
  __builtin_amdgcn_s_setprio(1);                                              \
  _Pragma("unroll") for (int k2 = 0; k2 < 2; ++k2)                            \
    _Pragma("unroll") for (int mq = 0; mq < 4; ++mq)                          \
      _Pragma("unroll") for (int nq = 0; nq < 2; ++nq)                        \
        acc[(MH) * 4 + mq][(NH) * 2 + nq] =                                   \
            __builtin_amdgcn_mfma_f32_16x16x32_bf16(                          \
                as_bf(av[mq][k2]), as_bf(bv[nq][k2]),                         \
                acc[(MH) * 4 + mq][(NH) * 2 + nq], 0, 0, 0);                  \
  __builtin_amdgcn_s_setprio(0);

__global__ __launch_bounds__(512) void gemm256(const u16* __restrict__ A,
                                               const u16* __restrict__ B,
                                               u16* __restrict__ C,
                                               int M, int N, int K) {
    extern __shared__ char smem[];
    const int tid = threadIdx.x, lane = tid & 63, wid = tid >> 6;
    const int bm = blockIdx.y * 256, bn = blockIdx.x * 256;
    const int wr = (wid >> 2) * 128, wc = (wid & 3) * 64;
    const int fr = lane & 15, fg = lane >> 4;

    u16* sA[2] = {(u16*)smem, (u16*)(smem + 65536)};
    u16* sB[2] = {(u16*)(smem + 32768), (u16*)(smem + 98304)};

    const int cs = (((tid & 7) ^ ((tid >> 3) & 7)) << 3);
    const int s8 = (tid & 7) << 3;
    const int rr6 = tid >> 3;
    const int rb0 = ((tid >> 8) << 6) + ((tid >> 3) & 31);

    auto stA = [&](int buf, int k0, int mh) {
#pragma unroll
        for (int j = 0; j < 2; ++j) {
            int r = j * 128 + mh * 64 + rr6;
            gload_lds16(A + (size_t)(bm + r) * K + k0 + cs, sA[buf] + r * 64 + s8);
        }
    };
    auto stB = [&](int buf, int k0, int nh) {
#pragma unroll
        for (int j = 0; j < 2; ++j) {
            int r = j * 128 + nh * 32 + rb0;
            gload_lds16(B + (size_t)(bn + r) * K + k0 + cs, sB[buf] + r * 64 + s8);
        }
    };

    f32x4 acc[8][4] = {};
    u16x8 av[4][2], bv[2][2];
    const int nt = K >> 6;

    stA(0, 0, 0); stA(0, 0, 1); stB(0, 0, 0); stB(0, 0, 1);
    stA(1, 64, 0); stB(1, 64, 1);
    VM4
    __builtin_amdgcn_s_barrier();
    __builtin_amdgcn_sched_barrier(0);

    for (int it = 0; it < (nt >> 1); ++it) {
        const int kc = it << 7;
        const int kn1 = kc + 64, kn2 = kc + 128, kn3 = kc + 192;
        const bool st2 = (kn2 < K), st3 = (kn3 < K);

        LDA(0, 0) LDB(0, 0)
        stA(1, kn1, 1);
        MFMAQ(0, 0) ENDP
        LDB(0, 1)
        stB(1, kn1, 0);
        MFMAQ(0, 1) ENDP
        LDA(0, 1)
        if (st2) stA(0, kn2, 0);
        MFMAQ(1, 1) ENDP
        LDB(0, 0)
        if (st2) stB(0, kn2, 1);
        MFMAQ(1, 0)
        if (st2) { VM4 } else { VM0 }
        ENDP
        LDA(1, 0) LDB(1, 0)
        if (st2) stA(0, kn2, 1);
        MFMAQ(0, 0) ENDP
        LDB(1, 1)
        if (st2) stB(0, kn2, 0);
        MFMAQ(0, 1) ENDP
        LDA(1, 1)
        if (st3) stA(1, kn3, 0);
        MFMAQ(1, 1) ENDP
        LDB(1, 0)
        if (st3) stB(1, kn3, 1);
        MFMAQ(1, 0)
        VM4
        ENDP
    }

#pragma unroll
    for (int am = 0; am < 8; ++am)
#pragma unroll
        for (int bq = 0; bq < 4; ++bq)
#pragma unroll
            for (int r = 0; r < 4; ++r) {
                int row = bm + wr + am * 16 + fg * 4 + r;
                int col = bn + wc + bq * 16 + fr;
                C[(size_t)row * N + col] = f2bf(acc[am][bq][r]);
            }
}

// ---- 128x128 variant for out-proj (same schedule, scaled; resid epilogue) --
#define LDAH(BUF, MH)                                                         \
  _Pragma("unroll") for (int mq = 0; mq < 2; ++mq) {                          \
    int ra = wr + (MH) * 32 + mq * 16 + fr;                                   \
    int sw = ra & 7;                                                          \
    _Pragma("unroll") for (int k2 = 0; k2 < 2; ++k2)                          \
      av[mq][k2] = *(const u16x8*)(sA[BUF] + ra * 64 +                        \
                                   ((((k2 << 2) | fg) ^ sw) << 3));           \
  }

#define LDBH(BUF, NH)                                                         \
  _Pragma("unroll") for (int nq = 0; nq < 2; ++nq) {                          \
    int rb = wc + (NH) * 32 + nq * 16 + fr;                                   \
    int sw = rb & 7;                                                          \
    _Pragma("unroll") for (int k2 = 0; k2 < 2; ++k2)                          \
      bv[nq][k2] = *(const u16x8*)(sB[BUF] + rb * 64 +                        \
                                   ((((k2 << 2) | fg) ^ sw) << 3));           \
  }

#define MFMAQH(MH, NH)                                                        \
  __builtin_amdgcn_s_barrier();                                               \
  __builtin_amdgcn_s_setprio(1);                                              \
  _Pragma("unroll") for (int k2 = 0; k2 < 2; ++k2)                            \
    _Pragma("unroll") for (int mq = 0; mq < 2; ++mq)                          \
      _Pragma("unroll") for (int nq = 0; nq < 2; ++nq)                        \
        acc[(MH) * 2 + mq][(NH) * 2 + nq] =                                   \
            __builtin_amdgcn_mfma_f32_16x16x32_bf16(                          \
                as_bf(av[mq][k2]), as_bf(bv[nq][k2]),                         \
                acc[(MH) * 2 + mq][(NH) * 2 + nq], 0, 0, 0);                  \
  __builtin_amdgcn_s_setprio(0);

__global__ __launch_bounds__(256) void gemm128(const u16* __restrict__ A,
                                               const u16* __restrict__ B,
                                               float* __restrict__ C,
                                               const float* __restrict__ resid,
                                               int M, int N, int K) {
    extern __shared__ char smem[];
    const int tid = threadIdx.x, lane = tid & 63, wid = tid >> 6;
    const int bm = blockIdx.y * 128, bn = blockIdx.x * 128;
    const int wr = (wid >> 1) * 64, wc = (wid & 1) * 64;
    const int fr = lane & 15, fg = lane >> 4;

    u16* sA[2] = {(u16*)smem, (u16*)(smem + 32768)};
    u16* sB[2] = {(u16*)(smem + 16384), (u16*)(smem + 49152)};

    const int cs = (((tid & 7) ^ ((tid >> 3) & 7)) << 3);
    const int s8 = (tid & 7) << 3;
    const int rr5 = tid >> 3;   // 0..31

    auto stA = [&](int buf, int k0, int mh) {
#pragma unroll
        for (int j = 0; j < 2; ++j) {
            int r = j * 64 + mh * 32 + rr5;
            gload_lds16(A + (size_t)(bm + r) * K + k0 + cs, sA[buf] + r * 64 + s8);
        }
    };
    auto stB = [&](int buf, int k0, int nh) {
#pragma unroll
        for (int j = 0; j < 2; ++j) {
            int r = j * 64 + nh * 32 + rr5;
            gload_lds16(B + (size_t)(bn + r) * K + k0 + cs, sB[buf] + r * 64 + s8);
        }
    };

    f32x4 acc[4][4] = {};
    u16x8 av[2][2], bv[2][2];
    const int nt = K >> 6;

    stA(0, 0, 0); stA(0, 0, 1); stB(0, 0, 0); stB(0, 0, 1);
    stA(1, 64, 0); stB(1, 64, 1);
    VM4
    __builtin_amdgcn_s_barrier();
    __builtin_amdgcn_sched_barrier(0);

    for (int it = 0; it < (nt >> 1); ++it) {
        const int kc = it << 7;
        const int kn1 = kc + 64, kn2 = kc + 128, kn3 = kc + 192;
        const bool st2 = (kn2 < K), st3 = (kn3 < K);

        LDAH(0, 0) LDBH(0, 0)
        stA(1, kn1, 1);
        MFMAQH(0, 0) ENDP
        LDBH(0, 1)
        stB(1, kn1, 0);
        MFMAQH(0, 1) ENDP
        LDAH(0, 1)
        if (st2) stA(0, kn2, 0);
        MFMAQH(1, 1) ENDP
        LDBH(0, 0)
        if (st2) stB(0, kn2, 1);
        MFMAQH(1, 0)
        if (st2) { VM4 } else { VM0 }
        ENDP
        LDAH(1, 0) LDBH(1, 0)
        if (st2) stA(0, kn2, 1);
        MFMAQH(0, 0) ENDP
        LDBH(1, 1)
        if (st2) stB(0, kn2, 0);
        MFMAQH(0, 1) ENDP
        LDAH(1, 1)
        if (st3) stA(1, kn3, 0);
        MFMAQH(1, 1) ENDP
        LDBH(1, 0)
        if (st3) stB(1, kn3, 1);
        MFMAQH(1, 0)
        VM4
        ENDP
    }

#pragma unroll
    for (int am = 0; am < 4; ++am)
#pragma unroll
        for (int bq = 0; bq < 4; ++bq)
#pragma unroll
            for (int r = 0; r < 4; ++r) {
                int row = bm + wr + am * 16 + fg * 4 + r;
                int col = bn + wc + bq * 16 + fr;
                float val = acc[am][bq][r] + resid[(size_t)row * N + col];
                C[(size_t)row * N + col] = val;
            }
}

// ---------------- per-head RMSNorm + RoPE (vectorized, bf16 qkv) -----------
__global__ __launch_bounds__(256) void rope_split(const u16* __restrict__ qkv,
                                                  const float* __restrict__ cosb,
                                                  const float* __restrict__ sinb,
                                                  u16* __restrict__ q_bf,
                                                  u16* __restrict__ k_bf,
                                                  float* __restrict__ k_out,
                                                  float* __restrict__ v_out) {
    const int t = blockIdx.x, tid = threadIdx.x, wid = tid >> 6, lane = tid & 63;
    const u16* row = qkv + (size_t)t * (3 * DMODEL);
    const int dp = (lane & 31) << 1;
    float2 c2 = *(const float2*)(cosb + t * 64 + dp);
    float2 s2 = *(const float2*)(sinb + t * 64 + dp);
    const bool hi = lane >= 32;

    for (int task = wid; task < 32; task += 4) {
        u32 w = *(const u32*)(row + task * 128 + lane * 2);
        float xa = lo2f(w), xb = hi2f(w);
        float ss = xa * xa + xb * xb;
#pragma unroll
        for (int off = 32; off; off >>= 1) ss += __shfl_xor(ss, off);
        float rn = rsqrtf(ss * (1.f / 128.f) + 1e-6f);
        float pa = __shfl_xor(xa, 32), pb = __shfl_xor(xb, 32);
        float oa, ob;
        if (!hi) {
            oa = (xa * c2.x - pa * s2.x) * rn;
            ob = (xb * c2.y - pb * s2.y) * rn;
        } else {
            oa = (pa * s2.x + xa * c2.x) * rn;
            ob = (pb * s2.y + xb * c2.y) * rn;
        }
        u32 pk = (u32)f2bf(oa) | ((u32)f2bf(ob) << 16);
        if (task < 16) {
            *(u32*)(q_bf + ((size_t)task * T_SEQ + t) * 128 + lane * 2) = pk;
        } else {
            int hh = task - 16;
            *(u32*)(k_bf + ((size_t)hh * T_SEQ + t) * 128 + lane * 2) = pk;
            float2 kk; kk.x = oa; kk.y = ob;
            *(float2*)(k_out + (size_t)t * DMODEL + hh * 128 + lane * 2) = kk;
        }
    }
    {
        u16x8 vv = *(const u16x8*)(row + 2 * DMODEL + tid * 8);
        float4 f0, f1;
        f0.x = __builtin_bit_cast(float, (u32)vv[0] << 16);
        f0.y = __builtin_bit_cast(float, (u32)vv[1] << 16);
        f0.z = __builtin_bit_cast(float, (u32)vv[2] << 16);
        f0.w = __builtin_bit_cast(float, (u32)vv[3] << 16);
        f1.x = __builtin_bit_cast(float, (u32)vv[4] << 16);
        f1.y = __builtin_bit_cast(float, (u32)vv[5] << 16);
        f1.z = __builtin_bit_cast(float, (u32)vv[6] << 16);
        f1.w = __builtin_bit_cast(float, (u32)vv[7] << 16);
        *(float4*)(v_out + (size_t)t * DMODEL + tid * 8) = f0;
        *(float4*)(v_out + (size_t)t * DMODEL + tid * 8 + 4) = f1;
    }
}

// ---------------- V transpose: qkv bf16 -> vt bf16 [h][128][T] -------------
__global__ __launch_bounds__(256) void vtrans(const u16* __restrict__ qkv,
                                              u16* __restrict__ vt) {
    const int b = blockIdx.x, tid = threadIdx.x;
    const int head = b >> 7;
    const int i = (b & 127) * 256 + tid;
    const int d = i & 127, tc = i >> 7;
    u16x8 o;
#pragma unroll
    for (int j = 0; j < 8; ++j)
        o[j] = qkv[(size_t)(tc * 8 + j) * (3 * DMODEL) + 2 * DMODEL + head * 128 + d];
    *(u16x8*)&vt[((size_t)head * 128 + d) * T_SEQ + tc * 8] = o;
}

// ---------------- causal flash attention (round-6 version) -----------------
__global__ __launch_bounds__(256) void attn_fwd(const u16* __restrict__ qb,
                                                const u16* __restrict__ kb,
                                                const u16* __restrict__ vtb,
                                                u16* __restrict__ xout) {
    __shared__ u16 Ks[2][64 * 128];
    __shared__ u16 Vs[2][128 * 64];
    __shared__ u16 Ps[4][16 * 64];

    const int bid = blockIdx.x;
    const int r8 = bid & 7, s = bid >> 3;
    const int head = r8 + ((s >> 5) << 3);
    const int j = s & 31;
    const int qt = (s < 32) ? (31 - j) : j;

    const int tid = threadIdx.x, wid = tid >> 6, lane = tid & 63;
    const int fr = lane & 15, fg = lane >> 4;
    const u16* kh = kb + (size_t)head * T_SEQ * 128;
    const u16* vth = vtb + (size_t)head * 128 * T_SEQ;
    const u16* qh = qb + (size_t)head * T_SEQ * 128;
    const int q0 = qt * 64 + wid * 16;
    const int qrow_g = q0 + fr;

    u16x8 bq[4];
    {
        const u16* qrow = qh + (size_t)(q0 + fr) * 128 + fg * 8;
#pragma unroll
        for (int cc = 0; cc < 4; ++cc) bq[cc] = *(const u16x8*)(qrow + cc * 32);
    }

    auto stage = [&](int kv0, int buf) {
#pragma unroll
        for (int i = 0; i < 4; ++i) {
            int idx = i * 256 + tid;
            int r = idx >> 4;
            int cbs = ((idx & 15) << 4) ^ ((r & 7) << 4);
            gload_lds16(kh + (size_t)(kv0 + r) * 128 + (cbs >> 1), &Ks[buf][idx * 8]);
        }
#pragma unroll
        for (int i = 0; i < 4; ++i) {
            int idx = i * 256 + tid;
            int d = idx >> 3;
            int cbs = ((idx & 7) << 4) ^ ((d & 7) << 4);
            gload_lds16(vth + (size_t)d * T_SEQ + kv0 + (cbs >> 1), &Vs[buf][idx * 8]);
        }
    };

    stage(0, 0);

    f32x4 o[8] = {};
    float m_run = -1e30f, l_run = 0.f;
    const int nt = qt + 1;

    for (int kt = 0; kt < nt; ++kt) {
        const int kv0 = kt * 64;
        const int buf = kt & 1;
        if (kt + 1 < nt) {
            stage(kv0 + 64, buf ^ 1);
            asm volatile("s_waitcnt vmcnt(8)" ::: "memory");
        } else {
            asm volatile("s_waitcnt vmcnt(0)" ::: "memory");
        }
        __builtin_amdgcn_s_barrier();
        __builtin_amdgcn_sched_barrier(0);

        const char* ksb = (const char*)&Ks[buf][0];
        const char* vsb = (const char*)&Vs[buf][0];
        char* psb = (char*)&Ps[wid][0];

        float p[4][4];
        float mx = -1e30f;
        const bool diag = (kv0 + 64 > q0);
#pragma unroll
        for (int st = 0; st < 4; ++st) {
            f32x4 sacc = {0.f, 0.f, 0.f, 0.f};
#pragma unroll
            for (int c4 = 0; c4 < 4; ++c4) {
                int r = st * 16 + fr;
                int cb = c4 * 64 + fg * 16;
                u16x8 ak = *(const u16x8*)(ksb + r * 256 + (cb ^ ((r & 7) << 4)));
                sacc = __builtin_amdgcn_mfma_f32_16x16x32_bf16(
                    as_bf(ak), as_bf(bq[c4]), sacc, 0, 0, 0);
            }
#pragma unroll
            for (int rr = 0; rr < 4; ++rr) {
                float sv = sacc[rr] * ATT_SCALE;
                if (diag) {
                    int kvg = kv0 + st * 16 + fg * 4 + rr;
                    sv = (kvg <= qrow_g) ? sv : -1e30f;
                }
                p[st][rr] = sv;
                mx = fmaxf(mx, sv);
            }
        }
        mx = fmaxf(mx, __shfl_xor(mx, 16));
        mx = fmaxf(mx, __shfl_xor(mx, 32));

        if (__all(mx - m_run <= 8.f)) {
            float rs = 0.f;
#pragma unroll
            for (int st = 0; st < 4; ++st) {
                u16x4 pw;
#pragma unroll
                for (int rr = 0; rr < 4; ++rr) {
                    float e = __expf(p[st][rr] - m_run);
                    rs += e;
                    pw[rr] = f2bf(e);
                }
                *(u16x4*)(psb + fr * 128 + ((st * 32 + fg * 8) ^ ((fr & 7) << 4))) = pw;
            }
            rs += __shfl_xor(rs, 16);
            rs += __shfl_xor(rs, 32);
            l_run += rs;
        } else {
            float m_new = fmaxf(m_run, mx);
            float corr = __expf(m_run - m_new);
            float rs = 0.f;
#pragma unroll
            for (int st = 0; st < 4; ++st) {
                u16x4 pw;
#pragma unroll
                for (int rr = 0; rr < 4; ++rr) {
                    float e = __expf(p[st][rr] - m_new);
                    rs += e;
                    pw[rr] = f2bf(e);
                }
                *(u16x4*)(psb + fr * 128 + ((st * 32 + fg * 8) ^ ((fr & 7) << 4))) = pw;
            }
            rs += __shfl_xor(rs, 16);
            rs += __shfl_xor(rs, 32);
            l_run = l_run * corr + rs;
            m_run = m_new;
            float ct[4];
#pragma unroll
            for (int rr = 0; rr < 4; ++rr) ct[rr] = __shfl(corr, fg * 4 + rr);
#pragma unroll
            for (int f = 0; f < 8; ++f)
#pragma unroll
                for (int rr = 0; rr < 4; ++rr) o[f][rr] *= ct[rr];
        }

#pragma unroll
        for (int ks = 0; ks < 2; ++ks) {
            u16x8 pa = *(const u16x8*)(psb + fr * 128 + ((ks * 64 + fg * 16) ^ ((fr & 7) << 4)));
#pragma unroll
            for (int f = 0; f < 8; ++f) {
                int d = f * 16 + fr;
                u16x8 vB = *(const u16x8*)(vsb + d * 128 + ((ks * 64 + fg * 16) ^ ((d & 7) << 4)));
                o[f] = __builtin_amdgcn_mfma_f32_16x16x32_bf16(
                    as_bf(pa), as_bf(vB), o[f], 0, 0, 0);
            }
        }
        __builtin_amdgcn_s_barrier();
    }

    float li[4];
#pragma unroll
    for (int rr = 0; rr < 4; ++rr) li[rr] = __shfl(l_run, fg * 4 + rr);
#pragma unroll
    for (int f = 0; f < 8; ++f)
#pragma unroll
        for (int rr = 0; rr < 4; ++rr) {
            int trow = q0 + fg * 4 + rr;
            float val = o[f][rr] / li[rr];
            xout[(size_t)trow * DMODEL + head * 128 + f * 16 + fr] = f2bf(val);
        }
}

extern "C" void kernel_launch(void* const* d_in, const int* in_sizes, int n_in,
                              void* d_out, int out_size, void* d_ws, size_t ws_size,
                              hipStream_t stream) {
    const float* x_in = (const float*)d_in[0];
    const float* w_qkv = (const float*)d_in[1];
    const float* w_o = (const float*)d_in[2];
    const float* cosb = (const float*)d_in[3];
    const float* sinb = (const float*)d_in[4];

    float* out = (float*)d_out;
    float* k_out = out + 4194304;
    float* v_out = out + 8388608;

    char* ws = (char*)d_ws;
    u16* xn    = (u16*)(ws);                         // 8 MiB  [T][D] bf16
    u16* w_bf  = (u16*)(ws + (size_t)(8u << 20));    // 24 MiB [3D][D] bf16
    u16* o_bf  = (u16*)(ws + (size_t)(32u << 20));   // 8 MiB  [D][D] bf16
    u16* qkv   = (u16*)(ws + (size_t)(40u << 20));   // 24 MiB [T][3D] bf16
    u16* q_bf  = (u16*)(ws + (size_t)(64u << 20));   // 8 MiB  [h][T][hd]
    u16* k_bf  = (u16*)(ws + (size_t)(72u << 20));   // 8 MiB
    u16* vt_bf = (u16*)(ws + (size_t)(80u << 20));   // 8 MiB  [h][hd][T]
    u16* x_bf  = (u16*)(ws + (size_t)(88u << 20));   // 8 MiB  [T][D]

    (void)hipFuncSetAttribute(reinterpret_cast<const void*>(&gemm256),
                              hipFuncAttributeMaxDynamicSharedMemorySize, 131072);
    (void)hipFuncSetAttribute(reinterpret_cast<const void*>(&gemm128),
                              hipFuncAttributeMaxDynamicSharedMemorySize, 65536);

    cast_both<<<8192, 256, 0, stream>>>(w_qkv, w_o, w_bf, o_bf);
    rmsnorm_row<<<2048, 256, 0, stream>>>(x_in, xn);
    gemm256<<<dim3(24, 8), 512, 131072, stream>>>(xn, w_bf, qkv, 2048, 6144, 2048);
    rope_split<<<2048, 256, 0, stream>>>(qkv, cosb, sinb, q_bf, k_bf, k_out, v_out);
    vtrans<<<2048, 256, 0, stream>>>(qkv, vt_bf);
    attn_fwd<<<512, 256, 0, stream>>>(q_bf, k_bf, vt_bf, x_bf);
    gemm128<<<dim3(16, 16), 256, 65536, stream>>>(x_bf, o_bf, out, x_in, 2048, 2048, 2048);
}

// Round 10
// 185.448 us; speedup vs baseline: 1.2877x; 1.0196x over previous
//
#include <hip/hip_runtime.h>
#include <hip/hip_bf16.h>

typedef unsigned short u16;
typedef unsigned int u32;
typedef __bf16 bf16x8 __attribute__((ext_vector_type(8)));
typedef u16 u16x8 __attribute__((ext_vector_type(8)));
typedef u16 u16x4 __attribute__((ext_vector_type(4)));
typedef float f32x4 __attribute__((ext_vector_type(4)));

#define T_SEQ 2048
#define DMODEL 2048
#define NHEAD 16
#define HDIM 128
// ATT_SCALE * log2(e): softmax runs in exp2 domain (v_exp_f32 is natively 2^x)
#define ATT_SCALE_L2E 0.12751744f

__device__ __forceinline__ u16 f2bf(float f) {
    return __builtin_bit_cast(u16, __float2bfloat16(f));
}
__device__ __forceinline__ bf16x8 as_bf(u16x8 v) {
    return __builtin_bit_cast(bf16x8, v);
}
__device__ __forceinline__ float lo2f(u32 w) { return __builtin_bit_cast(float, w << 16); }
__device__ __forceinline__ float hi2f(u32 w) { return __builtin_bit_cast(float, w & 0xffff0000u); }
__device__ __forceinline__ void gload_lds16(const u16* g, u16* l) {
    __builtin_amdgcn_global_load_lds(
        (const __attribute__((address_space(1))) u32*)(g),
        (__attribute__((address_space(3))) u32*)(l), 16, 0, 0);
}

// ---------------- fused weight casts fp32 -> bf16 ----------------
__global__ __launch_bounds__(256) void cast_both(const float* __restrict__ w1,
                                                 const float* __restrict__ w2,
                                                 u16* __restrict__ d1,
                                                 u16* __restrict__ d2) {
    int i = blockIdx.x * 256 + threadIdx.x;
    const float* src; u16* dst; int k;
    if (i < 1572864) { src = w1; dst = d1; k = i; }
    else             { src = w2; dst = d2; k = i - 1572864; }
    float4 a = ((const float4*)src)[2 * k];
    float4 b = ((const float4*)src)[2 * k + 1];
    u16x8 o;
    o[0] = f2bf(a.x); o[1] = f2bf(a.y); o[2] = f2bf(a.z); o[3] = f2bf(a.w);
    o[4] = f2bf(b.x); o[5] = f2bf(b.y); o[6] = f2bf(b.z); o[7] = f2bf(b.w);
    *(u16x8*)(dst + (size_t)k * 8) = o;
}

// ---------------- row RMSNorm over D=2048, write bf16 ----------------
__global__ __launch_bounds__(256) void rmsnorm_row(const float* __restrict__ x,
                                                   u16* __restrict__ xn) {
    const int row = blockIdx.x, tid = threadIdx.x;
    const float* xr = x + (size_t)row * DMODEL;
    float4 a = ((const float4*)xr)[2 * tid];
    float4 b = ((const float4*)xr)[2 * tid + 1];
    float ss = a.x*a.x + a.y*a.y + a.z*a.z + a.w*a.w
             + b.x*b.x + b.y*b.y + b.z*b.z + b.w*b.w;
#pragma unroll
    for (int off = 32; off; off >>= 1) ss += __shfl_xor(ss, off);
    __shared__ float red[4];
    if ((tid & 63) == 0) red[tid >> 6] = ss;
    __syncthreads();
    float tot = red[0] + red[1] + red[2] + red[3];
    float r = rsqrtf(tot * (1.f / DMODEL) + 1e-6f);
    u16x8 o;
    o[0] = f2bf(a.x*r); o[1] = f2bf(a.y*r); o[2] = f2bf(a.z*r); o[3] = f2bf(a.w*r);
    o[4] = f2bf(b.x*r); o[5] = f2bf(b.y*r); o[6] = f2bf(b.z*r); o[7] = f2bf(b.w*r);
    *(u16x8*)(xn + (size_t)row * DMODEL + tid * 8) = o;
}

// ================= shared 8-phase GEMM machinery ===========================
#define VM2 asm volatile("s_waitcnt vmcnt(2)" ::: "memory");
#define VM4 asm volatile("s_waitcnt vmcnt(4)" ::: "memory");
#define VM0 asm volatile("s_waitcnt vmcnt(0)" ::: "memory");

#define ENDP                                                                  \
  __builtin_amdgcn_s_barrier();                                               \
  __builtin_amdgcn_sched_barrier(0);

// ---- 256x192 variant for qkv (grid 32x8 = 256 blocks = 1/CU) ----
// Quadrant order per buf: (0,N0)->(0,N1)->(1,N1)->(1,N0).  A in 2 halves
// (2 gloads), B in 3 thirds (1 gload) = 7 loads/tile.  All B thirds last-read
// at P4/P8; A0 at P2/P6; A1 at P4/P8.  Stages strictly-later-phase:
//   P1 A1(b1,kn1)+Bt0(b1,kn1)  P2 Bt1+Bt2(b1,kn1)  P3 A0(b0,kn2)
//   P5 A1(b0,kn2)+Bt0(b0,kn2)  P6 Bt1+Bt2(b0,kn2)  P7 A0(b1,kn3)
// Waits: P4 vmcnt(2) [out=kn1:7+kn2:2] ; P8 vmcnt(2) [out=kn2:7+kn3:2].
#define LDA192(BUF, MH)                                                       \
  _Pragma("unroll") for (int mq = 0; mq < 4; ++mq) {                          \
    int ra = wr + (MH) * 64 + mq * 16 + fr;                                   \
    int sw = ra & 7;                                                          \
    _Pragma("unroll") for (int k2 = 0; k2 < 2; ++k2)                          \
      av[mq][k2] = *(const u16x8*)(sA[BUF] + ra * 64 +                        \
                                   ((((k2 << 2) | fg) ^ sw) << 3));           \
  }

#define LDB0_192(BUF)                                                         \
  _Pragma("unroll") for (int nq = 0; nq < 2; ++nq) {                          \
    int rb = wc + nq * 16 + fr;                                               \
    int sw = rb & 7;                                                          \
    _Pragma("unroll") for (int k2 = 0; k2 < 2; ++k2)                          \
      bv[nq][k2] = *(const u16x8*)(sB[BUF] + rb * 64 +                        \
                                   ((((k2 << 2) | fg) ^ sw) << 3));           \
  }

#define LDB1_192(BUF)                                                         \
  {                                                                           \
    int rb = wc + 32 + fr;                                                    \
    int sw = rb & 7;                                                          \
    _Pragma("unroll") for (int k2 = 0; k2 < 2; ++k2)                          \
      bv1[k2] = *(const u16x8*)(sB[BUF] + rb * 64 +                           \
                                ((((k2 << 2) | fg) ^ sw) << 3));              \
  }

#define MFMAQ_N0(MH)                                                          \
  __builtin_amdgcn_s_barrier();                                               \
  __builtin_amdgcn_s_setprio(1);                                              \
  _Pragma("unroll") for (int k2 = 0; k2 < 2; ++k2)                            \
    _Pragma("unroll") for (int mq = 0; mq < 4; ++mq)                          \
      _Pragma("unroll") for (int nq = 0; nq < 2; ++nq)                        \
        acc[(MH) * 4 + mq][nq] = __builtin_amdgcn_mfma_f32_16x16x32_bf16(     \
            as_bf(av[mq][k2]), as_bf(bv[nq][k2]), acc[(MH) * 4 + mq][nq],     \
            0, 0, 0);                                                         \
  __builtin_amdgcn_s_setprio(0);

#define MFMAQ_N1(MH)                                                          \
  __builtin_amdgcn_s_barrier();                                               \
  __builtin_amdgcn_s_setprio(1);                                              \
  _Pragma("unroll") for (int k2 = 0; k2 < 2; ++k2)                            \
    _Pragma("unroll") for (int mq = 0; mq < 4; ++mq)                          \
      acc[(MH) * 4 + mq][2] = __builtin_amdgcn_mfma_f32_16x16x32_bf16(        \
          as_bf(av[mq][k2]), as_bf(bv1[k2]), acc[(MH) * 4 + mq][2],           \
          0, 0, 0);                                                           \
  __builtin_amdgcn_s_setprio(0);

__global__ __launch_bounds__(512) void gemm192(const u16* __restrict__ A,
                                               const u16* __restrict__ B,
                                               u16* __restrict__ C,
                                               int M, int N, int K) {
    extern __shared__ char smem[];
    const int tid = threadIdx.x, lane = tid & 63, wid = tid >> 6;
    const int bm = blockIdx.y * 256, bn = blockIdx.x * 192;
    const int wr = (wid >> 2) * 128, wc = (wid & 3) * 48;
    const int fr = lane & 15, fg = lane >> 4;

    // sA: 32KB/buf, sB: 24KB/buf -> 112KB total
    u16* sA[2] = {(u16*)smem, (u16*)(smem + 57344)};
    u16* sB[2] = {(u16*)(smem + 32768), (u16*)(smem + 90112)};

    const int cs = (((tid & 7) ^ ((tid >> 3) & 7)) << 3);
    const int s8 = (tid & 7) << 3;
    const int rr6 = tid >> 3;   // 0..63

    auto stA = [&](int buf, int k0, int mh) {
#pragma unroll
        for (int j = 0; j < 2; ++j) {
            int r = j * 128 + mh * 64 + rr6;
            gload_lds16(A + (size_t)(bm + r) * K + k0 + cs, sA[buf] + r * 64 + s8);
        }
    };
    auto stB = [&](int buf, int k0, int bt) {
        int r = bt * 64 + rr6;
        gload_lds16(B + (size_t)(bn + r) * K + k0 + cs, sB[buf] + r * 64 + s8);
    };

    f32x4 acc[8][3] = {};
    u16x8 av[4][2], bv[2][2], bv1[2];
    const int nt = K >> 6;

    // prologue: kn0 full (7) + kn1's A0 (2); vmcnt(2) drains kn0's 7
    stA(0, 0, 0); stA(0, 0, 1); stB(0, 0, 0); stB(0, 0, 1); stB(0, 0, 2);
    stA(1, 64, 0);
    VM2
    __builtin_amdgcn_s_barrier();
    __builtin_amdgcn_sched_barrier(0);

    for (int it = 0; it < (nt >> 1); ++it) {
        const int kc = it << 7;
        const int kn1 = kc + 64, kn2 = kc + 128, kn3 = kc + 192;
        const bool st2 = (kn2 < K), st3 = (kn3 < K);

        // P1 (b0; 0,N0)
        LDA192(0, 0) LDB0_192(0)
        stA(1, kn1, 1); stB(1, kn1, 0);
        MFMAQ_N0(0) ENDP
        // P2 (b0; 0,N1)
        LDB1_192(0)
        stB(1, kn1, 1); stB(1, kn1, 2);
        MFMAQ_N1(0) ENDP
        // P3 (b0; 1,N1)
        LDA192(0, 1)
        if (st2) stA(0, kn2, 0);
        MFMAQ_N1(1) ENDP
        // P4 (b0; 1,N0)
        LDB0_192(0)
        MFMAQ_N0(1)
        if (st2) { VM2 } else { VM0 }
        ENDP
        // P5 (b1; 0,N0)
        LDA192(1, 0) LDB0_192(1)
        if (st2) { stA(0, kn2, 1); stB(0, kn2, 0); }
        MFMAQ_N0(0) ENDP
        // P6 (b1; 0,N1)
        LDB1_192(1)
        if (st2) { stB(0, kn2, 1); stB(0, kn2, 2); }
        MFMAQ_N1(0) ENDP
        // P7 (b1; 1,N1)
        LDA192(1, 1)
        if (st3) stA(1, kn3, 0);
        MFMAQ_N1(1) ENDP
        // P8 (b1; 1,N0)
        LDB0_192(1)
        MFMAQ_N0(1)
        if (st3) { VM2 } else { VM0 }
        ENDP
    }

#pragma unroll
    for (int am = 0; am < 8; ++am)
#pragma unroll
        for (int bq = 0; bq < 3; ++bq)
#pragma unroll
            for (int r = 0; r < 4; ++r) {
                int row = bm + wr + am * 16 + fg * 4 + r;
                int col = bn + wc + bq * 16 + fr;
                C[(size_t)row * N + col] = f2bf(acc[am][bq][r]);
            }
}

// ---- 128x128 8-phase variant for out-proj (resid epilogue) ----
#define LDAH(BUF, MH)                                                         \
  _Pragma("unroll") for (int mq = 0; mq < 2; ++mq) {                          \
    int ra = wr + (MH) * 32 + mq * 16 + fr;                                   \
    int sw = ra & 7;                                                          \
    _Pragma("unroll") for (int k2 = 0; k2 < 2; ++k2)                          \
      av[mq][k2] = *(const u16x8*)(sA[BUF] + ra * 64 +                        \
                                   ((((k2 << 2) | fg) ^ sw) << 3));           \
  }

#define LDBH(BUF, NH)                                                         \
  _Pragma("unroll") for (int nq = 0; nq < 2; ++nq) {                          \
    int rb = wc + (NH) * 32 + nq * 16 + fr;                                   \
    int sw = rb & 7;                                                          \
    _Pragma("unroll") for (int k2 = 0; k2 < 2; ++k2)                          \
      bv[nq][k2] = *(const u16x8*)(sB[BUF] + rb * 64 +                        \
                                   ((((k2 << 2) | fg) ^ sw) << 3));           \
  }

#define MFMAQH(MH, NH)                                                        \
  __builtin_amdgcn_s_barrier();                                               \
  __builtin_amdgcn_s_setprio(1);                                              \
  _Pragma("unroll") for (int k2 = 0; k2 < 2; ++k2)                            \
    _Pragma("unroll") for (int mq = 0; mq < 2; ++mq)                          \
      _Pragma("unroll") for (int nq = 0; nq < 2; ++nq)                        \
        acc[(MH) * 2 + mq][(NH) * 2 + nq] =                                   \
            __builtin_amdgcn_mfma_f32_16x16x32_bf16(                          \
                as_bf(av[mq][k2]), as_bf(bv[nq][k2]),                         \
                acc[(MH) * 2 + mq][(NH) * 2 + nq], 0, 0, 0);                  \
  __builtin_amdgcn_s_setprio(0);

__global__ __launch_bounds__(256) void gemm128(const u16* __restrict__ A,
                                               const u16* __restrict__ B,
                                               float* __restrict__ C,
                                               const float* __restrict__ resid,
                                               int M, int N, int K) {
    extern __shared__ char smem[];
    const int tid = threadIdx.x, lane = tid & 63, wid = tid >> 6;
    const int bm = blockIdx.y * 128, bn = blockIdx.x * 128;
    const int wr = (wid >> 1) * 64, wc = (wid & 1) * 64;
    const int fr = lane & 15, fg = lane >> 4;

    u16* sA[2] = {(u16*)smem, (u16*)(smem + 32768)};
    u16* sB[2] = {(u16*)(smem + 16384), (u16*)(smem + 49152)};

    const int cs = (((tid & 7) ^ ((tid >> 3) & 7)) << 3);
    const int s8 = (tid & 7) << 3;
    const int rr5 = tid >> 3;   // 0..31

    auto stA = [&](int buf, int k0, int mh) {
#pragma unroll
        for (int j = 0; j < 2; ++j) {
            int r = j * 64 + mh * 32 + rr5;
            gload_lds16(A + (size_t)(bm + r) * K + k0 + cs, sA[buf] + r * 64 + s8);
        }
    };
    auto stB = [&](int buf, int k0, int nh) {
#pragma unroll
        for (int j = 0; j < 2; ++j) {
            int r = j * 64 + nh * 32 + rr5;
            gload_lds16(B + (size_t)(bn + r) * K + k0 + cs, sB[buf] + r * 64 + s8);
        }
    };

    f32x4 acc[4][4] = {};
    u16x8 av[2][2], bv[2][2];
    const int nt = K >> 6;

    stA(0, 0, 0); stA(0, 0, 1); stB(0, 0, 0); stB(0, 0, 1);
    stA(1, 64, 0); stB(1, 64, 1);
    VM4
    __builtin_amdgcn_s_barrier();
    __builtin_amdgcn_sched_barrier(0);

    for (int it = 0; it < (nt >> 1); ++it) {
        const int kc = it << 7;
        const int kn1 = kc + 64, kn2 = kc + 128, kn3 = kc + 192;
        const bool st2 = (kn2 < K), st3 = (kn3 < K);

        LDAH(0, 0) LDBH(0, 0)
        stA(1, kn1, 1);
        MFMAQH(0, 0) ENDP
        LDBH(0, 1)
        stB(1, kn1, 0);
        MFMAQH(0, 1) ENDP
        LDAH(0, 1)
        if (st2) stA(0, kn2, 0);
        MFMAQH(1, 1) ENDP
        LDBH(0, 0)
        if (st2) stB(0, kn2, 1);
        MFMAQH(1, 0)
        if (st2) { VM4 } else { VM0 }
        ENDP
        LDAH(1, 0) LDBH(1, 0)
        if (st2) stA(0, kn2, 1);
        MFMAQH(0, 0) ENDP
        LDBH(1, 1)
        if (st2) stB(0, kn2, 0);
        MFMAQH(0, 1) ENDP
        LDAH(1, 1)
        if (st3) stA(1, kn3, 0);
        MFMAQH(1, 1) ENDP
        LDBH(1, 0)
        if (st3) stB(1, kn3, 1);
        MFMAQH(1, 0)
        VM4
        ENDP
    }

#pragma unroll
    for (int am = 0; am < 4; ++am)
#pragma unroll
        for (int bq = 0; bq < 4; ++bq)
#pragma unroll
            for (int r = 0; r < 4; ++r) {
                int row = bm + wr + am * 16 + fg * 4 + r;
                int col = bn + wc + bq * 16 + fr;
                float val = acc[am][bq][r] + resid[(size_t)row * N + col];
                C[(size_t)row * N + col] = val;
            }
}

// ---------------- per-head RMSNorm + RoPE (vectorized, bf16 qkv) -----------
__global__ __launch_bounds__(256) void rope_split(const u16* __restrict__ qkv,
                                                  const float* __restrict__ cosb,
                                                  const float* __restrict__ sinb,
                                                  u16* __restrict__ q_bf,
                                                  u16* __restrict__ k_bf,
                                                  float* __restrict__ k_out,
                                                  float* __restrict__ v_out) {
    const int t = blockIdx.x, tid = threadIdx.x, wid = tid >> 6, lane = tid & 63;
    const u16* row = qkv + (size_t)t * (3 * DMODEL);
    const int dp = (lane & 31) << 1;
    float2 c2 = *(const float2*)(cosb + t * 64 + dp);
    float2 s2 = *(const float2*)(sinb + t * 64 + dp);
    const bool hi = lane >= 32;

    for (int task = wid; task < 32; task += 4) {
        u32 w = *(const u32*)(row + task * 128 + lane * 2);
        float xa = lo2f(w), xb = hi2f(w);
        float ss = xa * xa + xb * xb;
#pragma unroll
        for (int off = 32; off; off >>= 1) ss += __shfl_xor(ss, off);
        float rn = rsqrtf(ss * (1.f / 128.f) + 1e-6f);
        float pa = __shfl_xor(xa, 32), pb = __shfl_xor(xb, 32);
        float oa, ob;
        if (!hi) {
            oa = (xa * c2.x - pa * s2.x) * rn;
            ob = (xb * c2.y - pb * s2.y) * rn;
        } else {
            oa = (pa * s2.x + xa * c2.x) * rn;
            ob = (pb * s2.y + xb * c2.y) * rn;
        }
        u32 pk = (u32)f2bf(oa) | ((u32)f2bf(ob) << 16);
        if (task < 16) {
            *(u32*)(q_bf + ((size_t)task * T_SEQ + t) * 128 + lane * 2) = pk;
        } else {
            int hh = task - 16;
            *(u32*)(k_bf + ((size_t)hh * T_SEQ + t) * 128 + lane * 2) = pk;
            float2 kk; kk.x = oa; kk.y = ob;
            *(float2*)(k_out + (size_t)t * DMODEL + hh * 128 + lane * 2) = kk;
        }
    }
    {
        u16x8 vv = *(const u16x8*)(row + 2 * DMODEL + tid * 8);
        float4 f0, f1;
        f0.x = __builtin_bit_cast(float, (u32)vv[0] << 16);
        f0.y = __builtin_bit_cast(float, (u32)vv[1] << 16);
        f0.z = __builtin_bit_cast(float, (u32)vv[2] << 16);
        f0.w = __builtin_bit_cast(float, (u32)vv[3] << 16);
        f1.x = __builtin_bit_cast(float, (u32)vv[4] << 16);
        f1.y = __builtin_bit_cast(float, (u32)vv[5] << 16);
        f1.z = __builtin_bit_cast(float, (u32)vv[6] << 16);
        f1.w = __builtin_bit_cast(float, (u32)vv[7] << 16);
        *(float4*)(v_out + (size_t)t * DMODEL + tid * 8) = f0;
        *(float4*)(v_out + (size_t)t * DMODEL + tid * 8 + 4) = f1;
    }
}

// ---------------- V transpose: qkv bf16 -> vt bf16 [h][128][T] -------------
__global__ __launch_bounds__(256) void vtrans(const u16* __restrict__ qkv,
                                              u16* __restrict__ vt) {
    const int b = blockIdx.x, tid = threadIdx.x;
    const int head = b >> 7;
    const int i = (b & 127) * 256 + tid;
    const int d = i & 127, tc = i >> 7;
    u16x8 o;
#pragma unroll
    for (int j = 0; j < 8; ++j)
        o[j] = qkv[(size_t)(tc * 8 + j) * (3 * DMODEL) + 2 * DMODEL + head * 128 + d];
    *(u16x8*)&vt[((size_t)head * 128 + d) * T_SEQ + tc * 8] = o;
}

// ---------------- causal flash attention (r6 structure, exp2-domain SM) ----
__global__ __launch_bounds__(256) void attn_fwd(const u16* __restrict__ qb,
                                                const u16* __restrict__ kb,
                                                const u16* __restrict__ vtb,
                                                u16* __restrict__ xout) {
    __shared__ u16 Ks[2][64 * 128];
    __shared__ u16 Vs[2][128 * 64];
    __shared__ u16 Ps[4][16 * 64];

    const int bid = blockIdx.x;
    const int r8 = bid & 7, s = bid >> 3;
    const int head = r8 + ((s >> 5) << 3);
    const int j = s & 31;
    const int qt = (s < 32) ? (31 - j) : j;

    const int tid = threadIdx.x, wid = tid >> 6, lane = tid & 63;
    const int fr = lane & 15, fg = lane >> 4;
    const u16* kh = kb + (size_t)head * T_SEQ * 128;
    const u16* vth = vtb + (size_t)head * 128 * T_SEQ;
    const u16* qh = qb + (size_t)head * T_SEQ * 128;
    const int q0 = qt * 64 + wid * 16;
    const int qrow_g = q0 + fr;

    u16x8 bq[4];
    {
        const u16* qrow = qh + (size_t)(q0 + fr) * 128 + fg * 8;
#pragma unroll
        for (int cc = 0; cc < 4; ++cc) bq[cc] = *(const u16x8*)(qrow + cc * 32);
    }

    auto stage = [&](int kv0, int buf) {
#pragma unroll
        for (int i = 0; i < 4; ++i) {
            int idx = i * 256 + tid;
            int r = idx >> 4;
            int cbs = ((idx & 15) << 4) ^ ((r & 7) << 4);
            gload_lds16(kh + (size_t)(kv0 + r) * 128 + (cbs >> 1), &Ks[buf][idx * 8]);
        }
#pragma unroll
        for (int i = 0; i < 4; ++i) {
            int idx = i * 256 + tid;
            int d = idx >> 3;
            int cbs = ((idx & 7) << 4) ^ ((d & 7) << 4);
            gload_lds16(vth + (size_t)d * T_SEQ + kv0 + (cbs >> 1), &Vs[buf][idx * 8]);
        }
    };

    stage(0, 0);

    f32x4 o[8] = {};
    float m_run = -1e30f, l_run = 0.f;
    const int nt = qt + 1;

    for (int kt = 0; kt < nt; ++kt) {
        const int kv0 = kt * 64;
        const int buf = kt & 1;
        if (kt + 1 < nt) {
            stage(kv0 + 64, buf ^ 1);
            asm volatile("s_waitcnt vmcnt(8)" ::: "memory");
        } else {
            asm volatile("s_waitcnt vmcnt(0)" ::: "memory");
        }
        __builtin_amdgcn_s_barrier();
        __builtin_amdgcn_sched_barrier(0);

        const char* ksb = (const char*)&Ks[buf][0];
        const char* vsb = (const char*)&Vs[buf][0];
        char* psb = (char*)&Ps[wid][0];

        float p[4][4];
        float mx = -1e30f;
        const bool diag = (kv0 + 64 > q0);
#pragma unroll
        for (int st = 0; st < 4; ++st) {
            f32x4 sacc = {0.f, 0.f, 0.f, 0.f};
#pragma unroll
            for (int c4 = 0; c4 < 4; ++c4) {
                int r = st * 16 + fr;
                int cb = c4 * 64 + fg * 16;
                u16x8 ak = *(const u16x8*)(ksb + r * 256 + (cb ^ ((r & 7) << 4)));
                sacc = __builtin_amdgcn_mfma_f32_16x16x32_bf16(
                    as_bf(ak), as_bf(bq[c4]), sacc, 0, 0, 0);
            }
#pragma unroll
            for (int rr = 0; rr < 4; ++rr) {
                float sv = sacc[rr] * ATT_SCALE_L2E;
                if (diag) {
                    int kvg = kv0 + st * 16 + fg * 4 + rr;
                    sv = (kvg <= qrow_g) ? sv : -1e30f;
                }
                p[st][rr] = sv;
                mx = fmaxf(mx, sv);
            }
        }
        mx = fmaxf(mx, __shfl_xor(mx, 16));
        mx = fmaxf(mx, __shfl_xor(mx, 32));

        // defer-max: 11.5 log2-units ~ e^8 headroom
        if (__all(mx - m_run <= 11.5f)) {
            float rs = 0.f;
#pragma unroll
            for (int st = 0; st < 4; ++st) {
                u16x4 pw;
#pragma unroll
                for (int rr = 0; rr < 4; ++rr) {
                    float e = exp2f(p[st][rr] - m_run);
                    rs += e;
                    pw[rr] = f2bf(e);
                }
                *(u16x4*)(psb + fr * 128 + ((st * 32 + fg * 8) ^ ((fr & 7) << 4))) = pw;
            }
            rs += __shfl_xor(rs, 16);
            rs += __shfl_xor(rs, 32);
            l_run += rs;
        } else {
            float m_new = fmaxf(m_run, mx);
            float corr = exp2f(m_run - m_new);
            float rs = 0.f;
#pragma unroll
            for (int st = 0; st < 4; ++st) {
                u16x4 pw;
#pragma unroll
                for (int rr = 0; rr < 4; ++rr) {
                    float e = exp2f(p[st][rr] - m_new);
                    rs += e;
                    pw[rr] = f2bf(e);
                }
                *(u16x4*)(psb + fr * 128 + ((st * 32 + fg * 8) ^ ((fr & 7) << 4))) = pw;
            }
            rs += __shfl_xor(rs, 16);
            rs += __shfl_xor(rs, 32);
            l_run = l_run * corr + rs;
            m_run = m_new;
            float ct[4];
#pragma unroll
            for (int rr = 0; rr < 4; ++rr) ct[rr] = __shfl(corr, fg * 4 + rr);
#pragma unroll
            for (int f = 0; f < 8; ++f)
#pragma unroll
                for (int rr = 0; rr < 4; ++rr) o[f][rr] *= ct[rr];
        }

#pragma unroll
        for (int ks = 0; ks < 2; ++ks) {
            u16x8 pa = *(const u16x8*)(psb + fr * 128 + ((ks * 64 + fg * 16) ^ ((fr & 7) << 4)));
#pragma unroll
            for (int f = 0; f < 8; ++f) {
                int d = f * 16 + fr;
                u16x8 vB = *(const u16x8*)(vsb + d * 128 + ((ks * 64 + fg * 16) ^ ((d & 7) << 4)));
                o[f] = __builtin_amdgcn_mfma_f32_16x16x32_bf16(
                    as_bf(pa), as_bf(vB), o[f], 0, 0, 0);
            }
        }
        __builtin_amdgcn_s_barrier();
    }

    float li[4];
#pragma unroll
    for (int rr = 0; rr < 4; ++rr) li[rr] = __shfl(l_run, fg * 4 + rr);
#pragma unroll
    for (int f = 0; f < 8; ++f)
#pragma unroll
        for (int rr = 0; rr < 4; ++rr) {
            int trow = q0 + fg * 4 + rr;
            float val = o[f][rr] / li[rr];
            xout[(size_t)trow * DMODEL + head * 128 + f * 16 + fr] = f2bf(val);
        }
}

extern "C" void kernel_launch(void* const* d_in, const int* in_sizes, int n_in,
                              void* d_out, int out_size, void* d_ws, size_t ws_size,
                              hipStream_t stream) {
    const float* x_in = (const float*)d_in[0];
    const float* w_qkv = (const float*)d_in[1];
    const float* w_o = (const float*)d_in[2];
    const float* cosb = (const float*)d_in[3];
    const float* sinb = (const float*)d_in[4];

    float* out = (float*)d_out;
    float* k_out = out + 4194304;
    float* v_out = out + 8388608;

    char* ws = (char*)d_ws;
    u16* xn    = (u16*)(ws);                         // 8 MiB  [T][D] bf16
    u16* w_bf  = (u16*)(ws + (size_t)(8u << 20));    // 24 MiB [3D][D] bf16
    u16* o_bf  = (u16*)(ws + (size_t)(32u << 20));   // 8 MiB  [D][D] bf16
    u16* qkv   = (u16*)(ws + (size_t)(40u << 20));   // 24 MiB [T][3D] bf16
    u16* q_bf  = (u16*)(ws + (size_t)(64u << 20));   // 8 MiB  [h][T][hd]
    u16* k_bf  = (u16*)(ws + (size_t)(72u << 20));   // 8 MiB
    u16* vt_bf = (u16*)(ws + (size_t)(80u << 20));   // 8 MiB  [h][hd][T]
    u16* x_bf  = (u16*)(ws + (size_t)(88u << 20));   // 8 MiB  [T][D]

    (void)hipFuncSetAttribute(reinterpret_cast<const void*>(&gemm192),
                              hipFuncAttributeMaxDynamicSharedMemorySize, 114688);
    (void)hipFuncSetAttribute(reinterpret_cast<const void*>(&gemm128),
                              hipFuncAttributeMaxDynamicSharedMemorySize, 65536);

    cast_both<<<8192, 256, 0, stream>>>(w_qkv, w_o, w_bf, o_bf);
    rmsnorm_row<<<2048, 256, 0, stream>>>(x_in, xn);
    gemm192<<<dim3(32, 8), 512, 114688, stream>>>(xn, w_bf, qkv, 2048, 6144, 2048);
    rope_split<<<2048, 256, 0, stream>>>(qkv, cosb, sinb, q_bf, k_bf, k_out, v_out);
    vtrans<<<2048, 256, 0, stream>>>(qkv, vt_bf);
    attn_fwd<<<512, 256, 0, stream>>>(q_bf, k_bf, vt_bf, x_bf);
    gemm128<<<dim3(16, 16), 256, 65536, stream>>>(x_bf, o_bf, out, x_in, 2048, 2048, 2048);
}

// Round 11
// 179.331 us; speedup vs baseline: 1.3316x; 1.0341x over previous
//
#include <hip/hip_runtime.h>
#include <hip/hip_bf16.h>

typedef unsigned short u16;
typedef unsigned int u32;
typedef __bf16 bf16x8 __attribute__((ext_vector_type(8)));
typedef u16 u16x8 __attribute__((ext_vector_type(8)));
typedef u16 u16x4 __attribute__((ext_vector_type(4)));
typedef float f32x4 __attribute__((ext_vector_type(4)));

#define T_SEQ 2048
#define DMODEL 2048
#define NHEAD 16
#define HDIM 128
#define ATT_SCALE 0.08838834764831843f

__device__ __forceinline__ u16 f2bf(float f) {
    return __builtin_bit_cast(u16, __float2bfloat16(f));
}
__device__ __forceinline__ bf16x8 as_bf(u16x8 v) {
    return __builtin_bit_cast(bf16x8, v);
}
__device__ __forceinline__ float lo2f(u32 w) { return __builtin_bit_cast(float, w << 16); }
__device__ __forceinline__ float hi2f(u32 w) { return __builtin_bit_cast(float, w & 0xffff0000u); }
__device__ __forceinline__ void gload_lds16(const u16* g, u16* l) {
    __builtin_amdgcn_global_load_lds(
        (const __attribute__((address_space(1))) u32*)(g),
        (__attribute__((address_space(3))) u32*)(l), 16, 0, 0);
}

// ------- fused prep: weight casts (blocks 0..8191) + RMSNorm (8192..10239) --
__global__ __launch_bounds__(256) void prep(const float* __restrict__ w1,
                                            const float* __restrict__ w2,
                                            const float* __restrict__ x,
                                            u16* __restrict__ d1,
                                            u16* __restrict__ d2,
                                            u16* __restrict__ xn) {
    const int b = blockIdx.x, tid = threadIdx.x;
    if (b < 8192) {
        int i = b * 256 + tid;
        const float* src; u16* dst; int k;
        if (i < 1572864) { src = w1; dst = d1; k = i; }
        else             { src = w2; dst = d2; k = i - 1572864; }
        float4 a = ((const float4*)src)[2 * k];
        float4 bb = ((const float4*)src)[2 * k + 1];
        u16x8 o;
        o[0] = f2bf(a.x); o[1] = f2bf(a.y); o[2] = f2bf(a.z); o[3] = f2bf(a.w);
        o[4] = f2bf(bb.x); o[5] = f2bf(bb.y); o[6] = f2bf(bb.z); o[7] = f2bf(bb.w);
        *(u16x8*)(dst + (size_t)k * 8) = o;
        return;
    }
    const int row = b - 8192;
    const float* xr = x + (size_t)row * DMODEL;
    float4 a = ((const float4*)xr)[2 * tid];
    float4 bb = ((const float4*)xr)[2 * tid + 1];
    float ss = a.x*a.x + a.y*a.y + a.z*a.z + a.w*a.w
             + bb.x*bb.x + bb.y*bb.y + bb.z*bb.z + bb.w*bb.w;
#pragma unroll
    for (int off = 32; off; off >>= 1) ss += __shfl_xor(ss, off);
    __shared__ float red[4];
    if ((tid & 63) == 0) red[tid >> 6] = ss;
    __syncthreads();
    float tot = red[0] + red[1] + red[2] + red[3];
    float r = rsqrtf(tot * (1.f / DMODEL) + 1e-6f);
    u16x8 o;
    o[0] = f2bf(a.x*r); o[1] = f2bf(a.y*r); o[2] = f2bf(a.z*r); o[3] = f2bf(a.w*r);
    o[4] = f2bf(bb.x*r); o[5] = f2bf(bb.y*r); o[6] = f2bf(bb.z*r); o[7] = f2bf(bb.w*r);
    *(u16x8*)(xn + (size_t)row * DMODEL + tid * 8) = o;
}

// ================= shared 8-phase GEMM machinery ===========================
#define VM2 asm volatile("s_waitcnt vmcnt(2)" ::: "memory");
#define VM4 asm volatile("s_waitcnt vmcnt(4)" ::: "memory");
#define VM0 asm volatile("s_waitcnt vmcnt(0)" ::: "memory");

#define ENDP                                                                  \
  __builtin_amdgcn_s_barrier();                                               \
  __builtin_amdgcn_sched_barrier(0);

// ---- 256x192 variant for qkv (grid 32x8 = 256 blocks = 1/CU) ----
#define LDA192(BUF, MH)                                                       \
  _Pragma("unroll") for (int mq = 0; mq < 4; ++mq) {                          \
    int ra = wr + (MH) * 64 + mq * 16 + fr;                                   \
    int sw = ra & 7;                                                          \
    _Pragma("unroll") for (int k2 = 0; k2 < 2; ++k2)                          \
      av[mq][k2] = *(const u16x8*)(sA[BUF] + ra * 64 +                        \
                                   ((((k2 << 2) | fg) ^ sw) << 3));           \
  }

#define LDB0_192(BUF)                                                         \
  _Pragma("unroll") for (int nq = 0; nq < 2; ++nq) {                          \
    int rb = wc + nq * 16 + fr;                                               \
    int sw = rb & 7;                                                          \
    _Pragma("unroll") for (int k2 = 0; k2 < 2; ++k2)                          \
      bv[nq][k2] = *(const u16x8*)(sB[BUF] + rb * 64 +                        \
                                   ((((k2 << 2) | fg) ^ sw) << 3));           \
  }

#define LDB1_192(BUF)                                                         \
  {                                                                           \
    int rb = wc + 32 + fr;                                                    \
    int sw = rb & 7;                                                          \
    _Pragma("unroll") for (int k2 = 0; k2 < 2; ++k2)                          \
      bv1[k2] = *(const u16x8*)(sB[BUF] + rb * 64 +                           \
                                ((((k2 << 2) | fg) ^ sw) << 3));              \
  }

#define MFMAQ_N0(MH)                                                          \
  __builtin_amdgcn_s_barrier();                                               \
  __builtin_amdgcn_s_setprio(1);                                              \
  _Pragma("unroll") for (int k2 = 0; k2 < 2; ++k2)                            \
    _Pragma("unroll") for (int mq = 0; mq < 4; ++mq)                          \
      _Pragma("unroll") for (int nq = 0; nq < 2; ++nq)                        \
        acc[(MH) * 4 + mq][nq] = __builtin_amdgcn_mfma_f32_16x16x32_bf16(     \
            as_bf(av[mq][k2]), as_bf(bv[nq][k2]), acc[(MH) * 4 + mq][nq],     \
            0, 0, 0);                                                         \
  __builtin_amdgcn_s_setprio(0);

#define MFMAQ_N1(MH)                                                          \
  __builtin_amdgcn_s_barrier();                                               \
  __builtin_amdgcn_s_setprio(1);                                              \
  _Pragma("unroll") for (int k2 = 0; k2 < 2; ++k2)                            \
    _Pragma("unroll") for (int mq = 0; mq < 4; ++mq)                          \
      acc[(MH) * 4 + mq][2] = __builtin_amdgcn_mfma_f32_16x16x32_bf16(        \
          as_bf(av[mq][k2]), as_bf(bv1[k2]), acc[(MH) * 4 + mq][2],           \
          0, 0, 0);                                                           \
  __builtin_amdgcn_s_setprio(0);

__global__ __launch_bounds__(512) void gemm192(const u16* __restrict__ A,
                                               const u16* __restrict__ B,
                                               u16* __restrict__ C,
                                               int M, int N, int K) {
    extern __shared__ char smem[];
    const int tid = threadIdx.x, lane = tid & 63, wid = tid >> 6;
    const int bm = blockIdx.y * 256, bn = blockIdx.x * 192;
    const int wr = (wid >> 2) * 128, wc = (wid & 3) * 48;
    const int fr = lane & 15, fg = lane >> 4;

    u16* sA[2] = {(u16*)smem, (u16*)(smem + 57344)};
    u16* sB[2] = {(u16*)(smem + 32768), (u16*)(smem + 90112)};

    const int cs = (((tid & 7) ^ ((tid >> 3) & 7)) << 3);
    const int s8 = (tid & 7) << 3;
    const int rr6 = tid >> 3;

    auto stA = [&](int buf, int k0, int mh) {
#pragma unroll
        for (int j = 0; j < 2; ++j) {
            int r = j * 128 + mh * 64 + rr6;
            gload_lds16(A + (size_t)(bm + r) * K + k0 + cs, sA[buf] + r * 64 + s8);
        }
    };
    auto stB = [&](int buf, int k0, int bt) {
        int r = bt * 64 + rr6;
        gload_lds16(B + (size_t)(bn + r) * K + k0 + cs, sB[buf] + r * 64 + s8);
    };

    f32x4 acc[8][3] = {};
    u16x8 av[4][2], bv[2][2], bv1[2];
    const int nt = K >> 6;

    stA(0, 0, 0); stA(0, 0, 1); stB(0, 0, 0); stB(0, 0, 1); stB(0, 0, 2);
    stA(1, 64, 0);
    VM2
    __builtin_amdgcn_s_barrier();
    __builtin_amdgcn_sched_barrier(0);

    for (int it = 0; it < (nt >> 1); ++it) {
        const int kc = it << 7;
        const int kn1 = kc + 64, kn2 = kc + 128, kn3 = kc + 192;
        const bool st2 = (kn2 < K), st3 = (kn3 < K);

        LDA192(0, 0) LDB0_192(0)
        stA(1, kn1, 1); stB(1, kn1, 0);
        MFMAQ_N0(0) ENDP
        LDB1_192(0)
        stB(1, kn1, 1); stB(1, kn1, 2);
        MFMAQ_N1(0) ENDP
        LDA192(0, 1)
        if (st2) stA(0, kn2, 0);
        MFMAQ_N1(1) ENDP
        LDB0_192(0)
        MFMAQ_N0(1)
        if (st2) { VM2 } else { VM0 }
        ENDP
        LDA192(1, 0) LDB0_192(1)
        if (st2) { stA(0, kn2, 1); stB(0, kn2, 0); }
        MFMAQ_N0(0) ENDP
        LDB1_192(1)
        if (st2) { stB(0, kn2, 1); stB(0, kn2, 2); }
        MFMAQ_N1(0) ENDP
        LDA192(1, 1)
        if (st3) stA(1, kn3, 0);
        MFMAQ_N1(1) ENDP
        LDB0_192(1)
        MFMAQ_N0(1)
        if (st3) { VM2 } else { VM0 }
        ENDP
    }

#pragma unroll
    for (int am = 0; am < 8; ++am)
#pragma unroll
        for (int bq = 0; bq < 3; ++bq)
#pragma unroll
            for (int r = 0; r < 4; ++r) {
                int row = bm + wr + am * 16 + fg * 4 + r;
                int col = bn + wc + bq * 16 + fr;
                C[(size_t)row * N + col] = f2bf(acc[am][bq][r]);
            }
}

// ---- 128x128 8-phase variant for out-proj (resid epilogue) ----
#define LDAH(BUF, MH)                                                         \
  _Pragma("unroll") for (int mq = 0; mq < 2; ++mq) {                          \
    int ra = wr + (MH) * 32 + mq * 16 + fr;                                   \
    int sw = ra & 7;                                                          \
    _Pragma("unroll") for (int k2 = 0; k2 < 2; ++k2)                          \
      av[mq][k2] = *(const u16x8*)(sA[BUF] + ra * 64 +                        \
                                   ((((k2 << 2) | fg) ^ sw) << 3));           \
  }

#define LDBH(BUF, NH)                                                         \
  _Pragma("unroll") for (int nq = 0; nq < 2; ++nq) {                          \
    int rb = wc + (NH) * 32 + nq * 16 + fr;                                   \
    int sw = rb & 7;                                                          \
    _Pragma("unroll") for (int k2 = 0; k2 < 2; ++k2)                          \
      bv[nq][k2] = *(const u16x8*)(sB[BUF] + rb * 64 +                        \
                                   ((((k2 << 2) | fg) ^ sw) << 3));           \
  }

#define MFMAQH(MH, NH)                                                        \
  __builtin_amdgcn_s_barrier();                                               \
  __builtin_amdgcn_s_setprio(1);                                              \
  _Pragma("unroll") for (int k2 = 0; k2 < 2; ++k2)                            \
    _Pragma("unroll") for (int mq = 0; mq < 2; ++mq)                          \
      _Pragma("unroll") for (int nq = 0; nq < 2; ++nq)                        \
        acc[(MH) * 2 + mq][(NH) * 2 + nq] =                                   \
            __builtin_amdgcn_mfma_f32_16x16x32_bf16(                          \
                as_bf(av[mq][k2]), as_bf(bv[nq][k2]),                         \
                acc[(MH) * 2 + mq][(NH) * 2 + nq], 0, 0, 0);                  \
  __builtin_amdgcn_s_setprio(0);

__global__ __launch_bounds__(256) void gemm128(const u16* __restrict__ A,
                                               const u16* __restrict__ B,
                                               float* __restrict__ C,
                                               const float* __restrict__ resid,
                                               int M, int N, int K) {
    extern __shared__ char smem[];
    const int tid = threadIdx.x, lane = tid & 63, wid = tid >> 6;
    const int bm = blockIdx.y * 128, bn = blockIdx.x * 128;
    const int wr = (wid >> 1) * 64, wc = (wid & 1) * 64;
    const int fr = lane & 15, fg = lane >> 4;

    u16* sA[2] = {(u16*)smem, (u16*)(smem + 32768)};
    u16* sB[2] = {(u16*)(smem + 16384), (u16*)(smem + 49152)};

    const int cs = (((tid & 7) ^ ((tid >> 3) & 7)) << 3);
    const int s8 = (tid & 7) << 3;
    const int rr5 = tid >> 3;

    auto stA = [&](int buf, int k0, int mh) {
#pragma unroll
        for (int j = 0; j < 2; ++j) {
            int r = j * 64 + mh * 32 + rr5;
            gload_lds16(A + (size_t)(bm + r) * K + k0 + cs, sA[buf] + r * 64 + s8);
        }
    };
    auto stB = [&](int buf, int k0, int nh) {
#pragma unroll
        for (int j = 0; j < 2; ++j) {
            int r = j * 64 + nh * 32 + rr5;
            gload_lds16(B + (size_t)(bn + r) * K + k0 + cs, sB[buf] + r * 64 + s8);
        }
    };

    f32x4 acc[4][4] = {};
    u16x8 av[2][2], bv[2][2];
    const int nt = K >> 6;

    stA(0, 0, 0); stA(0, 0, 1); stB(0, 0, 0); stB(0, 0, 1);
    stA(1, 64, 0); stB(1, 64, 1);
    VM4
    __builtin_amdgcn_s_barrier();
    __builtin_amdgcn_sched_barrier(0);

    for (int it = 0; it < (nt >> 1); ++it) {
        const int kc = it << 7;
        const int kn1 = kc + 64, kn2 = kc + 128, kn3 = kc + 192;
        const bool st2 = (kn2 < K), st3 = (kn3 < K);

        LDAH(0, 0) LDBH(0, 0)
        stA(1, kn1, 1);
        MFMAQH(0, 0) ENDP
        LDBH(0, 1)
        stB(1, kn1, 0);
        MFMAQH(0, 1) ENDP
        LDAH(0, 1)
        if (st2) stA(0, kn2, 0);
        MFMAQH(1, 1) ENDP
        LDBH(0, 0)
        if (st2) stB(0, kn2, 1);
        MFMAQH(1, 0)
        if (st2) { VM4 } else { VM0 }
        ENDP
        LDAH(1, 0) LDBH(1, 0)
        if (st2) stA(0, kn2, 1);
        MFMAQH(0, 0) ENDP
        LDBH(1, 1)
        if (st2) stB(0, kn2, 0);
        MFMAQH(0, 1) ENDP
        LDAH(1, 1)
        if (st3) stA(1, kn3, 0);
        MFMAQH(1, 1) ENDP
        LDBH(1, 0)
        if (st3) stB(1, kn3, 1);
        MFMAQH(1, 0)
        VM4
        ENDP
    }

#pragma unroll
    for (int am = 0; am < 4; ++am)
#pragma unroll
        for (int bq = 0; bq < 4; ++bq)
#pragma unroll
            for (int r = 0; r < 4; ++r) {
                int row = bm + wr + am * 16 + fg * 4 + r;
                int col = bn + wc + bq * 16 + fr;
                float val = acc[am][bq][r] + resid[(size_t)row * N + col];
                C[(size_t)row * N + col] = val;
            }
}

// ---------------- per-head RMSNorm + RoPE (vectorized, bf16 qkv) -----------
__global__ __launch_bounds__(256) void rope_split(const u16* __restrict__ qkv,
                                                  const float* __restrict__ cosb,
                                                  const float* __restrict__ sinb,
                                                  u16* __restrict__ q_bf,
                                                  u16* __restrict__ k_bf,
                                                  float* __restrict__ k_out,
                                                  float* __restrict__ v_out) {
    const int t = blockIdx.x, tid = threadIdx.x, wid = tid >> 6, lane = tid & 63;
    const u16* row = qkv + (size_t)t * (3 * DMODEL);
    const int dp = (lane & 31) << 1;
    float2 c2 = *(const float2*)(cosb + t * 64 + dp);
    float2 s2 = *(const float2*)(sinb + t * 64 + dp);
    const bool hi = lane >= 32;

    for (int task = wid; task < 32; task += 4) {
        u32 w = *(const u32*)(row + task * 128 + lane * 2);
        float xa = lo2f(w), xb = hi2f(w);
        float ss = xa * xa + xb * xb;
#pragma unroll
        for (int off = 32; off; off >>= 1) ss += __shfl_xor(ss, off);
        float rn = rsqrtf(ss * (1.f / 128.f) + 1e-6f);
        float pa = __shfl_xor(xa, 32), pb = __shfl_xor(xb, 32);
        float oa, ob;
        if (!hi) {
            oa = (xa * c2.x - pa * s2.x) * rn;
            ob = (xb * c2.y - pb * s2.y) * rn;
        } else {
            oa = (pa * s2.x + xa * c2.x) * rn;
            ob = (pb * s2.y + xb * c2.y) * rn;
        }
        u32 pk = (u32)f2bf(oa) | ((u32)f2bf(ob) << 16);
        if (task < 16) {
            *(u32*)(q_bf + ((size_t)task * T_SEQ + t) * 128 + lane * 2) = pk;
        } else {
            int hh = task - 16;
            *(u32*)(k_bf + ((size_t)hh * T_SEQ + t) * 128 + lane * 2) = pk;
            float2 kk; kk.x = oa; kk.y = ob;
            *(float2*)(k_out + (size_t)t * DMODEL + hh * 128 + lane * 2) = kk;
        }
    }
    {
        u16x8 vv = *(const u16x8*)(row + 2 * DMODEL + tid * 8);
        float4 f0, f1;
        f0.x = __builtin_bit_cast(float, (u32)vv[0] << 16);
        f0.y = __builtin_bit_cast(float, (u32)vv[1] << 16);
        f0.z = __builtin_bit_cast(float, (u32)vv[2] << 16);
        f0.w = __builtin_bit_cast(float, (u32)vv[3] << 16);
        f1.x = __builtin_bit_cast(float, (u32)vv[4] << 16);
        f1.y = __builtin_bit_cast(float, (u32)vv[5] << 16);
        f1.z = __builtin_bit_cast(float, (u32)vv[6] << 16);
        f1.w = __builtin_bit_cast(float, (u32)vv[7] << 16);
        *(float4*)(v_out + (size_t)t * DMODEL + tid * 8) = f0;
        *(float4*)(v_out + (size_t)t * DMODEL + tid * 8 + 4) = f1;
    }
}

// ---------------- V transpose: qkv bf16 -> vt bf16 [h][128][T] -------------
__global__ __launch_bounds__(256) void vtrans(const u16* __restrict__ qkv,
                                              u16* __restrict__ vt) {
    const int b = blockIdx.x, tid = threadIdx.x;
    const int head = b >> 7;
    const int i = (b & 127) * 256 + tid;
    const int d = i & 127, tc = i >> 7;
    u16x8 o;
#pragma unroll
    for (int j = 0; j < 8; ++j)
        o[j] = qkv[(size_t)(tc * 8 + j) * (3 * DMODEL) + 2 * DMODEL + head * 128 + d];
    *(u16x8*)&vt[((size_t)head * 128 + d) * T_SEQ + tc * 8] = o;
}

// ---------------- causal flash attention (round-6 exact) -------------------
__global__ __launch_bounds__(256) void attn_fwd(const u16* __restrict__ qb,
                                                const u16* __restrict__ kb,
                                                const u16* __restrict__ vtb,
                                                u16* __restrict__ xout) {
    __shared__ u16 Ks[2][64 * 128];
    __shared__ u16 Vs[2][128 * 64];
    __shared__ u16 Ps[4][16 * 64];

    const int bid = blockIdx.x;
    const int r8 = bid & 7, s = bid >> 3;
    const int head = r8 + ((s >> 5) << 3);
    const int j = s & 31;
    const int qt = (s < 32) ? (31 - j) : j;

    const int tid = threadIdx.x, wid = tid >> 6, lane = tid & 63;
    const int fr = lane & 15, fg = lane >> 4;
    const u16* kh = kb + (size_t)head * T_SEQ * 128;
    const u16* vth = vtb + (size_t)head * 128 * T_SEQ;
    const u16* qh = qb + (size_t)head * T_SEQ * 128;
    const int q0 = qt * 64 + wid * 16;
    const int qrow_g = q0 + fr;

    u16x8 bq[4];
    {
        const u16* qrow = qh + (size_t)(q0 + fr) * 128 + fg * 8;
#pragma unroll
        for (int cc = 0; cc < 4; ++cc) bq[cc] = *(const u16x8*)(qrow + cc * 32);
    }

    auto stage = [&](int kv0, int buf) {
#pragma unroll
        for (int i = 0; i < 4; ++i) {
            int idx = i * 256 + tid;
            int r = idx >> 4;
            int cbs = ((idx & 15) << 4) ^ ((r & 7) << 4);
            gload_lds16(kh + (size_t)(kv0 + r) * 128 + (cbs >> 1), &Ks[buf][idx * 8]);
        }
#pragma unroll
        for (int i = 0; i < 4; ++i) {
            int idx = i * 256 + tid;
            int d = idx >> 3;
            int cbs = ((idx & 7) << 4) ^ ((d & 7) << 4);
            gload_lds16(vth + (size_t)d * T_SEQ + kv0 + (cbs >> 1), &Vs[buf][idx * 8]);
        }
    };

    stage(0, 0);

    f32x4 o[8] = {};
    float m_run = -1e30f, l_run = 0.f;
    const int nt = qt + 1;

    for (int kt = 0; kt < nt; ++kt) {
        const int kv0 = kt * 64;
        const int buf = kt & 1;
        if (kt + 1 < nt) {
            stage(kv0 + 64, buf ^ 1);
            asm volatile("s_waitcnt vmcnt(8)" ::: "memory");
        } else {
            asm volatile("s_waitcnt vmcnt(0)" ::: "memory");
        }
        __builtin_amdgcn_s_barrier();
        __builtin_amdgcn_sched_barrier(0);

        const char* ksb = (const char*)&Ks[buf][0];
        const char* vsb = (const char*)&Vs[buf][0];
        char* psb = (char*)&Ps[wid][0];

        float p[4][4];
        float mx = -1e30f;
        const bool diag = (kv0 + 64 > q0);
#pragma unroll
        for (int st = 0; st < 4; ++st) {
            f32x4 sacc = {0.f, 0.f, 0.f, 0.f};
#pragma unroll
            for (int c4 = 0; c4 < 4; ++c4) {
                int r = st * 16 + fr;
                int cb = c4 * 64 + fg * 16;
                u16x8 ak = *(const u16x8*)(ksb + r * 256 + (cb ^ ((r & 7) << 4)));
                sacc = __builtin_amdgcn_mfma_f32_16x16x32_bf16(
                    as_bf(ak), as_bf(bq[c4]), sacc, 0, 0, 0);
            }
#pragma unroll
            for (int rr = 0; rr < 4; ++rr) {
                float sv = sacc[rr] * ATT_SCALE;
                if (diag) {
                    int kvg = kv0 + st * 16 + fg * 4 + rr;
                    sv = (kvg <= qrow_g) ? sv : -1e30f;
                }
                p[st][rr] = sv;
                mx = fmaxf(mx, sv);
            }
        }
        mx = fmaxf(mx, __shfl_xor(mx, 16));
        mx = fmaxf(mx, __shfl_xor(mx, 32));

        if (__all(mx - m_run <= 8.f)) {
            float rs = 0.f;
#pragma unroll
            for (int st = 0; st < 4; ++st) {
                u16x4 pw;
#pragma unroll
                for (int rr = 0; rr < 4; ++rr) {
                    float e = __expf(p[st][rr] - m_run);
                    rs += e;
                    pw[rr] = f2bf(e);
                }
                *(u16x4*)(psb + fr * 128 + ((st * 32 + fg * 8) ^ ((fr & 7) << 4))) = pw;
            }
            rs += __shfl_xor(rs, 16);
            rs += __shfl_xor(rs, 32);
            l_run += rs;
        } else {
            float m_new = fmaxf(m_run, mx);
            float corr = __expf(m_run - m_new);
            float rs = 0.f;
#pragma unroll
            for (int st = 0; st < 4; ++st) {
                u16x4 pw;
#pragma unroll
                for (int rr = 0; rr < 4; ++rr) {
                    float e = __expf(p[st][rr] - m_new);
                    rs += e;
                    pw[rr] = f2bf(e);
                }
                *(u16x4*)(psb + fr * 128 + ((st * 32 + fg * 8) ^ ((fr & 7) << 4))) = pw;
            }
            rs += __shfl_xor(rs, 16);
            rs += __shfl_xor(rs, 32);
            l_run = l_run * corr + rs;
            m_run = m_new;
            float ct[4];
#pragma unroll
            for (int rr = 0; rr < 4; ++rr) ct[rr] = __shfl(corr, fg * 4 + rr);
#pragma unroll
            for (int f = 0; f < 8; ++f)
#pragma unroll
                for (int rr = 0; rr < 4; ++rr) o[f][rr] *= ct[rr];
        }

#pragma unroll
        for (int ks = 0; ks < 2; ++ks) {
            u16x8 pa = *(const u16x8*)(psb + fr * 128 + ((ks * 64 + fg * 16) ^ ((fr & 7) << 4)));
#pragma unroll
            for (int f = 0; f < 8; ++f) {
                int d = f * 16 + fr;
                u16x8 vB = *(const u16x8*)(vsb + d * 128 + ((ks * 64 + fg * 16) ^ ((d & 7) << 4)));
                o[f] = __builtin_amdgcn_mfma_f32_16x16x32_bf16(
                    as_bf(pa), as_bf(vB), o[f], 0, 0, 0);
            }
        }
        __builtin_amdgcn_s_barrier();
    }

    float li[4];
#pragma unroll
    for (int rr = 0; rr < 4; ++rr) li[rr] = __shfl(l_run, fg * 4 + rr);
#pragma unroll
    for (int f = 0; f < 8; ++f)
#pragma unroll
        for (int rr = 0; rr < 4; ++rr) {
            int trow = q0 + fg * 4 + rr;
            float val = o[f][rr] / li[rr];
            xout[(size_t)trow * DMODEL + head * 128 + f * 16 + fr] = f2bf(val);
        }
}

extern "C" void kernel_launch(void* const* d_in, const int* in_sizes, int n_in,
                              void* d_out, int out_size, void* d_ws, size_t ws_size,
                              hipStream_t stream) {
    const float* x_in = (const float*)d_in[0];
    const float* w_qkv = (const float*)d_in[1];
    const float* w_o = (const float*)d_in[2];
    const float* cosb = (const float*)d_in[3];
    const float* sinb = (const float*)d_in[4];

    float* out = (float*)d_out;
    float* k_out = out + 4194304;
    float* v_out = out + 8388608;

    char* ws = (char*)d_ws;
    u16* xn    = (u16*)(ws);                         // 8 MiB  [T][D] bf16
    u16* w_bf  = (u16*)(ws + (size_t)(8u << 20));    // 24 MiB [3D][D] bf16
    u16* o_bf  = (u16*)(ws + (size_t)(32u << 20));   // 8 MiB  [D][D] bf16
    u16* qkv   = (u16*)(ws + (size_t)(40u << 20));   // 24 MiB [T][3D] bf16
    u16* q_bf  = (u16*)(ws + (size_t)(64u << 20));   // 8 MiB  [h][T][hd]
    u16* k_bf  = (u16*)(ws + (size_t)(72u << 20));   // 8 MiB
    u16* vt_bf = (u16*)(ws + (size_t)(80u << 20));   // 8 MiB  [h][hd][T]
    u16* x_bf  = (u16*)(ws + (size_t)(88u << 20));   // 8 MiB  [T][D]

    (void)hipFuncSetAttribute(reinterpret_cast<const void*>(&gemm192),
                              hipFuncAttributeMaxDynamicSharedMemorySize, 114688);
    (void)hipFuncSetAttribute(reinterpret_cast<const void*>(&gemm128),
                              hipFuncAttributeMaxDynamicSharedMemorySize, 65536);

    prep<<<10240, 256, 0, stream>>>(w_qkv, w_o, x_in, w_bf, o_bf, xn);
    gemm192<<<dim3(32, 8), 512, 114688, stream>>>(xn, w_bf, qkv, 2048, 6144, 2048);
    rope_split<<<2048, 256, 0, stream>>>(qkv, cosb, sinb, q_bf, k_bf, k_out, v_out);
    vtrans<<<2048, 256, 0, stream>>>(qkv, vt_bf);
    attn_fwd<<<512, 256, 0, stream>>>(q_bf, k_bf, vt_bf, x_bf);
    gemm128<<<dim3(16, 16), 256, 65536, stream>>>(x_bf, o_bf, out, x_in, 2048, 2048, 2048);
}

// Round 12
// 176.967 us; speedup vs baseline: 1.3494x; 1.0134x over previous
//
#include <hip/hip_runtime.h>
#include <hip/hip_bf16.h>

typedef unsigned short u16;
typedef unsigned int u32;
typedef __bf16 bf16x8 __attribute__((ext_vector_type(8)));
typedef u16 u16x8 __attribute__((ext_vector_type(8)));
typedef u16 u16x4 __attribute__((ext_vector_type(4)));
typedef float f32x4 __attribute__((ext_vector_type(4)));

#define T_SEQ 2048
#define DMODEL 2048
#define NHEAD 16
#define HDIM 128
#define ATT_SCALE 0.08838834764831843f

__device__ __forceinline__ u16 f2bf(float f) {
    return __builtin_bit_cast(u16, __float2bfloat16(f));
}
__device__ __forceinline__ bf16x8 as_bf(u16x8 v) {
    return __builtin_bit_cast(bf16x8, v);
}
__device__ __forceinline__ float lo2f(u32 w) { return __builtin_bit_cast(float, w << 16); }
__device__ __forceinline__ float hi2f(u32 w) { return __builtin_bit_cast(float, w & 0xffff0000u); }
__device__ __forceinline__ float bf2f(u16 v) { return __builtin_bit_cast(float, (u32)v << 16); }
__device__ __forceinline__ void gload_lds16(const u16* g, u16* l) {
    __builtin_amdgcn_global_load_lds(
        (const __attribute__((address_space(1))) u32*)(g),
        (__attribute__((address_space(3))) u32*)(l), 16, 0, 0);
}

// ------- fused prep: weight casts (blocks 0..8191) + RMSNorm (8192..10239) --
__global__ __launch_bounds__(256) void prep(const float* __restrict__ w1,
                                            const float* __restrict__ w2,
                                            const float* __restrict__ x,
                                            u16* __restrict__ d1,
                                            u16* __restrict__ d2,
                                            u16* __restrict__ xn) {
    const int b = blockIdx.x, tid = threadIdx.x;
    if (b < 8192) {
        int i = b * 256 + tid;
        const float* src; u16* dst; int k;
        if (i < 1572864) { src = w1; dst = d1; k = i; }
        else             { src = w2; dst = d2; k = i - 1572864; }
        float4 a = ((const float4*)src)[2 * k];
        float4 bb = ((const float4*)src)[2 * k + 1];
        u16x8 o;
        o[0] = f2bf(a.x); o[1] = f2bf(a.y); o[2] = f2bf(a.z); o[3] = f2bf(a.w);
        o[4] = f2bf(bb.x); o[5] = f2bf(bb.y); o[6] = f2bf(bb.z); o[7] = f2bf(bb.w);
        *(u16x8*)(dst + (size_t)k * 8) = o;
        return;
    }
    const int row = b - 8192;
    const float* xr = x + (size_t)row * DMODEL;
    float4 a = ((const float4*)xr)[2 * tid];
    float4 bb = ((const float4*)xr)[2 * tid + 1];
    float ss = a.x*a.x + a.y*a.y + a.z*a.z + a.w*a.w
             + bb.x*bb.x + bb.y*bb.y + bb.z*bb.z + bb.w*bb.w;
#pragma unroll
    for (int off = 32; off; off >>= 1) ss += __shfl_xor(ss, off);
    __shared__ float red[4];
    if ((tid & 63) == 0) red[tid >> 6] = ss;
    __syncthreads();
    float tot = red[0] + red[1] + red[2] + red[3];
    float r = rsqrtf(tot * (1.f / DMODEL) + 1e-6f);
    u16x8 o;
    o[0] = f2bf(a.x*r); o[1] = f2bf(a.y*r); o[2] = f2bf(a.z*r); o[3] = f2bf(a.w*r);
    o[4] = f2bf(bb.x*r); o[5] = f2bf(bb.y*r); o[6] = f2bf(bb.z*r); o[7] = f2bf(bb.w*r);
    *(u16x8*)(xn + (size_t)row * DMODEL + tid * 8) = o;
}

// ================= shared 8-phase GEMM machinery ===========================
#define VM2 asm volatile("s_waitcnt vmcnt(2)" ::: "memory");
#define VM4 asm volatile("s_waitcnt vmcnt(4)" ::: "memory");
#define VM0 asm volatile("s_waitcnt vmcnt(0)" ::: "memory");

#define ENDP                                                                  \
  __builtin_amdgcn_s_barrier();                                               \
  __builtin_amdgcn_sched_barrier(0);

// ---- 256x192 variant for qkv (grid 32x8 = 256 blocks = 1/CU) ----
#define LDA192(BUF, MH)                                                       \
  _Pragma("unroll") for (int mq = 0; mq < 4; ++mq) {                          \
    int ra = wr + (MH) * 64 + mq * 16 + fr;                                   \
    int sw = ra & 7;                                                          \
    _Pragma("unroll") for (int k2 = 0; k2 < 2; ++k2)                          \
      av[mq][k2] = *(const u16x8*)(sA[BUF] + ra * 64 +                        \
                                   ((((k2 << 2) | fg) ^ sw) << 3));           \
  }

#define LDB0_192(BUF)                                                         \
  _Pragma("unroll") for (int nq = 0; nq < 2; ++nq) {                          \
    int rb = wc + nq * 16 + fr;                                               \
    int sw = rb & 7;                                                          \
    _Pragma("unroll") for (int k2 = 0; k2 < 2; ++k2)                          \
      bv[nq][k2] = *(const u16x8*)(sB[BUF] + rb * 64 +                        \
                                   ((((k2 << 2) | fg) ^ sw) << 3));           \
  }

#define LDB1_192(BUF)                                                         \
  {                                                                           \
    int rb = wc + 32 + fr;                                                    \
    int sw = rb & 7;                                                          \
    _Pragma("unroll") for (int k2 = 0; k2 < 2; ++k2)                          \
      bv1[k2] = *(const u16x8*)(sB[BUF] + rb * 64 +                           \
                                ((((k2 << 2) | fg) ^ sw) << 3));              \
  }

#define MFMAQ_N0(MH)                                                          \
  __builtin_amdgcn_s_barrier();                                               \
  __builtin_amdgcn_s_setprio(1);                                              \
  _Pragma("unroll") for (int k2 = 0; k2 < 2; ++k2)                            \
    _Pragma("unroll") for (int mq = 0; mq < 4; ++mq)                          \
      _Pragma("unroll") for (int nq = 0; nq < 2; ++nq)                        \
        acc[(MH) * 4 + mq][nq] = __builtin_amdgcn_mfma_f32_16x16x32_bf16(     \
            as_bf(av[mq][k2]), as_bf(bv[nq][k2]), acc[(MH) * 4 + mq][nq],     \
            0, 0, 0);                                                         \
  __builtin_amdgcn_s_setprio(0);

#define MFMAQ_N1(MH)                                                          \
  __builtin_amdgcn_s_barrier();                                               \
  __builtin_amdgcn_s_setprio(1);                                              \
  _Pragma("unroll") for (int k2 = 0; k2 < 2; ++k2)                            \
    _Pragma("unroll") for (int mq = 0; mq < 4; ++mq)                          \
      acc[(MH) * 4 + mq][2] = __builtin_amdgcn_mfma_f32_16x16x32_bf16(        \
          as_bf(av[mq][k2]), as_bf(bv1[k2]), acc[(MH) * 4 + mq][2],           \
          0, 0, 0);                                                           \
  __builtin_amdgcn_s_setprio(0);

__global__ __launch_bounds__(512) void gemm192(const u16* __restrict__ A,
                                               const u16* __restrict__ B,
                                               u16* __restrict__ C,
                                               int M, int N, int K) {
    extern __shared__ char smem[];
    const int tid = threadIdx.x, lane = tid & 63, wid = tid >> 6;
    const int bm = blockIdx.y * 256, bn = blockIdx.x * 192;
    const int wr = (wid >> 2) * 128, wc = (wid & 3) * 48;
    const int fr = lane & 15, fg = lane >> 4;

    u16* sA[2] = {(u16*)smem, (u16*)(smem + 57344)};
    u16* sB[2] = {(u16*)(smem + 32768), (u16*)(smem + 90112)};

    const int cs = (((tid & 7) ^ ((tid >> 3) & 7)) << 3);
    const int s8 = (tid & 7) << 3;
    const int rr6 = tid >> 3;

    auto stA = [&](int buf, int k0, int mh) {
#pragma unroll
        for (int j = 0; j < 2; ++j) {
            int r = j * 128 + mh * 64 + rr6;
            gload_lds16(A + (size_t)(bm + r) * K + k0 + cs, sA[buf] + r * 64 + s8);
        }
    };
    auto stB = [&](int buf, int k0, int bt) {
        int r = bt * 64 + rr6;
        gload_lds16(B + (size_t)(bn + r) * K + k0 + cs, sB[buf] + r * 64 + s8);
    };

    f32x4 acc[8][3] = {};
    u16x8 av[4][2], bv[2][2], bv1[2];
    const int nt = K >> 6;

    stA(0, 0, 0); stA(0, 0, 1); stB(0, 0, 0); stB(0, 0, 1); stB(0, 0, 2);
    stA(1, 64, 0);
    VM2
    __builtin_amdgcn_s_barrier();
    __builtin_amdgcn_sched_barrier(0);

    for (int it = 0; it < (nt >> 1); ++it) {
        const int kc = it << 7;
        const int kn1 = kc + 64, kn2 = kc + 128, kn3 = kc + 192;
        const bool st2 = (kn2 < K), st3 = (kn3 < K);

        LDA192(0, 0) LDB0_192(0)
        stA(1, kn1, 1); stB(1, kn1, 0);
        MFMAQ_N0(0) ENDP
        LDB1_192(0)
        stB(1, kn1, 1); stB(1, kn1, 2);
        MFMAQ_N1(0) ENDP
        LDA192(0, 1)
        if (st2) stA(0, kn2, 0);
        MFMAQ_N1(1) ENDP
        LDB0_192(0)
        MFMAQ_N0(1)
        if (st2) { VM2 } else { VM0 }
        ENDP
        LDA192(1, 0) LDB0_192(1)
        if (st2) { stA(0, kn2, 1); stB(0, kn2, 0); }
        MFMAQ_N0(0) ENDP
        LDB1_192(1)
        if (st2) { stB(0, kn2, 1); stB(0, kn2, 2); }
        MFMAQ_N1(0) ENDP
        LDA192(1, 1)
        if (st3) stA(1, kn3, 0);
        MFMAQ_N1(1) ENDP
        LDB0_192(1)
        MFMAQ_N0(1)
        if (st3) { VM2 } else { VM0 }
        ENDP
    }

#pragma unroll
    for (int am = 0; am < 8; ++am)
#pragma unroll
        for (int bq = 0; bq < 3; ++bq)
#pragma unroll
            for (int r = 0; r < 4; ++r) {
                int row = bm + wr + am * 16 + fg * 4 + r;
                int col = bn + wc + bq * 16 + fr;
                C[(size_t)row * N + col] = f2bf(acc[am][bq][r]);
            }
}

// ---- 128x128 8-phase variant for out-proj (resid epilogue) ----
#define LDAH(BUF, MH)                                                         \
  _Pragma("unroll") for (int mq = 0; mq < 2; ++mq) {                          \
    int ra = wr + (MH) * 32 + mq * 16 + fr;                                   \
    int sw = ra & 7;                                                          \
    _Pragma("unroll") for (int k2 = 0; k2 < 2; ++k2)                          \
      av[mq][k2] = *(const u16x8*)(sA[BUF] + ra * 64 +                        \
                                   ((((k2 << 2) | fg) ^ sw) << 3));           \
  }

#define LDBH(BUF, NH)                                                         \
  _Pragma("unroll") for (int nq = 0; nq < 2; ++nq) {                          \
    int rb = wc + (NH) * 32 + nq * 16 + fr;                                   \
    int sw = rb & 7;                                                          \
    _Pragma("unroll") for (int k2 = 0; k2 < 2; ++k2)                          \
      bv[nq][k2] = *(const u16x8*)(sB[BUF] + rb * 64 +                        \
                                   ((((k2 << 2) | fg) ^ sw) << 3));           \
  }

#define MFMAQH(MH, NH)                                                        \
  __builtin_amdgcn_s_barrier();                                               \
  __builtin_amdgcn_s_setprio(1);                                              \
  _Pragma("unroll") for (int k2 = 0; k2 < 2; ++k2)                            \
    _Pragma("unroll") for (int mq = 0; mq < 2; ++mq)                          \
      _Pragma("unroll") for (int nq = 0; nq < 2; ++nq)                        \
        acc[(MH) * 2 + mq][(NH) * 2 + nq] =                                   \
            __builtin_amdgcn_mfma_f32_16x16x32_bf16(                          \
                as_bf(av[mq][k2]), as_bf(bv[nq][k2]),                         \
                acc[(MH) * 2 + mq][(NH) * 2 + nq], 0, 0, 0);                  \
  __builtin_amdgcn_s_setprio(0);

__global__ __launch_bounds__(256) void gemm128(const u16* __restrict__ A,
                                               const u16* __restrict__ B,
                                               float* __restrict__ C,
                                               const float* __restrict__ resid,
                                               int M, int N, int K) {
    extern __shared__ char smem[];
    const int tid = threadIdx.x, lane = tid & 63, wid = tid >> 6;
    const int bm = blockIdx.y * 128, bn = blockIdx.x * 128;
    const int wr = (wid >> 1) * 64, wc = (wid & 1) * 64;
    const int fr = lane & 15, fg = lane >> 4;

    u16* sA[2] = {(u16*)smem, (u16*)(smem + 32768)};
    u16* sB[2] = {(u16*)(smem + 16384), (u16*)(smem + 49152)};

    const int cs = (((tid & 7) ^ ((tid >> 3) & 7)) << 3);
    const int s8 = (tid & 7) << 3;
    const int rr5 = tid >> 3;

    auto stA = [&](int buf, int k0, int mh) {
#pragma unroll
        for (int j = 0; j < 2; ++j) {
            int r = j * 64 + mh * 32 + rr5;
            gload_lds16(A + (size_t)(bm + r) * K + k0 + cs, sA[buf] + r * 64 + s8);
        }
    };
    auto stB = [&](int buf, int k0, int nh) {
#pragma unroll
        for (int j = 0; j < 2; ++j) {
            int r = j * 64 + nh * 32 + rr5;
            gload_lds16(B + (size_t)(bn + r) * K + k0 + cs, sB[buf] + r * 64 + s8);
        }
    };

    f32x4 acc[4][4] = {};
    u16x8 av[2][2], bv[2][2];
    const int nt = K >> 6;

    stA(0, 0, 0); stA(0, 0, 1); stB(0, 0, 0); stB(0, 0, 1);
    stA(1, 64, 0); stB(1, 64, 1);
    VM4
    __builtin_amdgcn_s_barrier();
    __builtin_amdgcn_sched_barrier(0);

    for (int it = 0; it < (nt >> 1); ++it) {
        const int kc = it << 7;
        const int kn1 = kc + 64, kn2 = kc + 128, kn3 = kc + 192;
        const bool st2 = (kn2 < K), st3 = (kn3 < K);

        LDAH(0, 0) LDBH(0, 0)
        stA(1, kn1, 1);
        MFMAQH(0, 0) ENDP
        LDBH(0, 1)
        stB(1, kn1, 0);
        MFMAQH(0, 1) ENDP
        LDAH(0, 1)
        if (st2) stA(0, kn2, 0);
        MFMAQH(1, 1) ENDP
        LDBH(0, 0)
        if (st2) stB(0, kn2, 1);
        MFMAQH(1, 0)
        if (st2) { VM4 } else { VM0 }
        ENDP
        LDAH(1, 0) LDBH(1, 0)
        if (st2) stA(0, kn2, 1);
        MFMAQH(0, 0) ENDP
        LDBH(1, 1)
        if (st2) stB(0, kn2, 0);
        MFMAQH(0, 1) ENDP
        LDAH(1, 1)
        if (st3) stA(1, kn3, 0);
        MFMAQH(1, 1) ENDP
        LDBH(1, 0)
        if (st3) stB(1, kn3, 1);
        MFMAQH(1, 0)
        VM4
        ENDP
    }

#pragma unroll
    for (int am = 0; am < 4; ++am)
#pragma unroll
        for (int bq = 0; bq < 4; ++bq)
#pragma unroll
            for (int r = 0; r < 4; ++r) {
                int row = bm + wr + am * 16 + fg * 4 + r;
                int col = bn + wc + bq * 16 + fr;
                float val = acc[am][bq][r] + resid[(size_t)row * N + col];
                C[(size_t)row * N + col] = val;
            }
}

// ---------------- per-head RMSNorm + RoPE (vectorized, bf16 qkv) -----------
__global__ __launch_bounds__(256) void rope_split(const u16* __restrict__ qkv,
                                                  const float* __restrict__ cosb,
                                                  const float* __restrict__ sinb,
                                                  u16* __restrict__ q_bf,
                                                  u16* __restrict__ k_bf,
                                                  float* __restrict__ k_out,
                                                  float* __restrict__ v_out) {
    const int t = blockIdx.x, tid = threadIdx.x, wid = tid >> 6, lane = tid & 63;
    const u16* row = qkv + (size_t)t * (3 * DMODEL);
    const int dp = (lane & 31) << 1;
    float2 c2 = *(const float2*)(cosb + t * 64 + dp);
    float2 s2 = *(const float2*)(sinb + t * 64 + dp);
    const bool hi = lane >= 32;

    for (int task = wid; task < 32; task += 4) {
        u32 w = *(const u32*)(row + task * 128 + lane * 2);
        float xa = lo2f(w), xb = hi2f(w);
        float ss = xa * xa + xb * xb;
#pragma unroll
        for (int off = 32; off; off >>= 1) ss += __shfl_xor(ss, off);
        float rn = rsqrtf(ss * (1.f / 128.f) + 1e-6f);
        float pa = __shfl_xor(xa, 32), pb = __shfl_xor(xb, 32);
        float oa, ob;
        if (!hi) {
            oa = (xa * c2.x - pa * s2.x) * rn;
            ob = (xb * c2.y - pb * s2.y) * rn;
        } else {
            oa = (pa * s2.x + xa * c2.x) * rn;
            ob = (pb * s2.y + xb * c2.y) * rn;
        }
        u32 pk = (u32)f2bf(oa) | ((u32)f2bf(ob) << 16);
        if (task < 16) {
            *(u32*)(q_bf + ((size_t)task * T_SEQ + t) * 128 + lane * 2) = pk;
        } else {
            int hh = task - 16;
            *(u32*)(k_bf + ((size_t)hh * T_SEQ + t) * 128 + lane * 2) = pk;
            float2 kk; kk.x = oa; kk.y = ob;
            *(float2*)(k_out + (size_t)t * DMODEL + hh * 128 + lane * 2) = kk;
        }
    }
    {
        u16x8 vv = *(const u16x8*)(row + 2 * DMODEL + tid * 8);
        float4 f0, f1;
        f0.x = bf2f(vv[0]); f0.y = bf2f(vv[1]); f0.z = bf2f(vv[2]); f0.w = bf2f(vv[3]);
        f1.x = bf2f(vv[4]); f1.y = bf2f(vv[5]); f1.z = bf2f(vv[6]); f1.w = bf2f(vv[7]);
        *(float4*)(v_out + (size_t)t * DMODEL + tid * 8) = f0;
        *(float4*)(v_out + (size_t)t * DMODEL + tid * 8 + 4) = f1;
    }
}

// ---------------- V transpose: qkv bf16 -> vt bf16 [h][128][T] -------------
__global__ __launch_bounds__(256) void vtrans(const u16* __restrict__ qkv,
                                              u16* __restrict__ vt) {
    const int b = blockIdx.x, tid = threadIdx.x;
    const int head = b >> 7;
    const int i = (b & 127) * 256 + tid;
    const int d = i & 127, tc = i >> 7;
    u16x8 o;
#pragma unroll
    for (int j = 0; j < 8; ++j)
        o[j] = qkv[(size_t)(tc * 8 + j) * (3 * DMODEL) + 2 * DMODEL + head * 128 + d];
    *(u16x8*)&vt[((size_t)head * 128 + d) * T_SEQ + tc * 8] = o;
}

// ---------------- causal flash attention, kv-split partials ----------------
// 1024 blocks: r8=bid&7 (XCD residue -> heads {r8, r8+8}); s=bid>>3 in 0..127:
// hs=s>>6, g=(s>>5)&1, m=s&31. head=r8+8*hs; qt = g ? 31-m : m; half=g.
// half0 kv-tiles [0, ceil(nt/2)), half1 [ceil(nt/2), nt) -> per-CU work
// balanced (~16.5 tiles/slot). Single-buffer LDS (40960B) -> 4 blocks/CU,
// 16 waves/CU TLP hides vmcnt(0). Writes bf16 O-partials + (m,l); merged by
// attn_merge.
__global__ __launch_bounds__(256) void attn_part(const u16* __restrict__ qb,
                                                 const u16* __restrict__ kb,
                                                 const u16* __restrict__ vtb,
                                                 u16* __restrict__ opart,
                                                 float* __restrict__ ml) {
    __shared__ u16 Ks[64 * 128];
    __shared__ u16 Vs[128 * 64];
    __shared__ u16 Ps[4][16 * 64];

    const int bid = blockIdx.x;
    const int r8 = bid & 7, s = bid >> 3;
    const int hs = s >> 6, g = (s >> 5) & 1, m = s & 31;
    const int head = r8 + (hs << 3);
    const int qt = g ? (31 - m) : m;
    const int nt = qt + 1;
    const int h0c = (nt + 1) >> 1;
    const int first = g ? h0c : 0;
    const int count = g ? (nt - h0c) : h0c;
    const int pidx = (head * 32 + qt) * 2 + g;

    const int tid = threadIdx.x, wid = tid >> 6, lane = tid & 63;
    const int fr = lane & 15, fg = lane >> 4;
    const u16* kh = kb + (size_t)head * T_SEQ * 128;
    const u16* vth = vtb + (size_t)head * 128 * T_SEQ;
    const u16* qh = qb + (size_t)head * T_SEQ * 128;
    const int q0 = qt * 64 + wid * 16;
    const int qrow_g = q0 + fr;

    u16x8 bq[4];
    {
        const u16* qrow = qh + (size_t)(q0 + fr) * 128 + fg * 8;
#pragma unroll
        for (int cc = 0; cc < 4; ++cc) bq[cc] = *(const u16x8*)(qrow + cc * 32);
    }

    auto stage = [&](int kv0) {
#pragma unroll
        for (int i = 0; i < 4; ++i) {
            int idx = i * 256 + tid;
            int r = idx >> 4;
            int cbs = ((idx & 15) << 4) ^ ((r & 7) << 4);
            gload_lds16(kh + (size_t)(kv0 + r) * 128 + (cbs >> 1), &Ks[idx * 8]);
        }
#pragma unroll
        for (int i = 0; i < 4; ++i) {
            int idx = i * 256 + tid;
            int d = idx >> 3;
            int cbs = ((idx & 7) << 4) ^ ((d & 7) << 4);
            gload_lds16(vth + (size_t)d * T_SEQ + kv0 + (cbs >> 1), &Vs[idx * 8]);
        }
    };

    f32x4 o[8] = {};
    float m_run = -1e30f, l_run = 0.f;

    for (int i = 0; i < count; ++i) {
        const int kv0 = (first + i) * 64;
        stage(kv0);
        asm volatile("s_waitcnt vmcnt(0)" ::: "memory");
        __builtin_amdgcn_s_barrier();
        __builtin_amdgcn_sched_barrier(0);

        const char* ksb = (const char*)&Ks[0];
        const char* vsb = (const char*)&Vs[0];
        char* psb = (char*)&Ps[wid][0];

        float p[4][4];
        float mx = -1e30f;
        const bool diag = (kv0 + 64 > q0);
#pragma unroll
        for (int st = 0; st < 4; ++st) {
            f32x4 sacc = {0.f, 0.f, 0.f, 0.f};
#pragma unroll
            for (int c4 = 0; c4 < 4; ++c4) {
                int r = st * 16 + fr;
                int cb = c4 * 64 + fg * 16;
                u16x8 ak = *(const u16x8*)(ksb + r * 256 + (cb ^ ((r & 7) << 4)));
                sacc = __builtin_amdgcn_mfma_f32_16x16x32_bf16(
                    as_bf(ak), as_bf(bq[c4]), sacc, 0, 0, 0);
            }
#pragma unroll
            for (int rr = 0; rr < 4; ++rr) {
                float sv = sacc[rr] * ATT_SCALE;
                if (diag) {
                    int kvg = kv0 + st * 16 + fg * 4 + rr;
                    sv = (kvg <= qrow_g) ? sv : -1e30f;
                }
                p[st][rr] = sv;
                mx = fmaxf(mx, sv);
            }
        }
        mx = fmaxf(mx, __shfl_xor(mx, 16));
        mx = fmaxf(mx, __shfl_xor(mx, 32));

        if (__all(mx - m_run <= 8.f)) {
            float rs = 0.f;
#pragma unroll
            for (int st = 0; st < 4; ++st) {
                u16x4 pw;
#pragma unroll
                for (int rr = 0; rr < 4; ++rr) {
                    float e = __expf(p[st][rr] - m_run);
                    rs += e;
                    pw[rr] = f2bf(e);
                }
                *(u16x4*)(psb + fr * 128 + ((st * 32 + fg * 8) ^ ((fr & 7) << 4))) = pw;
            }
            rs += __shfl_xor(rs, 16);
            rs += __shfl_xor(rs, 32);
            l_run += rs;
        } else {
            float m_new = fmaxf(m_run, mx);
            float corr = __expf(m_run - m_new);
            float rs = 0.f;
#pragma unroll
            for (int st = 0; st < 4; ++st) {
                u16x4 pw;
#pragma unroll
                for (int rr = 0; rr < 4; ++rr) {
                    float e = __expf(p[st][rr] - m_new);
                    rs += e;
                    pw[rr] = f2bf(e);
                }
                *(u16x4*)(psb + fr * 128 + ((st * 32 + fg * 8) ^ ((fr & 7) << 4))) = pw;
            }
            rs += __shfl_xor(rs, 16);
            rs += __shfl_xor(rs, 32);
            l_run = l_run * corr + rs;
            m_run = m_new;
            float ct[4];
#pragma unroll
            for (int rr = 0; rr < 4; ++rr) ct[rr] = __shfl(corr, fg * 4 + rr);
#pragma unroll
            for (int f = 0; f < 8; ++f)
#pragma unroll
                for (int rr = 0; rr < 4; ++rr) o[f][rr] *= ct[rr];
        }

#pragma unroll
        for (int ks = 0; ks < 2; ++ks) {
            u16x8 pa = *(const u16x8*)(psb + fr * 128 + ((ks * 64 + fg * 16) ^ ((fr & 7) << 4)));
#pragma unroll
            for (int f = 0; f < 8; ++f) {
                int d = f * 16 + fr;
                u16x8 vB = *(const u16x8*)(vsb + d * 128 + ((ks * 64 + fg * 16) ^ ((d & 7) << 4)));
                o[f] = __builtin_amdgcn_mfma_f32_16x16x32_bf16(
                    as_bf(pa), as_bf(vB), o[f], 0, 0, 0);
            }
        }
        __builtin_amdgcn_s_barrier();       // all waves done reading before next stage
        __builtin_amdgcn_sched_barrier(0);
    }

    // partial epilogue: O (bf16, unnormalized) + per-row m,l
    u16* op = opart + (size_t)pidx * 8192;
#pragma unroll
    for (int f = 0; f < 8; ++f)
#pragma unroll
        for (int rr = 0; rr < 4; ++rr)
            op[(wid * 16 + fg * 4 + rr) * 128 + f * 16 + fr] = f2bf(o[f][rr]);
    if (fg == 0) {
        ml[pidx * 128 + wid * 16 + fr] = m_run;
        ml[pidx * 128 + 64 + wid * 16 + fr] = l_run;
    }
}

// ---------------- merge kv-split partials -> x_bf --------------------------
// 512 blocks = (head, qt); 256 thr: 4 thr/row x 32 d each.
__global__ __launch_bounds__(256) void attn_merge(const u16* __restrict__ opart,
                                                  const float* __restrict__ ml,
                                                  u16* __restrict__ xout) {
    const int b = blockIdx.x, tid = threadIdx.x;
    const int head = b >> 5, qt = b & 31;
    const int p0 = b * 2, p1 = b * 2 + 1;
    const int row = tid >> 2, d0 = (tid & 3) * 32;

    float m0 = ml[p0 * 128 + row], l0 = ml[p0 * 128 + 64 + row];
    float m1 = ml[p1 * 128 + row], l1 = ml[p1 * 128 + 64 + row];
    float M = fmaxf(m0, m1);
    float w0 = __expf(m0 - M), w1 = __expf(m1 - M);
    float inv = 1.f / (l0 * w0 + l1 * w1);
    w0 *= inv; w1 *= inv;

    const u16* a0 = opart + (size_t)p0 * 8192 + row * 128 + d0;
    const u16* a1 = opart + (size_t)p1 * 8192 + row * 128 + d0;
    u16* dst = xout + (size_t)(qt * 64 + row) * DMODEL + head * 128 + d0;
#pragma unroll
    for (int j = 0; j < 4; ++j) {
        u16x8 v0 = *(const u16x8*)(a0 + j * 8);
        u16x8 v1 = *(const u16x8*)(a1 + j * 8);
        u16x8 ov;
#pragma unroll
        for (int e = 0; e < 8; ++e)
            ov[e] = f2bf(bf2f(v0[e]) * w0 + bf2f(v1[e]) * w1);
        *(u16x8*)(dst + j * 8) = ov;
    }
}

extern "C" void kernel_launch(void* const* d_in, const int* in_sizes, int n_in,
                              void* d_out, int out_size, void* d_ws, size_t ws_size,
                              hipStream_t stream) {
    const float* x_in = (const float*)d_in[0];
    const float* w_qkv = (const float*)d_in[1];
    const float* w_o = (const float*)d_in[2];
    const float* cosb = (const float*)d_in[3];
    const float* sinb = (const float*)d_in[4];

    float* out = (float*)d_out;
    float* k_out = out + 4194304;
    float* v_out = out + 8388608;

    char* ws = (char*)d_ws;
    u16* xn    = (u16*)(ws);                         // 8 MiB  [T][D] bf16
    u16* w_bf  = (u16*)(ws + (size_t)(8u << 20));    // 24 MiB [3D][D] bf16
    u16* o_bf  = (u16*)(ws + (size_t)(32u << 20));   // 8 MiB  [D][D] bf16
    u16* qkv   = (u16*)(ws + (size_t)(40u << 20));   // 24 MiB [T][3D] bf16
    u16* q_bf  = (u16*)(ws + (size_t)(64u << 20));   // 8 MiB  [h][T][hd]
    u16* k_bf  = (u16*)(ws + (size_t)(72u << 20));   // 8 MiB
    u16* vt_bf = (u16*)(ws + (size_t)(80u << 20));   // 8 MiB  [h][hd][T]
    u16* x_bf  = (u16*)(ws + (size_t)(88u << 20));   // 8 MiB  [T][D]
    // attn partials alias the qkv region (dead after vtrans):
    u16* opart = (u16*)(ws + (size_t)(40u << 20));   // 16 MiB [1024][64][128] bf16
    float* mlb = (float*)(ws + (size_t)(56u << 20)); // 512 KiB [1024][2][64]

    (void)hipFuncSetAttribute(reinterpret_cast<const void*>(&gemm192),
                              hipFuncAttributeMaxDynamicSharedMemorySize, 114688);
    (void)hipFuncSetAttribute(reinterpret_cast<const void*>(&gemm128),
                              hipFuncAttributeMaxDynamicSharedMemorySize, 65536);

    prep<<<10240, 256, 0, stream>>>(w_qkv, w_o, x_in, w_bf, o_bf, xn);
    gemm192<<<dim3(32, 8), 512, 114688, stream>>>(xn, w_bf, qkv, 2048, 6144, 2048);
    rope_split<<<2048, 256, 0, stream>>>(qkv, cosb, sinb, q_bf, k_bf, k_out, v_out);
    vtrans<<<2048, 256, 0, stream>>>(qkv, vt_bf);
    attn_part<<<1024, 256, 0, stream>>>(q_bf, k_bf, vt_bf, opart, mlb);
    attn_merge<<<512, 256, 0, stream>>>(opart, mlb, x_bf);
    gemm128<<<dim3(16, 16), 256, 65536, stream>>>(x_bf, o_bf, out, x_in, 2048, 2048, 2048);
}

// Round 13
// 176.952 us; speedup vs baseline: 1.3495x; 1.0001x over previous
//
#include <hip/hip_runtime.h>
#include <hip/hip_bf16.h>

typedef unsigned short u16;
typedef unsigned int u32;
typedef __bf16 bf16x8 __attribute__((ext_vector_type(8)));
typedef u16 u16x8 __attribute__((ext_vector_type(8)));
typedef u16 u16x4 __attribute__((ext_vector_type(4)));
typedef float f32x4 __attribute__((ext_vector_type(4)));

#define T_SEQ 2048
#define DMODEL 2048
#define NHEAD 16
#define HDIM 128
#define ATT_SCALE 0.08838834764831843f

__device__ __forceinline__ u16 f2bf(float f) {
    return __builtin_bit_cast(u16, __float2bfloat16(f));
}
__device__ __forceinline__ bf16x8 as_bf(u16x8 v) {
    return __builtin_bit_cast(bf16x8, v);
}
__device__ __forceinline__ float lo2f(u32 w) { return __builtin_bit_cast(float, w << 16); }
__device__ __forceinline__ float hi2f(u32 w) { return __builtin_bit_cast(float, w & 0xffff0000u); }
__device__ __forceinline__ float bf2f(u16 v) { return __builtin_bit_cast(float, (u32)v << 16); }
__device__ __forceinline__ void gload_lds16(const u16* g, u16* l) {
    __builtin_amdgcn_global_load_lds(
        (const __attribute__((address_space(1))) u32*)(g),
        (__attribute__((address_space(3))) u32*)(l), 16, 0, 0);
}

// ------- fused prep: weight casts (blocks 0..8191) + RMSNorm (8192..10239) --
__global__ __launch_bounds__(256) void prep(const float* __restrict__ w1,
                                            const float* __restrict__ w2,
                                            const float* __restrict__ x,
                                            u16* __restrict__ d1,
                                            u16* __restrict__ d2,
                                            u16* __restrict__ xn) {
    const int b = blockIdx.x, tid = threadIdx.x;
    if (b < 8192) {
        int i = b * 256 + tid;
        const float* src; u16* dst; int k;
        if (i < 1572864) { src = w1; dst = d1; k = i; }
        else             { src = w2; dst = d2; k = i - 1572864; }
        float4 a = ((const float4*)src)[2 * k];
        float4 bb = ((const float4*)src)[2 * k + 1];
        u16x8 o;
        o[0] = f2bf(a.x); o[1] = f2bf(a.y); o[2] = f2bf(a.z); o[3] = f2bf(a.w);
        o[4] = f2bf(bb.x); o[5] = f2bf(bb.y); o[6] = f2bf(bb.z); o[7] = f2bf(bb.w);
        *(u16x8*)(dst + (size_t)k * 8) = o;
        return;
    }
    const int row = b - 8192;
    const float* xr = x + (size_t)row * DMODEL;
    float4 a = ((const float4*)xr)[2 * tid];
    float4 bb = ((const float4*)xr)[2 * tid + 1];
    float ss = a.x*a.x + a.y*a.y + a.z*a.z + a.w*a.w
             + bb.x*bb.x + bb.y*bb.y + bb.z*bb.z + bb.w*bb.w;
#pragma unroll
    for (int off = 32; off; off >>= 1) ss += __shfl_xor(ss, off);
    __shared__ float red[4];
    if ((tid & 63) == 0) red[tid >> 6] = ss;
    __syncthreads();
    float tot = red[0] + red[1] + red[2] + red[3];
    float r = rsqrtf(tot * (1.f / DMODEL) + 1e-6f);
    u16x8 o;
    o[0] = f2bf(a.x*r); o[1] = f2bf(a.y*r); o[2] = f2bf(a.z*r); o[3] = f2bf(a.w*r);
    o[4] = f2bf(bb.x*r); o[5] = f2bf(bb.y*r); o[6] = f2bf(bb.z*r); o[7] = f2bf(bb.w*r);
    *(u16x8*)(xn + (size_t)row * DMODEL + tid * 8) = o;
}

// ================= shared 8-phase GEMM machinery ===========================
#define VM2 asm volatile("s_waitcnt vmcnt(2)" ::: "memory");
#define VM4 asm volatile("s_waitcnt vmcnt(4)" ::: "memory");
#define VM0 asm volatile("s_waitcnt vmcnt(0)" ::: "memory");

#define ENDP                                                                  \
  __builtin_amdgcn_s_barrier();                                               \
  __builtin_amdgcn_sched_barrier(0);

// ---- 256x192 qkv GEMM, 6-phase uniform-16-MFMA schedule -------------------
// Waves 2Mx4N (48-wide N). Per buf 3 phases: Ph_a {A-MH0 + B0 reads; 16 MFMA
// N0/MH0}, Ph_b {B1 + A-MH1 reads; 16 MFMA = N1/MH0 (8, av) + N1/MH1 (8,
// av2)}, Ph_c {no reads (av2+bv held in regs); 16 MFMA N0/MH1}.
// Stage plan (region strictly-later than its last LDS read; audited):
//   Ph_a: B(1,kn1)t0,t1   Ph_b: B(1,kn1)t2 + A(0,kn2)mh0   Ph_c: A(0,kn2)mh1
//   Ph_d: B(0,kn2)t0,t1   Ph_e: B(0,kn2)t2 + A(1,kn3)mh0   Ph_f: A(1,kn3)mh1
// Ledger (steady): W1@Ph_c = vmcnt(4) [outstanding 11; youngest 4 = A(0,kn2),
// drains old A(1,kn1)x4 + B(1,kn1)x3]; W2@Ph_f = vmcnt(4) [youngest 4 =
// A(1,kn3), drains A(0,kn2)+B(0,kn2)]. Tails: st2/st3 false -> vmcnt(0).
// Prologue: buf0 full (7) + A(1,64) (4), vmcnt(4).
#define LDA6(DST, BUF, MH)                                                    \
  _Pragma("unroll") for (int mq = 0; mq < 4; ++mq) {                          \
    int ra = wr + (MH) * 64 + mq * 16 + fr;                                   \
    int sw = ra & 7;                                                          \
    _Pragma("unroll") for (int k2 = 0; k2 < 2; ++k2)                          \
      DST[mq][k2] = *(const u16x8*)(sA[BUF] + ra * 64 +                       \
                                    ((((k2 << 2) | fg) ^ sw) << 3));          \
  }

#define LDB0_192(BUF)                                                         \
  _Pragma("unroll") for (int nq = 0; nq < 2; ++nq) {                          \
    int rb = wc + nq * 16 + fr;                                               \
    int sw = rb & 7;                                                          \
    _Pragma("unroll") for (int k2 = 0; k2 < 2; ++k2)                          \
      bv[nq][k2] = *(const u16x8*)(sB[BUF] + rb * 64 +                        \
                                   ((((k2 << 2) | fg) ^ sw) << 3));           \
  }

#define LDB1_192(BUF)                                                         \
  {                                                                           \
    int rb = wc + 32 + fr;                                                    \
    int sw = rb & 7;                                                          \
    _Pragma("unroll") for (int k2 = 0; k2 < 2; ++k2)                          \
      bv1[k2] = *(const u16x8*)(sB[BUF] + rb * 64 +                           \
                                ((((k2 << 2) | fg) ^ sw) << 3));              \
  }

#define MN0(AV, MH)                                                           \
  __builtin_amdgcn_s_barrier();                                               \
  __builtin_amdgcn_s_setprio(1);                                              \
  _Pragma("unroll") for (int k2 = 0; k2 < 2; ++k2)                            \
    _Pragma("unroll") for (int mq = 0; mq < 4; ++mq)                          \
      _Pragma("unroll") for (int nq = 0; nq < 2; ++nq)                        \
        acc[(MH) * 4 + mq][nq] = __builtin_amdgcn_mfma_f32_16x16x32_bf16(     \
            as_bf(AV[mq][k2]), as_bf(bv[nq][k2]), acc[(MH) * 4 + mq][nq],     \
            0, 0, 0);                                                         \
  __builtin_amdgcn_s_setprio(0);

#define MN1B                                                                  \
  __builtin_amdgcn_s_barrier();                                               \
  __builtin_amdgcn_s_setprio(1);                                              \
  _Pragma("unroll") for (int k2 = 0; k2 < 2; ++k2)                            \
    _Pragma("unroll") for (int mq = 0; mq < 4; ++mq) {                        \
      acc[mq][2] = __builtin_amdgcn_mfma_f32_16x16x32_bf16(                   \
          as_bf(av[mq][k2]), as_bf(bv1[k2]), acc[mq][2], 0, 0, 0);            \
      acc[4 + mq][2] = __builtin_amdgcn_mfma_f32_16x16x32_bf16(               \
          as_bf(av2[mq][k2]), as_bf(bv1[k2]), acc[4 + mq][2], 0, 0, 0);       \
    }                                                                         \
  __builtin_amdgcn_s_setprio(0);

__global__ __launch_bounds__(512) void gemm192(const u16* __restrict__ A,
                                               const u16* __restrict__ B,
                                               u16* __restrict__ C,
                                               int M, int N, int K) {
    extern __shared__ char smem[];
    const int tid = threadIdx.x, lane = tid & 63, wid = tid >> 6;
    const int bm = blockIdx.y * 256, bn = blockIdx.x * 192;
    const int wr = (wid >> 2) * 128, wc = (wid & 3) * 48;
    const int fr = lane & 15, fg = lane >> 4;

    u16* sA[2] = {(u16*)smem, (u16*)(smem + 57344)};
    u16* sB[2] = {(u16*)(smem + 32768), (u16*)(smem + 90112)};

    const int cs = (((tid & 7) ^ ((tid >> 3) & 7)) << 3);
    const int s8 = (tid & 7) << 3;
    const int rr6 = tid >> 3;

    auto stA = [&](int buf, int k0, int mh) {
#pragma unroll
        for (int j = 0; j < 2; ++j) {
            int r = j * 128 + mh * 64 + rr6;
            gload_lds16(A + (size_t)(bm + r) * K + k0 + cs, sA[buf] + r * 64 + s8);
        }
    };
    auto stB = [&](int buf, int k0, int bt) {
        int r = bt * 64 + rr6;
        gload_lds16(B + (size_t)(bn + r) * K + k0 + cs, sB[buf] + r * 64 + s8);
    };

    f32x4 acc[8][3] = {};
    u16x8 av[4][2], av2[4][2], bv[2][2], bv1[2];
    const int nt = K >> 6;

    // prologue: buf0 tile0 full (7) + buf1 A(k=64) (4); vmcnt(4)
    stA(0, 0, 0); stA(0, 0, 1); stB(0, 0, 0); stB(0, 0, 1); stB(0, 0, 2);
    stA(1, 64, 0); stA(1, 64, 1);
    VM4
    __builtin_amdgcn_s_barrier();
    __builtin_amdgcn_sched_barrier(0);

    for (int it = 0; it < (nt >> 1); ++it) {
        const int kc = it << 7;
        const int kn1 = kc + 64, kn2 = kc + 128, kn3 = kc + 192;
        const bool st2 = (kn2 < K), st3 = (kn3 < K);

        // Ph_a (buf0): reads A-MH0 + B0; 16 MFMA N0/MH0
        LDA6(av, 0, 0) LDB0_192(0)
        stB(1, kn1, 0); stB(1, kn1, 1);
        MN0(av, 0) ENDP
        // Ph_b (buf0): reads B1 + A-MH1; 16 MFMA N1 both MH
        LDB1_192(0) LDA6(av2, 0, 1)
        stB(1, kn1, 2);
        if (st2) stA(0, kn2, 0);
        MN1B ENDP
        // Ph_c (buf0): no reads (av2, bv in regs); 16 MFMA N0/MH1
        if (st2) stA(0, kn2, 1);
        MN0(av2, 1)
        if (st2) { VM4 } else { VM0 }
        ENDP
        // Ph_d (buf1)
        LDA6(av, 1, 0) LDB0_192(1)
        if (st2) { stB(0, kn2, 0); stB(0, kn2, 1); }
        MN0(av, 0) ENDP
        // Ph_e (buf1)
        LDB1_192(1) LDA6(av2, 1, 1)
        if (st2) stB(0, kn2, 2);
        if (st3) stA(1, kn3, 0);
        MN1B ENDP
        // Ph_f (buf1)
        if (st3) stA(1, kn3, 1);
        MN0(av2, 1)
        if (st3) { VM4 } else { VM0 }
        ENDP
    }

#pragma unroll
    for (int am = 0; am < 8; ++am)
#pragma unroll
        for (int bq = 0; bq < 3; ++bq)
#pragma unroll
            for (int r = 0; r < 4; ++r) {
                int row = bm + wr + am * 16 + fg * 4 + r;
                int col = bn + wc + bq * 16 + fr;
                C[(size_t)row * N + col] = f2bf(acc[am][bq][r]);
            }
}

// ---- 128x128 8-phase variant for out-proj (resid epilogue) ----
#define LDAH(BUF, MH)                                                         \
  _Pragma("unroll") for (int mq = 0; mq < 2; ++mq) {                          \
    int ra = wr + (MH) * 32 + mq * 16 + fr;                                   \
    int sw = ra & 7;                                                          \
    _Pragma("unroll") for (int k2 = 0; k2 < 2; ++k2)                          \
      avh[mq][k2] = *(const u16x8*)(sA[BUF] + ra * 64 +                       \
                                    ((((k2 << 2) | fg) ^ sw) << 3));          \
  }

#define LDBH(BUF, NH)                                                         \
  _Pragma("unroll") for (int nq = 0; nq < 2; ++nq) {                          \
    int rb = wc + (NH) * 32 + nq * 16 + fr;                                   \
    int sw = rb & 7;                                                          \
    _Pragma("unroll") for (int k2 = 0; k2 < 2; ++k2)                          \
      bvh[nq][k2] = *(const u16x8*)(sB[BUF] + rb * 64 +                       \
                                    ((((k2 << 2) | fg) ^ sw) << 3));          \
  }

#define MFMAQH(MH, NH)                                                        \
  __builtin_amdgcn_s_barrier();                                               \
  __builtin_amdgcn_s_setprio(1);                                              \
  _Pragma("unroll") for (int k2 = 0; k2 < 2; ++k2)                            \
    _Pragma("unroll") for (int mq = 0; mq < 2; ++mq)                          \
      _Pragma("unroll") for (int nq = 0; nq < 2; ++nq)                        \
        acc[(MH) * 2 + mq][(NH) * 2 + nq] =                                   \
            __builtin_amdgcn_mfma_f32_16x16x32_bf16(                          \
                as_bf(avh[mq][k2]), as_bf(bvh[nq][k2]),                       \
                acc[(MH) * 2 + mq][(NH) * 2 + nq], 0, 0, 0);                  \
  __builtin_amdgcn_s_setprio(0);

__global__ __launch_bounds__(256) void gemm128(const u16* __restrict__ A,
                                               const u16* __restrict__ B,
                                               float* __restrict__ C,
                                               const float* __restrict__ resid,
                                               int M, int N, int K) {
    extern __shared__ char smem[];
    const int tid = threadIdx.x, lane = tid & 63, wid = tid >> 6;
    const int bm = blockIdx.y * 128, bn = blockIdx.x * 128;
    const int wr = (wid >> 1) * 64, wc = (wid & 1) * 64;
    const int fr = lane & 15, fg = lane >> 4;

    u16* sA[2] = {(u16*)smem, (u16*)(smem + 32768)};
    u16* sB[2] = {(u16*)(smem + 16384), (u16*)(smem + 49152)};

    const int cs = (((tid & 7) ^ ((tid >> 3) & 7)) << 3);
    const int s8 = (tid & 7) << 3;
    const int rr5 = tid >> 3;

    auto stA = [&](int buf, int k0, int mh) {
#pragma unroll
        for (int j = 0; j < 2; ++j) {
            int r = j * 64 + mh * 32 + rr5;
            gload_lds16(A + (size_t)(bm + r) * K + k0 + cs, sA[buf] + r * 64 + s8);
        }
    };
    auto stB = [&](int buf, int k0, int nh) {
#pragma unroll
        for (int j = 0; j < 2; ++j) {
            int r = j * 64 + nh * 32 + rr5;
            gload_lds16(B + (size_t)(bn + r) * K + k0 + cs, sB[buf] + r * 64 + s8);
        }
    };

    f32x4 acc[4][4] = {};
    u16x8 avh[2][2], bvh[2][2];
    const int nt = K >> 6;

    stA(0, 0, 0); stA(0, 0, 1); stB(0, 0, 0); stB(0, 0, 1);
    stA(1, 64, 0); stB(1, 64, 1);
    VM4
    __builtin_amdgcn_s_barrier();
    __builtin_amdgcn_sched_barrier(0);

    for (int it = 0; it < (nt >> 1); ++it) {
        const int kc = it << 7;
        const int kn1 = kc + 64, kn2 = kc + 128, kn3 = kc + 192;
        const bool st2 = (kn2 < K), st3 = (kn3 < K);

        LDAH(0, 0) LDBH(0, 0)
        stA(1, kn1, 1);
        MFMAQH(0, 0) ENDP
        LDBH(0, 1)
        stB(1, kn1, 0);
        MFMAQH(0, 1) ENDP
        LDAH(0, 1)
        if (st2) stA(0, kn2, 0);
        MFMAQH(1, 1) ENDP
        LDBH(0, 0)
        if (st2) stB(0, kn2, 1);
        MFMAQH(1, 0)
        if (st2) { VM4 } else { VM0 }
        ENDP
        LDAH(1, 0) LDBH(1, 0)
        if (st2) stA(0, kn2, 1);
        MFMAQH(0, 0) ENDP
        LDBH(1, 1)
        if (st2) stB(0, kn2, 0);
        MFMAQH(0, 1) ENDP
        LDAH(1, 1)
        if (st3) stA(1, kn3, 0);
        MFMAQH(1, 1) ENDP
        LDBH(1, 0)
        if (st3) stB(1, kn3, 1);
        MFMAQH(1, 0)
        VM4
        ENDP
    }

#pragma unroll
    for (int am = 0; am < 4; ++am)
#pragma unroll
        for (int bq = 0; bq < 4; ++bq)
#pragma unroll
            for (int r = 0; r < 4; ++r) {
                int row = bm + wr + am * 16 + fg * 4 + r;
                int col = bn + wc + bq * 16 + fr;
                float val = acc[am][bq][r] + resid[(size_t)row * N + col];
                C[(size_t)row * N + col] = val;
            }
}

// ---------------- per-head RMSNorm + RoPE (vectorized, bf16 qkv) -----------
__global__ __launch_bounds__(256) void rope_split(const u16* __restrict__ qkv,
                                                  const float* __restrict__ cosb,
                                                  const float* __restrict__ sinb,
                                                  u16* __restrict__ q_bf,
                                                  u16* __restrict__ k_bf,
                                                  float* __restrict__ k_out,
                                                  float* __restrict__ v_out) {
    const int t = blockIdx.x, tid = threadIdx.x, wid = tid >> 6, lane = tid & 63;
    const u16* row = qkv + (size_t)t * (3 * DMODEL);
    const int dp = (lane & 31) << 1;
    float2 c2 = *(const float2*)(cosb + t * 64 + dp);
    float2 s2 = *(const float2*)(sinb + t * 64 + dp);
    const bool hi = lane >= 32;

    for (int task = wid; task < 32; task += 4) {
        u32 w = *(const u32*)(row + task * 128 + lane * 2);
        float xa = lo2f(w), xb = hi2f(w);
        float ss = xa * xa + xb * xb;
#pragma unroll
        for (int off = 32; off; off >>= 1) ss += __shfl_xor(ss, off);
        float rn = rsqrtf(ss * (1.f / 128.f) + 1e-6f);
        float pa = __shfl_xor(xa, 32), pb = __shfl_xor(xb, 32);
        float oa, ob;
        if (!hi) {
            oa = (xa * c2.x - pa * s2.x) * rn;
            ob = (xb * c2.y - pb * s2.y) * rn;
        } else {
            oa = (pa * s2.x + xa * c2.x) * rn;
            ob = (pb * s2.y + xb * c2.y) * rn;
        }
        u32 pk = (u32)f2bf(oa) | ((u32)f2bf(ob) << 16);
        if (task < 16) {
            *(u32*)(q_bf + ((size_t)task * T_SEQ + t) * 128 + lane * 2) = pk;
        } else {
            int hh = task - 16;
            *(u32*)(k_bf + ((size_t)hh * T_SEQ + t) * 128 + lane * 2) = pk;
            float2 kk; kk.x = oa; kk.y = ob;
            *(float2*)(k_out + (size_t)t * DMODEL + hh * 128 + lane * 2) = kk;
        }
    }
    {
        u16x8 vv = *(const u16x8*)(row + 2 * DMODEL + tid * 8);
        float4 f0, f1;
        f0.x = bf2f(vv[0]); f0.y = bf2f(vv[1]); f0.z = bf2f(vv[2]); f0.w = bf2f(vv[3]);
        f1.x = bf2f(vv[4]); f1.y = bf2f(vv[5]); f1.z = bf2f(vv[6]); f1.w = bf2f(vv[7]);
        *(float4*)(v_out + (size_t)t * DMODEL + tid * 8) = f0;
        *(float4*)(v_out + (size_t)t * DMODEL + tid * 8 + 4) = f1;
    }
}

// ---------------- V transpose: qkv bf16 -> vt bf16 [h][128][T] -------------
__global__ __launch_bounds__(256) void vtrans(const u16* __restrict__ qkv,
                                              u16* __restrict__ vt) {
    const int b = blockIdx.x, tid = threadIdx.x;
    const int head = b >> 7;
    const int i = (b & 127) * 256 + tid;
    const int d = i & 127, tc = i >> 7;
    u16x8 o;
#pragma unroll
    for (int j = 0; j < 8; ++j)
        o[j] = qkv[(size_t)(tc * 8 + j) * (3 * DMODEL) + 2 * DMODEL + head * 128 + d];
    *(u16x8*)&vt[((size_t)head * 128 + d) * T_SEQ + tc * 8] = o;
}

// ---------------- causal flash attention, kv-split partials ----------------
__global__ __launch_bounds__(256) void attn_part(const u16* __restrict__ qb,
                                                 const u16* __restrict__ kb,
                                                 const u16* __restrict__ vtb,
                                                 u16* __restrict__ opart,
                                                 float* __restrict__ ml) {
    __shared__ u16 Ks[64 * 128];
    __shared__ u16 Vs[128 * 64];
    __shared__ u16 Ps[4][16 * 64];

    const int bid = blockIdx.x;
    const int r8 = bid & 7, s = bid >> 3;
    const int hs = s >> 6, g = (s >> 5) & 1, m = s & 31;
    const int head = r8 + (hs << 3);
    const int qt = g ? (31 - m) : m;
    const int nt = qt + 1;
    const int h0c = (nt + 1) >> 1;
    const int first = g ? h0c : 0;
    const int count = g ? (nt - h0c) : h0c;
    const int pidx = (head * 32 + qt) * 2 + g;

    const int tid = threadIdx.x, wid = tid >> 6, lane = tid & 63;
    const int fr = lane & 15, fg = lane >> 4;
    const u16* kh = kb + (size_t)head * T_SEQ * 128;
    const u16* vth = vtb + (size_t)head * 128 * T_SEQ;
    const u16* qh = qb + (size_t)head * T_SEQ * 128;
    const int q0 = qt * 64 + wid * 16;
    const int qrow_g = q0 + fr;

    u16x8 bq[4];
    {
        const u16* qrow = qh + (size_t)(q0 + fr) * 128 + fg * 8;
#pragma unroll
        for (int cc = 0; cc < 4; ++cc) bq[cc] = *(const u16x8*)(qrow + cc * 32);
    }

    auto stage = [&](int kv0) {
#pragma unroll
        for (int i = 0; i < 4; ++i) {
            int idx = i * 256 + tid;
            int r = idx >> 4;
            int cbs = ((idx & 15) << 4) ^ ((r & 7) << 4);
            gload_lds16(kh + (size_t)(kv0 + r) * 128 + (cbs >> 1), &Ks[idx * 8]);
        }
#pragma unroll
        for (int i = 0; i < 4; ++i) {
            int idx = i * 256 + tid;
            int d = idx >> 3;
            int cbs = ((idx & 7) << 4) ^ ((d & 7) << 4);
            gload_lds16(vth + (size_t)d * T_SEQ + kv0 + (cbs >> 1), &Vs[idx * 8]);
        }
    };

    f32x4 o[8] = {};
    float m_run = -1e30f, l_run = 0.f;

    for (int i = 0; i < count; ++i) {
        const int kv0 = (first + i) * 64;
        stage(kv0);
        asm volatile("s_waitcnt vmcnt(0)" ::: "memory");
        __builtin_amdgcn_s_barrier();
        __builtin_amdgcn_sched_barrier(0);

        const char* ksb = (const char*)&Ks[0];
        const char* vsb = (const char*)&Vs[0];
        char* psb = (char*)&Ps[wid][0];

        float p[4][4];
        float mx = -1e30f;
        const bool diag = (kv0 + 64 > q0);
#pragma unroll
        for (int st = 0; st < 4; ++st) {
            f32x4 sacc = {0.f, 0.f, 0.f, 0.f};
#pragma unroll
            for (int c4 = 0; c4 < 4; ++c4) {
                int r = st * 16 + fr;
                int cb = c4 * 64 + fg * 16;
                u16x8 ak = *(const u16x8*)(ksb + r * 256 + (cb ^ ((r & 7) << 4)));
                sacc = __builtin_amdgcn_mfma_f32_16x16x32_bf16(
                    as_bf(ak), as_bf(bq[c4]), sacc, 0, 0, 0);
            }
#pragma unroll
            for (int rr = 0; rr < 4; ++rr) {
                float sv = sacc[rr] * ATT_SCALE;
                if (diag) {
                    int kvg = kv0 + st * 16 + fg * 4 + rr;
                    sv = (kvg <= qrow_g) ? sv : -1e30f;
                }
                p[st][rr] = sv;
                mx = fmaxf(mx, sv);
            }
        }
        mx = fmaxf(mx, __shfl_xor(mx, 16));
        mx = fmaxf(mx, __shfl_xor(mx, 32));

        if (__all(mx - m_run <= 8.f)) {
            float rs = 0.f;
#pragma unroll
            for (int st = 0; st < 4; ++st) {
                u16x4 pw;
#pragma unroll
                for (int rr = 0; rr < 4; ++rr) {
                    float e = __expf(p[st][rr] - m_run);
                    rs += e;
                    pw[rr] = f2bf(e);
                }
                *(u16x4*)(psb + fr * 128 + ((st * 32 + fg * 8) ^ ((fr & 7) << 4))) = pw;
            }
            rs += __shfl_xor(rs, 16);
            rs += __shfl_xor(rs, 32);
            l_run += rs;
        } else {
            float m_new = fmaxf(m_run, mx);
            float corr = __expf(m_run - m_new);
            float rs = 0.f;
#pragma unroll
            for (int st = 0; st < 4; ++st) {
                u16x4 pw;
#pragma unroll
                for (int rr = 0; rr < 4; ++rr) {
                    float e = __expf(p[st][rr] - m_new);
                    rs += e;
                    pw[rr] = f2bf(e);
                }
                *(u16x4*)(psb + fr * 128 + ((st * 32 + fg * 8) ^ ((fr & 7) << 4))) = pw;
            }
            rs += __shfl_xor(rs, 16);
            rs += __shfl_xor(rs, 32);
            l_run = l_run * corr + rs;
            m_run = m_new;
            float ct[4];
#pragma unroll
            for (int rr = 0; rr < 4; ++rr) ct[rr] = __shfl(corr, fg * 4 + rr);
#pragma unroll
            for (int f = 0; f < 8; ++f)
#pragma unroll
                for (int rr = 0; rr < 4; ++rr) o[f][rr] *= ct[rr];
        }

#pragma unroll
        for (int ks = 0; ks < 2; ++ks) {
            u16x8 pa = *(const u16x8*)(psb + fr * 128 + ((ks * 64 + fg * 16) ^ ((fr & 7) << 4)));
#pragma unroll
            for (int f = 0; f < 8; ++f) {
                int d = f * 16 + fr;
                u16x8 vB = *(const u16x8*)(vsb + d * 128 + ((ks * 64 + fg * 16) ^ ((d & 7) << 4)));
                o[f] = __builtin_amdgcn_mfma_f32_16x16x32_bf16(
                    as_bf(pa), as_bf(vB), o[f], 0, 0, 0);
            }
        }
        __builtin_amdgcn_s_barrier();
        __builtin_amdgcn_sched_barrier(0);
    }

    u16* op = opart + (size_t)pidx * 8192;
#pragma unroll
    for (int f = 0; f < 8; ++f)
#pragma unroll
        for (int rr = 0; rr < 4; ++rr)
            op[(wid * 16 + fg * 4 + rr) * 128 + f * 16 + fr] = f2bf(o[f][rr]);
    if (fg == 0) {
        ml[pidx * 128 + wid * 16 + fr] = m_run;
        ml[pidx * 128 + 64 + wid * 16 + fr] = l_run;
    }
}

// ---------------- merge kv-split partials -> x_bf --------------------------
__global__ __launch_bounds__(256) void attn_merge(const u16* __restrict__ opart,
                                                  const float* __restrict__ ml,
                                                  u16* __restrict__ xout) {
    const int b = blockIdx.x, tid = threadIdx.x;
    const int head = b >> 5, qt = b & 31;
    const int p0 = b * 2, p1 = b * 2 + 1;
    const int row = tid >> 2, d0 = (tid & 3) * 32;

    float m0 = ml[p0 * 128 + row], l0 = ml[p0 * 128 + 64 + row];
    float m1 = ml[p1 * 128 + row], l1 = ml[p1 * 128 + 64 + row];
    float M = fmaxf(m0, m1);
    float w0 = __expf(m0 - M), w1 = __expf(m1 - M);
    float inv = 1.f / (l0 * w0 + l1 * w1);
    w0 *= inv; w1 *= inv;

    const u16* a0 = opart + (size_t)p0 * 8192 + row * 128 + d0;
    const u16* a1 = opart + (size_t)p1 * 8192 + row * 128 + d0;
    u16* dst = xout + (size_t)(qt * 64 + row) * DMODEL + head * 128 + d0;
#pragma unroll
    for (int j = 0; j < 4; ++j) {
        u16x8 v0 = *(const u16x8*)(a0 + j * 8);
        u16x8 v1 = *(const u16x8*)(a1 + j * 8);
        u16x8 ov;
#pragma unroll
        for (int e = 0; e < 8; ++e)
            ov[e] = f2bf(bf2f(v0[e]) * w0 + bf2f(v1[e]) * w1);
        *(u16x8*)(dst + j * 8) = ov;
    }
}

extern "C" void kernel_launch(void* const* d_in, const int* in_sizes, int n_in,
                              void* d_out, int out_size, void* d_ws, size_t ws_size,
                              hipStream_t stream) {
    const float* x_in = (const float*)d_in[0];
    const float* w_qkv = (const float*)d_in[1];
    const float* w_o = (const float*)d_in[2];
    const float* cosb = (const float*)d_in[3];
    const float* sinb = (const float*)d_in[4];

    float* out = (float*)d_out;
    float* k_out = out + 4194304;
    float* v_out = out + 8388608;

    char* ws = (char*)d_ws;
    u16* xn    = (u16*)(ws);                         // 8 MiB  [T][D] bf16
    u16* w_bf  = (u16*)(ws + (size_t)(8u << 20));    // 24 MiB [3D][D] bf16
    u16* o_bf  = (u16*)(ws + (size_t)(32u << 20));   // 8 MiB  [D][D] bf16
    u16* qkv   = (u16*)(ws + (size_t)(40u << 20));   // 24 MiB [T][3D] bf16
    u16* q_bf  = (u16*)(ws + (size_t)(64u << 20));   // 8 MiB  [h][T][hd]
    u16* k_bf  = (u16*)(ws + (size_t)(72u << 20));   // 8 MiB
    u16* vt_bf = (u16*)(ws + (size_t)(80u << 20));   // 8 MiB  [h][hd][T]
    u16* x_bf  = (u16*)(ws + (size_t)(88u << 20));   // 8 MiB  [T][D]
    u16* opart = (u16*)(ws + (size_t)(40u << 20));   // 16 MiB (aliases dead qkv)
    float* mlb = (float*)(ws + (size_t)(56u << 20)); // 512 KiB

    (void)hipFuncSetAttribute(reinterpret_cast<const void*>(&gemm192),
                              hipFuncAttributeMaxDynamicSharedMemorySize, 114688);
    (void)hipFuncSetAttribute(reinterpret_cast<const void*>(&gemm128),
                              hipFuncAttributeMaxDynamicSharedMemorySize, 65536);

    prep<<<10240, 256, 0, stream>>>(w_qkv, w_o, x_in, w_bf, o_bf, xn);
    gemm192<<<dim3(32, 8), 512, 114688, stream>>>(xn, w_bf, qkv, 2048, 6144, 2048);
    rope_split<<<2048, 256, 0, stream>>>(qkv, cosb, sinb, q_bf, k_bf, k_out, v_out);
    vtrans<<<2048, 256, 0, stream>>>(qkv, vt_bf);
    attn_part<<<1024, 256, 0, stream>>>(q_bf, k_bf, vt_bf, opart, mlb);
    attn_merge<<<512, 256, 0, stream>>>(opart, mlb, x_bf);
    gemm128<<<dim3(16, 16), 256, 65536, stream>>>(x_bf, o_bf, out, x_in, 2048, 2048, 2048);
}